// Round 1
// baseline (324.950 us; speedup 1.0000x reference)
//
#include <hip/hip_runtime.h>
#include <hip/hip_bf16.h>

#define DEVINL static __device__ __forceinline__

typedef __attribute__((ext_vector_type(4))) float f32x4;
typedef __attribute__((ext_vector_type(8))) short bf16x8;

DEVINL short f2bf(float f) {
  union { float f; unsigned u; } v; v.f = f;
  unsigned r = v.u + 0x7fffu + ((v.u >> 16) & 1u);
  return (short)(r >> 16);
}
DEVINL float bf2f(short s) {
  union { unsigned u; float f; } v; v.u = ((unsigned)(unsigned short)s) << 16;
  return v.f;
}
DEVINL float ldf(float x) { return x; }
DEVINL float ldf(short x) { return bf2f(x); }

// ---------------- f32 -> bf16 convert, 4 elems/thread ----------------
__global__ void k_cvt(const float* __restrict__ in, short* __restrict__ out, int n4) {
  int i = blockIdx.x * blockDim.x + threadIdx.x;
  if (i >= n4) return;
  const float4 v = reinterpret_cast<const float4*>(in)[i];
  short4 o;
  o.x = f2bf(v.x); o.y = f2bf(v.y); o.z = f2bf(v.z); o.w = f2bf(v.w);
  reinterpret_cast<short4*>(out)[i] = o;
}

// ------- batched transpose [batch][R][C] -> [batch][C][R], out bf16 -------
template <typename Tin>
__global__ void k_tr(const Tin* __restrict__ in, short* __restrict__ out, int R, int C) {
  __shared__ float tile[32][33];
  const int bz = blockIdx.z;
  const int r0 = blockIdx.y * 32, c0 = blockIdx.x * 32;
  const int tx = threadIdx.x & 31, ty = threadIdx.x >> 5;  // ty in 0..7
  const Tin* ip = in + (size_t)bz * R * C;
  short* op = out + (size_t)bz * R * C;
#pragma unroll
  for (int k = 0; k < 4; k++)
    tile[ty + k * 8][tx] = ldf(ip[(size_t)(r0 + ty + k * 8) * C + c0 + tx]);
  __syncthreads();
#pragma unroll
  for (int k = 0; k < 4; k++)
    op[(size_t)(c0 + ty + k * 8) * R + r0 + tx] = f2bf(tile[tx][ty + k * 8]);
}

// ---------------- bf16 MFMA GEMM: C[M][N] = A[M][K] * Bt[N][K]^T ----------------
// mode 0: fused q/kv projection epilogue (bf16, head-major scatter)
// mode 2: f32 row-major into Out0
__global__ __launch_bounds__(256) void k_gemm(
    const short* __restrict__ A, const short* __restrict__ Bt,
    void* __restrict__ Out0, void* __restrict__ Out1,
    int M, int N, int K, int mode) {
  __shared__ __align__(16) short lA[128 * 32];
  __shared__ __align__(16) short lB[128 * 32];
  const int m0 = blockIdx.x * 128, n0 = blockIdx.y * 128;
  const int tid = threadIdx.x, lane = tid & 63, w = tid >> 6;
  const int wr = w >> 1, wc = w & 1;
  const int lr = lane & 15, lk = (lane >> 4) * 8;
  f32x4 acc[4][4] = {};
  for (int k0 = 0; k0 < K; k0 += 32) {
#pragma unroll
    for (int c = 0; c < 2; c++) {
      const int off = w * 1024 + c * 512 + lane * 8;  // element offset in 4096-elem tile
      const int row = off >> 5, col = off & 31;
      __builtin_amdgcn_global_load_lds(
          (const __attribute__((address_space(1))) void*)(A + (size_t)(m0 + row) * K + k0 + col),
          (__attribute__((address_space(3))) void*)(lA + off), 16, 0, 0);
      __builtin_amdgcn_global_load_lds(
          (const __attribute__((address_space(1))) void*)(Bt + (size_t)(n0 + row) * K + k0 + col),
          (__attribute__((address_space(3))) void*)(lB + off), 16, 0, 0);
    }
    __syncthreads();
    bf16x8 af[4], bfr[4];
#pragma unroll
    for (int i = 0; i < 4; i++)
      af[i] = *reinterpret_cast<const bf16x8*>(lA + (wr * 64 + i * 16 + lr) * 32 + lk);
#pragma unroll
    for (int j = 0; j < 4; j++)
      bfr[j] = *reinterpret_cast<const bf16x8*>(lB + (wc * 64 + j * 16 + lr) * 32 + lk);
#pragma unroll
    for (int i = 0; i < 4; i++)
#pragma unroll
      for (int j = 0; j < 4; j++)
        acc[i][j] = __builtin_amdgcn_mfma_f32_16x16x32_bf16(af[i], bfr[j], acc[i][j], 0, 0, 0);
    __syncthreads();
  }
  const int rg = lane >> 4;
#pragma unroll
  for (int i = 0; i < 4; i++)
#pragma unroll
    for (int j = 0; j < 4; j++)
#pragma unroll
      for (int r = 0; r < 4; r++) {
        const int m = m0 + wr * 64 + i * 16 + rg * 4 + r;
        const int n = n0 + wc * 64 + j * 16 + lr;
        const float v = acc[i][j][r];
        if (mode == 2) {
          ((float*)Out0)[(size_t)m * N + n] = v;
        } else {
          const int b = m >> 11, t = m & 2047;
          if (n < 2048) {  // q: [b][n_head][t][h]
            ((short*)Out0)[(((size_t)(b * 16 + (n >> 7))) << 18) + t * 128 + (n & 127)] = f2bf(v);
          } else {  // kv: [c][b][kv][t][h]
            const int nn = n - 2048;
            ((short*)Out1)[(((size_t)(((nn >> 9) * 2 + b) * 4 + ((nn >> 7) & 3))) << 18) +
                           t * 128 + (nn & 127)] = f2bf(v);
          }
        }
      }
}

// ---------------- in-place RoPE on bf16 [rows][128]; t = row & 2047 ----------------
__global__ void k_rope(short* __restrict__ q, float scale) {
  const int gid = blockIdx.x * blockDim.x + threadIdx.x;
  const int i = gid & 63;
  const int row = gid >> 6;
  const int t = row & 2047;
  short* p = q + (size_t)row * 128;
  const float inv = __expf(-(float)i * (float)(9.210340371976184 / 64.0));  // 10000^{-i/64}
  const float ang = (float)t * inv;
  float sn, cs;
  sincosf(ang, &sn, &cs);
  const float x1 = bf2f(p[i]), x2 = bf2f(p[i + 64]);
  p[i] = f2bf((x1 * cs - x2 * sn) * scale);
  p[i + 64] = f2bf((x2 * cs + x1 * sn) * scale);
}

// ---------------- flash attention, sliding window + tanh soft-cap ----------------
// q: [b][n][t][h] bf16 (roped+scaled); kk: [b][kv][s][h] bf16 (roped);
// vT: [b][kv][h][s] bf16; enc out: [b][t][n*128+h] bf16
__global__ __launch_bounds__(256) void k_attn(
    const short* __restrict__ q, const short* __restrict__ kk,
    const short* __restrict__ vT, short* __restrict__ enc) {
  __shared__ __align__(16) short lK[32 * 128];   // swizzled: byte(s,q8)=s*256+((q8*16)^((s&7)<<4))
  __shared__ __align__(16) short lV[128 * 32];   // swizzled: byte(h,u)=h*64+((u^((h>>1)&3))<<4)
  __shared__ __align__(16) short lP[4][16 * 40]; // per-wave P, padded stride 40
  const int bn = blockIdx.y, b = bn >> 4, n = bn & 15, kv = n >> 2;
  const int qt0 = blockIdx.x * 64;
  const int tid = threadIdx.x, lane = tid & 63, w = tid >> 6;
  const int lr = lane & 15, lu = lane >> 4;
  const short* qbase = q + (((size_t)(b * 16 + n)) << 18) + (size_t)(qt0 + w * 16) * 128;
  bf16x8 qa[4];
#pragma unroll
  for (int c = 0; c < 4; c++)
    qa[c] = *reinterpret_cast<const bf16x8*>(qbase + lr * 128 + c * 32 + lu * 8);
  f32x4 o[8] = {};
  float mrow[4] = {-1e30f, -1e30f, -1e30f, -1e30f};
  float lsum[4] = {0.f, 0.f, 0.f, 0.f};
  const short* kbase = kk + (((size_t)(b * 4 + kv)) << 18);
  const short* vbase = vT + (((size_t)(b * 4 + kv)) << 18);
  const int t_row = qt0 + w * 16 + lu * 4;
  int st0 = qt0 - 1023; if (st0 < 0) st0 = 0;
  st0 >>= 5;
  const int stE = (qt0 + 63) >> 5;
  for (int st = st0; st <= stE; st++) {
    const int s0 = st << 5;
#pragma unroll
    for (int c = 0; c < 2; c++) {
      const int L = w * 2048 + c * 1024 + lane * 16;  // byte offset in 8 KiB tile
      {  // K tile
        const int s = L >> 8;
        const int low = (L & 255) ^ ((s & 7) << 4);
        const int koff = (low >> 4) * 8;
        __builtin_amdgcn_global_load_lds(
            (const __attribute__((address_space(1))) void*)(kbase + (size_t)(s0 + s) * 128 + koff),
            (__attribute__((address_space(3))) void*)((char*)lK + L), 16, 0, 0);
      }
      {  // V tile
        const int h = L >> 6;
        const int u = ((L >> 4) & 3) ^ ((h >> 1) & 3);
        __builtin_amdgcn_global_load_lds(
            (const __attribute__((address_space(1))) void*)(vbase + (size_t)h * 2048 + s0 + u * 8),
            (__attribute__((address_space(3))) void*)((char*)lV + L), 16, 0, 0);
      }
    }
    __syncthreads();
    f32x4 sc[2] = {};
#pragma unroll
    for (int cg = 0; cg < 2; cg++) {
      const int s = cg * 16 + lr;
      const int sw = (s & 7) << 4;
#pragma unroll
      for (int c = 0; c < 4; c++) {
        bf16x8 kb = *reinterpret_cast<const bf16x8*>((char*)lK + s * 256 + (((c * 4 + lu) << 4) ^ sw));
        sc[cg] = __builtin_amdgcn_mfma_f32_16x16x32_bf16(qa[c], kb, sc[cg], 0, 0, 0);
      }
    }
    float pv[2][4];
#pragma unroll
    for (int cg = 0; cg < 2; cg++)
#pragma unroll
      for (int r = 0; r < 4; r++) {
        const int s = s0 + cg * 16 + lr;
        const int t = t_row + r;
        const float capped = tanhf(sc[cg][r] * (1.f / 50.f)) * 50.f;
        const bool valid = (s <= t) && (s > t - 1024);
        pv[cg][r] = valid ? capped : -1e30f;
      }
#pragma unroll
    for (int r = 0; r < 4; r++) {
      float m2 = fmaxf(pv[0][r], pv[1][r]);
#pragma unroll
      for (int d = 1; d < 16; d <<= 1) m2 = fmaxf(m2, __shfl_xor(m2, d, 64));
      const float mnew = fmaxf(mrow[r], m2);
      const float alpha = __expf(mrow[r] - mnew);
      mrow[r] = mnew;
      const float p0 = (pv[0][r] > -1e29f) ? __expf(pv[0][r] - mnew) : 0.f;
      const float p1 = (pv[1][r] > -1e29f) ? __expf(pv[1][r] - mnew) : 0.f;
      float ps = p0 + p1;
#pragma unroll
      for (int d = 1; d < 16; d <<= 1) ps += __shfl_xor(ps, d, 64);
      lsum[r] = lsum[r] * alpha + ps;
#pragma unroll
      for (int oc = 0; oc < 8; oc++) o[oc][r] *= alpha;
      lP[w][(lu * 4 + r) * 40 + lr] = f2bf(p0);
      lP[w][(lu * 4 + r) * 40 + 16 + lr] = f2bf(p1);
    }
    const bf16x8 pf = *reinterpret_cast<const bf16x8*>(&lP[w][lr * 40 + lu * 8]);
#pragma unroll
    for (int oc = 0; oc < 8; oc++) {
      const int h = oc * 16 + lr;
      bf16x8 vb = *reinterpret_cast<const bf16x8*>((char*)lV + h * 64 + ((lu ^ ((h >> 1) & 3)) << 4));
      o[oc] = __builtin_amdgcn_mfma_f32_16x16x32_bf16(pf, vb, o[oc], 0, 0, 0);
    }
    __syncthreads();
  }
#pragma unroll
  for (int oc = 0; oc < 8; oc++)
#pragma unroll
    for (int r = 0; r < 4; r++) {
      const int t = t_row + r;
      enc[((size_t)b * 2048 + t) * 2048 + n * 128 + oc * 16 + lr] = f2bf(o[oc][r] / lsum[r]);
    }
}

extern "C" void kernel_launch(void* const* d_in, const int* in_sizes, int n_in,
                              void* d_out, int out_size, void* d_ws, size_t ws_size,
                              hipStream_t stream) {
  (void)in_sizes; (void)n_in; (void)out_size; (void)ws_size;
  const float* x    = (const float*)d_in[0];
  const float* wq   = (const float*)d_in[3];
  const float* wkv  = (const float*)d_in[4];
  const float* wvec = (const float*)d_in[5];
  char* ws = (char*)d_ws;
  size_t off = 0;
  short* xbf   = (short*)(ws + off); off += (size_t)8388608 * 2;            // x bf16 [B*T][D]
  short* wall  = (short*)(ws + off); off += (size_t)3072 * 2048 * 2;        // [wqT|wkT|wvT] rows x K
  short* wvecT = (short*)(ws + off); off += (size_t)2048 * 2048 * 2;        // [d][nh]
  short* qbuf  = (short*)(ws + off); off += (size_t)2 * 16 * 2048 * 128 * 2; // q bf16 [b][n][t][h]
  short* kvbuf = (short*)(ws + off); off += (size_t)2 * 2 * 4 * 2048 * 128 * 2; // [c][b][kv][t][h]
  short* vTbuf = (short*)(ws + off); off += (size_t)2 * 4 * 128 * 2048 * 2; // [b][kv][h][s]
  short* encb  = (short*)(ws + off); off += (size_t)2 * 2048 * 2048 * 2;    // [b][t][nh]

  k_cvt<<<8192, 256, 0, stream>>>(x, xbf, 2097152);
  k_tr<float><<<dim3(4, 64, 16), 256, 0, stream>>>(wq, wall, 2048, 128);
  k_tr<float><<<dim3(4, 64, 4), 256, 0, stream>>>(wkv, wall + 4194304, 2048, 128);
  k_tr<float><<<dim3(4, 64, 4), 256, 0, stream>>>(wkv + 1048576, wall + 5242880, 2048, 128);
  k_tr<float><<<dim3(64, 64, 1), 256, 0, stream>>>(wvec, wvecT, 2048, 2048);
  k_gemm<<<dim3(32, 24), 256, 0, stream>>>(xbf, wall, qbuf, kvbuf, 4096, 3072, 2048, 0);
  k_rope<<<16384, 256, 0, stream>>>(qbuf, 0.08838834764831845f);  // 1/sqrt(128)
  k_rope<<<4096, 256, 0, stream>>>(kvbuf, 1.0f);
  k_tr<short><<<dim3(4, 64, 8), 256, 0, stream>>>(kvbuf + 2097152, vTbuf, 2048, 128);
  k_attn<<<dim3(32, 32), 256, 0, stream>>>(qbuf, kvbuf, vTbuf, encb);
  k_gemm<<<dim3(32, 16), 256, 0, stream>>>(encb, wvecT, d_out, nullptr, 4096, 2048, 2048, 2);
}

// Round 2
// 259.627 us; speedup vs baseline: 1.2516x; 1.2516x over previous
//
#include <hip/hip_runtime.h>
#include <hip/hip_bf16.h>

#define DEVINL static __device__ __forceinline__

typedef __attribute__((ext_vector_type(4))) float f32x4;
typedef __attribute__((ext_vector_type(8))) short bf16x8;

DEVINL short f2bf(float f) {
  union { float f; unsigned u; } v; v.f = f;
  unsigned r = v.u + 0x7fffu + ((v.u >> 16) & 1u);
  return (short)(r >> 16);
}
DEVINL float bf2f(short s) {
  union { unsigned u; float f; } v; v.u = ((unsigned)(unsigned short)s) << 16;
  return v.f;
}
DEVINL float ldf(float x) { return x; }
DEVINL float ldf(short x) { return bf2f(x); }

// ---------------- f32 -> bf16 convert, 4 elems/thread ----------------
__global__ void k_cvt(const float* __restrict__ in, short* __restrict__ out, int n4) {
  int i = blockIdx.x * blockDim.x + threadIdx.x;
  if (i >= n4) return;
  const float4 v = reinterpret_cast<const float4*>(in)[i];
  short4 o;
  o.x = f2bf(v.x); o.y = f2bf(v.y); o.z = f2bf(v.z); o.w = f2bf(v.w);
  reinterpret_cast<short4*>(out)[i] = o;
}

// ------- batched transpose [batch][R][C] -> [batch][C][R], out bf16 -------
template <typename Tin>
__global__ void k_tr(const Tin* __restrict__ in, short* __restrict__ out, int R, int C) {
  __shared__ float tile[32][33];
  const int bz = blockIdx.z;
  const int r0 = blockIdx.y * 32, c0 = blockIdx.x * 32;
  const int tx = threadIdx.x & 31, ty = threadIdx.x >> 5;  // ty in 0..7
  const Tin* ip = in + (size_t)bz * R * C;
  short* op = out + (size_t)bz * R * C;
#pragma unroll
  for (int k = 0; k < 4; k++)
    tile[ty + k * 8][tx] = ldf(ip[(size_t)(r0 + ty + k * 8) * C + c0 + tx]);
  __syncthreads();
#pragma unroll
  for (int k = 0; k < 4; k++)
    op[(size_t)(c0 + ty + k * 8) * R + r0 + tx] = f2bf(tile[tx][ty + k * 8]);
}

// ---------------- bf16 MFMA GEMM: C[M][N] = A[M][K] * Bt[N][K]^T ----------------
// mode 0: fused q/kv projection epilogue (bf16, head-major scatter)
// mode 2: f32 row-major into Out0
__global__ __launch_bounds__(256) void k_gemm(
    const short* __restrict__ A, const short* __restrict__ Bt,
    void* __restrict__ Out0, void* __restrict__ Out1,
    int M, int N, int K, int mode) {
  __shared__ __align__(16) short lA[128 * 32];
  __shared__ __align__(16) short lB[128 * 32];
  const int m0 = blockIdx.x * 128, n0 = blockIdx.y * 128;
  const int tid = threadIdx.x, lane = tid & 63, w = tid >> 6;
  const int wr = w >> 1, wc = w & 1;
  const int lr = lane & 15, lk = (lane >> 4) * 8;
  f32x4 acc[4][4] = {};
  for (int k0 = 0; k0 < K; k0 += 32) {
#pragma unroll
    for (int c = 0; c < 2; c++) {
      const int off = w * 1024 + c * 512 + lane * 8;  // element offset in 4096-elem tile
      const int row = off >> 5, col = off & 31;
      __builtin_amdgcn_global_load_lds(
          (const __attribute__((address_space(1))) void*)(A + (size_t)(m0 + row) * K + k0 + col),
          (__attribute__((address_space(3))) void*)(lA + off), 16, 0, 0);
      __builtin_amdgcn_global_load_lds(
          (const __attribute__((address_space(1))) void*)(Bt + (size_t)(n0 + row) * K + k0 + col),
          (__attribute__((address_space(3))) void*)(lB + off), 16, 0, 0);
    }
    __syncthreads();
    bf16x8 af[4], bfr[4];
#pragma unroll
    for (int i = 0; i < 4; i++)
      af[i] = *reinterpret_cast<const bf16x8*>(lA + (wr * 64 + i * 16 + lr) * 32 + lk);
#pragma unroll
    for (int j = 0; j < 4; j++)
      bfr[j] = *reinterpret_cast<const bf16x8*>(lB + (wc * 64 + j * 16 + lr) * 32 + lk);
#pragma unroll
    for (int i = 0; i < 4; i++)
#pragma unroll
      for (int j = 0; j < 4; j++)
        acc[i][j] = __builtin_amdgcn_mfma_f32_16x16x32_bf16(af[i], bfr[j], acc[i][j], 0, 0, 0);
    __syncthreads();
  }
  const int rg = lane >> 4;
#pragma unroll
  for (int i = 0; i < 4; i++)
#pragma unroll
    for (int j = 0; j < 4; j++)
#pragma unroll
      for (int r = 0; r < 4; r++) {
        const int m = m0 + wr * 64 + i * 16 + rg * 4 + r;
        const int n = n0 + wc * 64 + j * 16 + lr;
        const float v = acc[i][j][r];
        if (mode == 2) {
          ((float*)Out0)[(size_t)m * N + n] = v;
        } else {
          const int b = m >> 11, t = m & 2047;
          if (n < 2048) {  // q: [b][n_head][t][h]
            ((short*)Out0)[(((size_t)(b * 16 + (n >> 7))) << 18) + t * 128 + (n & 127)] = f2bf(v);
          } else {  // kv: [c][b][kv][t][h]
            const int nn = n - 2048;
            ((short*)Out1)[(((size_t)(((nn >> 9) * 2 + b) * 4 + ((nn >> 7) & 3))) << 18) +
                           t * 128 + (nn & 127)] = f2bf(v);
          }
        }
      }
}

// ---------------- in-place RoPE on bf16 [rows][128]; t = row & 2047 ----------------
__global__ void k_rope(short* __restrict__ q, float scale) {
  const int gid = blockIdx.x * blockDim.x + threadIdx.x;
  const int i = gid & 63;
  const int row = gid >> 6;
  const int t = row & 2047;
  short* p = q + (size_t)row * 128;
  const float inv = __expf(-(float)i * (float)(9.210340371976184 / 64.0));  // 10000^{-i/64}
  const float ang = (float)t * inv;
  float sn, cs;
  sincosf(ang, &sn, &cs);
  const float x1 = bf2f(p[i]), x2 = bf2f(p[i + 64]);
  p[i] = f2bf((x1 * cs - x2 * sn) * scale);
  p[i + 64] = f2bf((x2 * cs + x1 * sn) * scale);
}

// ---------------- flash attention, sliding window + tanh soft-cap ----------------
// Soft-cap bounds logits to [-50,50] => fixed-max softmax (max=0): p = exp(capped),
// no online max tracking, no o-rescale, sum reduced once at the end.
// q: [b][n][t][h] bf16 (roped+scaled); kk: [b][kv][s][h] bf16 (roped);
// vT: [b][kv][h][s] bf16; enc out: [b][t][n*128+h] bf16
__global__ __launch_bounds__(256) void k_attn(
    const short* __restrict__ q, const short* __restrict__ kk,
    const short* __restrict__ vT, short* __restrict__ enc) {
  __shared__ __align__(16) short lK[64 * 128];   // [s][h], byte ^= ((s&7)<<4)
  __shared__ __align__(16) short lV[128 * 64];   // [h][s], byte ^= ((h&7)<<4)
  __shared__ __align__(16) short lP[4][16 * 64]; // per-wave P [t][s], byte ^= ((t&7)<<4)
  const int bn = blockIdx.y, b = bn >> 4, n = bn & 15, kv = n >> 2;
  const int qt0 = (31 - blockIdx.x) * 64;  // reversed: heavy blocks first
  const int tid = threadIdx.x, lane = tid & 63, w = tid >> 6;
  const int lr = lane & 15, lu = lane >> 4;
  const short* qbase = q + (((size_t)(b * 16 + n)) << 18) + (size_t)(qt0 + w * 16) * 128;
  bf16x8 qa[4];
#pragma unroll
  for (int c = 0; c < 4; c++)
    qa[c] = *reinterpret_cast<const bf16x8*>(qbase + lr * 128 + c * 32 + lu * 8);
  f32x4 o[8] = {};
  float lsum[4] = {0.f, 0.f, 0.f, 0.f};
  const short* kbase = kk + (((size_t)(b * 4 + kv)) << 18);
  const short* vbase = vT + (((size_t)(b * 4 + kv)) << 18);
  char* lPw = (char*)lP[w];
  const int t_row = qt0 + w * 16 + lu * 4;
  int st0 = qt0 - 1023; if (st0 < 0) st0 = 0;
  st0 >>= 6;
  const int stE = (qt0 + 63) >> 6;
  for (int st = st0; st <= stE; st++) {
    const int s0 = st << 6;
#pragma unroll
    for (int c = 0; c < 4; c++) {
      const int L = w * 4096 + c * 1024 + lane * 16;  // byte offset in 16 KiB tile
      {  // K tile: linear LDS dest, pre-swizzled global source
        const int s = L >> 8, slot = (L >> 4) & 15;
        const int sp = slot ^ (s & 7);
        __builtin_amdgcn_global_load_lds(
            (const __attribute__((address_space(1))) void*)(kbase + (size_t)(s0 + s) * 128 + sp * 8),
            (__attribute__((address_space(3))) void*)((char*)lK + L), 16, 0, 0);
      }
      {  // V tile
        const int h = L >> 7, slot = (L >> 4) & 7;
        const int u = slot ^ (h & 7);
        __builtin_amdgcn_global_load_lds(
            (const __attribute__((address_space(1))) void*)(vbase + (size_t)h * 2048 + s0 + u * 8),
            (__attribute__((address_space(3))) void*)((char*)lV + L), 16, 0, 0);
      }
    }
    __syncthreads();
    // ---- QK^T: sc[cg] = D[t=lu*4+r][s=cg*16+lr] ----
    f32x4 sc[4];
#pragma unroll
    for (int cg = 0; cg < 4; cg++) {
      sc[cg] = (f32x4){0.f, 0.f, 0.f, 0.f};
      const int s = cg * 16 + lr;
      const int sw = (s & 7) << 4;
#pragma unroll
      for (int c = 0; c < 4; c++) {
        bf16x8 kb = *reinterpret_cast<const bf16x8*>((char*)lK + s * 256 + (((c * 4 + lu) << 4) ^ sw));
        sc[cg] = __builtin_amdgcn_mfma_f32_16x16x32_bf16(qa[c], kb, sc[cg], 0, 0, 0);
      }
    }
    // ---- soft-cap + exp (fixed max), write P to swizzled LDS ----
#pragma unroll
    for (int cg = 0; cg < 4; cg++) {
      const int s = s0 + cg * 16 + lr;
#pragma unroll
      for (int r = 0; r < 4; r++) {
        const int t = t_row + r;
        const bool valid = (s <= t) & (s > t - 1024);
        const float e2 = __expf(sc[cg][r] * 0.04f);                 // exp(2x/50)
        const float th = 1.f - 2.f * __builtin_amdgcn_rcpf(e2 + 1.f); // tanh(x/50)
        const float p = valid ? __expf(50.f * th) : 0.f;
        lsum[r] += p;
        const int row = lu * 4 + r;
        *(short*)(lPw + (row << 7) + ((((cg * 16 + lr) << 1)) ^ ((row & 7) << 4))) = f2bf(p);
      }
    }
    // ---- PV: o[oc] += P[t][s] * V[s][h] ----
#pragma unroll
    for (int ks = 0; ks < 2; ks++) {
      const bf16x8 pf = *reinterpret_cast<const bf16x8*>(
          lPw + (lr << 7) + ((ks * 64 + lu * 16) ^ ((lr & 7) << 4)));
#pragma unroll
      for (int oc = 0; oc < 8; oc++) {
        const int h = oc * 16 + lr;
        bf16x8 vb = *reinterpret_cast<const bf16x8*>(
            (char*)lV + h * 128 + (((ks * 4 + lu) << 4) ^ ((h & 7) << 4)));
        o[oc] = __builtin_amdgcn_mfma_f32_16x16x32_bf16(pf, vb, o[oc], 0, 0, 0);
      }
    }
    __syncthreads();
  }
  // ---- one cross-lane sum reduce, then write ----
  float rs[4];
#pragma unroll
  for (int r = 0; r < 4; r++) {
    float s = lsum[r];
    s += __shfl_xor(s, 1, 64);
    s += __shfl_xor(s, 2, 64);
    s += __shfl_xor(s, 4, 64);
    s += __shfl_xor(s, 8, 64);
    rs[r] = 1.f / s;
  }
#pragma unroll
  for (int oc = 0; oc < 8; oc++)
#pragma unroll
    for (int r = 0; r < 4; r++) {
      const int t = t_row + r;
      enc[((size_t)b * 2048 + t) * 2048 + n * 128 + oc * 16 + lr] = f2bf(o[oc][r] * rs[r]);
    }
}

extern "C" void kernel_launch(void* const* d_in, const int* in_sizes, int n_in,
                              void* d_out, int out_size, void* d_ws, size_t ws_size,
                              hipStream_t stream) {
  (void)in_sizes; (void)n_in; (void)out_size; (void)ws_size;
  const float* x    = (const float*)d_in[0];
  const float* wq   = (const float*)d_in[3];
  const float* wkv  = (const float*)d_in[4];
  const float* wvec = (const float*)d_in[5];
  char* ws = (char*)d_ws;
  size_t off = 0;
  short* xbf   = (short*)(ws + off); off += (size_t)8388608 * 2;            // x bf16 [B*T][D]
  short* wall  = (short*)(ws + off); off += (size_t)3072 * 2048 * 2;        // [wqT|wkT|wvT] rows x K
  short* wvecT = (short*)(ws + off); off += (size_t)2048 * 2048 * 2;        // [d][nh]
  short* qbuf  = (short*)(ws + off); off += (size_t)2 * 16 * 2048 * 128 * 2; // q bf16 [b][n][t][h]
  short* kvbuf = (short*)(ws + off); off += (size_t)2 * 2 * 4 * 2048 * 128 * 2; // [c][b][kv][t][h]
  short* vTbuf = (short*)(ws + off); off += (size_t)2 * 4 * 128 * 2048 * 2; // [b][kv][h][s]
  short* encb  = (short*)(ws + off); off += (size_t)2 * 2048 * 2048 * 2;    // [b][t][nh]

  k_cvt<<<8192, 256, 0, stream>>>(x, xbf, 2097152);
  k_tr<float><<<dim3(4, 64, 16), 256, 0, stream>>>(wq, wall, 2048, 128);
  k_tr<float><<<dim3(4, 64, 4), 256, 0, stream>>>(wkv, wall + 4194304, 2048, 128);
  k_tr<float><<<dim3(4, 64, 4), 256, 0, stream>>>(wkv + 1048576, wall + 5242880, 2048, 128);
  k_tr<float><<<dim3(64, 64, 1), 256, 0, stream>>>(wvec, wvecT, 2048, 2048);
  k_gemm<<<dim3(32, 24), 256, 0, stream>>>(xbf, wall, qbuf, kvbuf, 4096, 3072, 2048, 0);
  k_rope<<<16384, 256, 0, stream>>>(qbuf, 0.08838834764831845f);  // 1/sqrt(128)
  k_rope<<<4096, 256, 0, stream>>>(kvbuf, 1.0f);
  k_tr<short><<<dim3(4, 64, 8), 256, 0, stream>>>(kvbuf + 2097152, vTbuf, 2048, 128);
  k_attn<<<dim3(32, 32), 256, 0, stream>>>(qbuf, kvbuf, vTbuf, encb);
  k_gemm<<<dim3(32, 16), 256, 0, stream>>>(encb, wvecT, d_out, nullptr, 4096, 2048, 2048, 2);
}

// Round 3
// 232.927 us; speedup vs baseline: 1.3951x; 1.1146x over previous
//
#include <hip/hip_runtime.h>
#include <hip/hip_bf16.h>

#define DEVINL static __device__ __forceinline__

typedef __attribute__((ext_vector_type(4))) float f32x4;
typedef __attribute__((ext_vector_type(8))) short bf16x8;

DEVINL short f2bf(float f) {
  __hip_bfloat16 h = __float2bfloat16(f);
  union { __hip_bfloat16 h; short s; } u; u.h = h; return u.s;
}
DEVINL float bf2f(short s) {
  union { unsigned u; float f; } v; v.u = ((unsigned)(unsigned short)s) << 16;
  return v.f;
}
DEVINL float ldf(float x) { return x; }
DEVINL float ldf(short x) { return bf2f(x); }

// ---------------- f32 -> bf16 convert, 4 elems/thread ----------------
__global__ void k_cvt(const float* __restrict__ in, short* __restrict__ out, int n4) {
  int i = blockIdx.x * blockDim.x + threadIdx.x;
  if (i >= n4) return;
  const float4 v = reinterpret_cast<const float4*>(in)[i];
  short4 o;
  o.x = f2bf(v.x); o.y = f2bf(v.y); o.z = f2bf(v.z); o.w = f2bf(v.w);
  reinterpret_cast<short4*>(out)[i] = o;
}

// ------- batched transpose [batch][R][C] -> [batch][C][R], out bf16 -------
template <typename Tin>
__global__ void k_tr(const Tin* __restrict__ in, short* __restrict__ out, int R, int C) {
  __shared__ float tile[32][33];
  const int bz = blockIdx.z;
  const int r0 = blockIdx.y * 32, c0 = blockIdx.x * 32;
  const int tx = threadIdx.x & 31, ty = threadIdx.x >> 5;  // ty in 0..7
  const Tin* ip = in + (size_t)bz * R * C;
  short* op = out + (size_t)bz * R * C;
#pragma unroll
  for (int k = 0; k < 4; k++)
    tile[ty + k * 8][tx] = ldf(ip[(size_t)(r0 + ty + k * 8) * C + c0 + tx]);
  __syncthreads();
#pragma unroll
  for (int k = 0; k < 4; k++)
    op[(size_t)(c0 + ty + k * 8) * R + r0 + tx] = f2bf(tile[tx][ty + k * 8]);
}

// ---------------- bf16 MFMA GEMM: C[M][N] = A[M][K] * Bt[N][K]^T ----------------
// mode 0: fused q/kv projection epilogue (bf16, head-major scatter)
// mode 2: f32 row-major into Out0
__global__ __launch_bounds__(256) void k_gemm(
    const short* __restrict__ A, const short* __restrict__ Bt,
    void* __restrict__ Out0, void* __restrict__ Out1,
    int M, int N, int K, int mode) {
  __shared__ __align__(16) short lA[128 * 32];
  __shared__ __align__(16) short lB[128 * 32];
  const int m0 = blockIdx.x * 128, n0 = blockIdx.y * 128;
  const int tid = threadIdx.x, lane = tid & 63, w = tid >> 6;
  const int wr = w >> 1, wc = w & 1;
  const int lr = lane & 15, lk = (lane >> 4) * 8;
  f32x4 acc[4][4] = {};
  for (int k0 = 0; k0 < K; k0 += 32) {
#pragma unroll
    for (int c = 0; c < 2; c++) {
      const int off = w * 1024 + c * 512 + lane * 8;  // element offset in 4096-elem tile
      const int row = off >> 5, col = off & 31;
      __builtin_amdgcn_global_load_lds(
          (const __attribute__((address_space(1))) void*)(A + (size_t)(m0 + row) * K + k0 + col),
          (__attribute__((address_space(3))) void*)(lA + off), 16, 0, 0);
      __builtin_amdgcn_global_load_lds(
          (const __attribute__((address_space(1))) void*)(Bt + (size_t)(n0 + row) * K + k0 + col),
          (__attribute__((address_space(3))) void*)(lB + off), 16, 0, 0);
    }
    __syncthreads();
    bf16x8 af[4], bfr[4];
#pragma unroll
    for (int i = 0; i < 4; i++)
      af[i] = *reinterpret_cast<const bf16x8*>(lA + (wr * 64 + i * 16 + lr) * 32 + lk);
#pragma unroll
    for (int j = 0; j < 4; j++)
      bfr[j] = *reinterpret_cast<const bf16x8*>(lB + (wc * 64 + j * 16 + lr) * 32 + lk);
#pragma unroll
    for (int i = 0; i < 4; i++)
#pragma unroll
      for (int j = 0; j < 4; j++)
        acc[i][j] = __builtin_amdgcn_mfma_f32_16x16x32_bf16(af[i], bfr[j], acc[i][j], 0, 0, 0);
    __syncthreads();
  }
  const int rg = lane >> 4;
#pragma unroll
  for (int i = 0; i < 4; i++)
#pragma unroll
    for (int j = 0; j < 4; j++)
#pragma unroll
      for (int r = 0; r < 4; r++) {
        const int m = m0 + wr * 64 + i * 16 + rg * 4 + r;
        const int n = n0 + wc * 64 + j * 16 + lr;
        const float v = acc[i][j][r];
        if (mode == 2) {
          ((float*)Out0)[(size_t)m * N + n] = v;
        } else {
          const int b = m >> 11, t = m & 2047;
          if (n < 2048) {  // q: [b][n_head][t][h]
            ((short*)Out0)[(((size_t)(b * 16 + (n >> 7))) << 18) + t * 128 + (n & 127)] = f2bf(v);
          } else {  // kv: [c][b][kv][t][h]
            const int nn = n - 2048;
            ((short*)Out1)[(((size_t)(((nn >> 9) * 2 + b) * 4 + ((nn >> 7) & 3))) << 18) +
                           t * 128 + (nn & 127)] = f2bf(v);
          }
        }
      }
}

// ---------------- in-place RoPE on bf16 [rows][128]; t = row & 2047 ----------------
__global__ void k_rope(short* __restrict__ q, float scale) {
  const int gid = blockIdx.x * blockDim.x + threadIdx.x;
  const int i = gid & 63;
  const int row = gid >> 6;
  const int t = row & 2047;
  short* p = q + (size_t)row * 128;
  const float inv = __expf(-(float)i * (float)(9.210340371976184 / 64.0));  // 10000^{-i/64}
  const float ang = (float)t * inv;
  float sn, cs;
  sincosf(ang, &sn, &cs);
  const float x1 = bf2f(p[i]), x2 = bf2f(p[i + 64]);
  p[i] = f2bf((x1 * cs - x2 * sn) * scale);
  p[i + 64] = f2bf((x2 * cs + x1 * sn) * scale);
}

// ---------------- flash attention, sliding window + tanh soft-cap ----------------
// Soft-cap bounds logits to [-50,50] => fixed-max softmax (max=0):
//   p = exp(50*tanh(sc/50)) = exp(fma(rc,-100,50)), rc = rcp(exp(sc*0.04)+1)
// q: [b][n][t][h] bf16 (roped+scaled); kk: [b][kv][s][h] bf16 (roped);
// vT: [b][kv][h][s] bf16; enc out: [b][t][n*128+h] bf16
__global__ __launch_bounds__(256) void k_attn(
    const short* __restrict__ q, const short* __restrict__ kk,
    const short* __restrict__ vT, short* __restrict__ enc) {
  __shared__ __align__(16) short lK[64 * 128];   // [s][h], byte ^= ((s&7)<<4)
  __shared__ __align__(16) short lV[128 * 64];   // [h][s], byte ^= ((h&7)<<4)
  __shared__ __align__(16) short lP[4][16 * 64]; // per-wave P [t][s], byte ^= ((t&7)<<4)
  const int bn = blockIdx.x, b = bn >> 4, n = bn & 15, kv = n >> 2;
  const int qt0 = (31 - blockIdx.y) * 64;  // heavy blocks dispatched first
  const int tid = threadIdx.x, lane = tid & 63, w = tid >> 6;
  const int lr = lane & 15, lu = lane >> 4;
  const short* qbase = q + (((size_t)(b * 16 + n)) << 18) + (size_t)(qt0 + w * 16) * 128;
  bf16x8 qa[4];
#pragma unroll
  for (int c = 0; c < 4; c++)
    qa[c] = *reinterpret_cast<const bf16x8*>(qbase + lr * 128 + c * 32 + lu * 8);
  f32x4 o[8] = {};
  float lsum[4] = {0.f, 0.f, 0.f, 0.f};
  const short* kbase = kk + (((size_t)(b * 4 + kv)) << 18);
  const short* vbase = vT + (((size_t)(b * 4 + kv)) << 18);
  char* lPw = (char*)lP[w];
  const int tw = qt0 + w * 16;
  const int t_row = tw + lu * 4;
  int st0 = qt0 - 1023; if (st0 < 0) st0 = 0;
  st0 >>= 6;
  const int stE = (qt0 + 63) >> 6;
  for (int st = st0; st <= stE; st++) {
    const int s0 = st << 6;
#pragma unroll
    for (int c = 0; c < 4; c++) {
      const int L = w * 4096 + c * 1024 + lane * 16;  // byte offset in 16 KiB tile
      {  // K tile: linear LDS dest, pre-swizzled global source
        const int s = L >> 8, slot = (L >> 4) & 15;
        const int sp = slot ^ (s & 7);
        __builtin_amdgcn_global_load_lds(
            (const __attribute__((address_space(1))) void*)(kbase + (size_t)(s0 + s) * 128 + sp * 8),
            (__attribute__((address_space(3))) void*)((char*)lK + L), 16, 0, 0);
      }
      {  // V tile
        const int h = L >> 7, slot = (L >> 4) & 7;
        const int u = slot ^ (h & 7);
        __builtin_amdgcn_global_load_lds(
            (const __attribute__((address_space(1))) void*)(vbase + (size_t)h * 2048 + s0 + u * 8),
            (__attribute__((address_space(3))) void*)((char*)lV + L), 16, 0, 0);
      }
    }
    __syncthreads();
    // ---- QK^T: sc[cg] = D[t=lu*4+r][s=cg*16+lr] ----
    f32x4 sc[4];
    __builtin_amdgcn_s_setprio(1);
#pragma unroll
    for (int cg = 0; cg < 4; cg++) {
      sc[cg] = (f32x4){0.f, 0.f, 0.f, 0.f};
      const int s = cg * 16 + lr;
      const int sw = (s & 7) << 4;
#pragma unroll
      for (int c = 0; c < 4; c++) {
        bf16x8 kb = *reinterpret_cast<const bf16x8*>((char*)lK + s * 256 + (((c * 4 + lu) << 4) ^ sw));
        sc[cg] = __builtin_amdgcn_mfma_f32_16x16x32_bf16(qa[c], kb, sc[cg], 0, 0, 0);
      }
    }
    __builtin_amdgcn_s_setprio(0);
    // ---- soft-cap + exp (fixed max), write P to swizzled LDS ----
    // all-valid iff s0+63 <= tw  AND  s0 >= tw+15-1023
    const bool allv = (s0 + 63 <= tw) && (s0 + 1008 >= tw);
    if (allv) {
#pragma unroll
      for (int cg = 0; cg < 4; cg++)
#pragma unroll
        for (int r = 0; r < 4; r++) {
          const float rc = __builtin_amdgcn_rcpf(__expf(sc[cg][r] * 0.04f) + 1.f);
          const float p = __expf(__builtin_fmaf(rc, -100.f, 50.f));
          lsum[r] += p;
          const int row = lu * 4 + r;
          *(short*)(lPw + (row << 7) + ((((cg * 16 + lr) << 1)) ^ ((row & 7) << 4))) = f2bf(p);
        }
    } else {
#pragma unroll
      for (int cg = 0; cg < 4; cg++) {
        const int s = s0 + cg * 16 + lr;
#pragma unroll
        for (int r = 0; r < 4; r++) {
          const int t = t_row + r;
          const bool valid = (s <= t) & (s + 1024 > t);
          const float rc = __builtin_amdgcn_rcpf(__expf(sc[cg][r] * 0.04f) + 1.f);
          float p = __expf(__builtin_fmaf(rc, -100.f, 50.f));
          p = valid ? p : 0.f;
          lsum[r] += p;
          const int row = lu * 4 + r;
          *(short*)(lPw + (row << 7) + ((((cg * 16 + lr) << 1)) ^ ((row & 7) << 4))) = f2bf(p);
        }
      }
    }
    // ---- PV: o[oc] += P[t][s] * V[s][h] ----
#pragma unroll
    for (int ks = 0; ks < 2; ks++) {
      const bf16x8 pf = *reinterpret_cast<const bf16x8*>(
          lPw + (lr << 7) + ((ks * 64 + lu * 16) ^ ((lr & 7) << 4)));
      __builtin_amdgcn_s_setprio(1);
#pragma unroll
      for (int oc = 0; oc < 8; oc++) {
        const int h = oc * 16 + lr;
        bf16x8 vb = *reinterpret_cast<const bf16x8*>(
            (char*)lV + h * 128 + (((ks * 4 + lu) << 4) ^ ((h & 7) << 4)));
        o[oc] = __builtin_amdgcn_mfma_f32_16x16x32_bf16(pf, vb, o[oc], 0, 0, 0);
      }
      __builtin_amdgcn_s_setprio(0);
    }
    __syncthreads();
  }
  // ---- one cross-lane sum reduce, then write ----
  float rs[4];
#pragma unroll
  for (int r = 0; r < 4; r++) {
    float s = lsum[r];
    s += __shfl_xor(s, 1, 64);
    s += __shfl_xor(s, 2, 64);
    s += __shfl_xor(s, 4, 64);
    s += __shfl_xor(s, 8, 64);
    rs[r] = 1.f / s;
  }
#pragma unroll
  for (int oc = 0; oc < 8; oc++)
#pragma unroll
    for (int r = 0; r < 4; r++) {
      const int t = t_row + r;
      enc[((size_t)b * 2048 + t) * 2048 + n * 128 + oc * 16 + lr] = f2bf(o[oc][r] * rs[r]);
    }
}

extern "C" void kernel_launch(void* const* d_in, const int* in_sizes, int n_in,
                              void* d_out, int out_size, void* d_ws, size_t ws_size,
                              hipStream_t stream) {
  (void)in_sizes; (void)n_in; (void)out_size; (void)ws_size;
  const float* x    = (const float*)d_in[0];
  const float* wq   = (const float*)d_in[3];
  const float* wkv  = (const float*)d_in[4];
  const float* wvec = (const float*)d_in[5];
  char* ws = (char*)d_ws;
  size_t off = 0;
  short* xbf   = (short*)(ws + off); off += (size_t)8388608 * 2;            // x bf16 [B*T][D]
  short* wall  = (short*)(ws + off); off += (size_t)3072 * 2048 * 2;        // [wqT|wkT|wvT] rows x K
  short* wvecT = (short*)(ws + off); off += (size_t)2048 * 2048 * 2;        // [d][nh]
  short* qbuf  = (short*)(ws + off); off += (size_t)2 * 16 * 2048 * 128 * 2; // q bf16 [b][n][t][h]
  short* kvbuf = (short*)(ws + off); off += (size_t)2 * 2 * 4 * 2048 * 128 * 2; // [c][b][kv][t][h]
  short* vTbuf = (short*)(ws + off); off += (size_t)2 * 4 * 128 * 2048 * 2; // [b][kv][h][s]
  short* encb  = (short*)(ws + off); off += (size_t)2 * 2048 * 2048 * 2;    // [b][t][nh]

  k_cvt<<<8192, 256, 0, stream>>>(x, xbf, 2097152);
  k_tr<float><<<dim3(4, 64, 16), 256, 0, stream>>>(wq, wall, 2048, 128);
  k_tr<float><<<dim3(4, 64, 4), 256, 0, stream>>>(wkv, wall + 4194304, 2048, 128);
  k_tr<float><<<dim3(4, 64, 4), 256, 0, stream>>>(wkv + 1048576, wall + 5242880, 2048, 128);
  k_tr<float><<<dim3(64, 64, 1), 256, 0, stream>>>(wvec, wvecT, 2048, 2048);
  k_gemm<<<dim3(32, 24), 256, 0, stream>>>(xbf, wall, qbuf, kvbuf, 4096, 3072, 2048, 0);
  k_rope<<<16384, 256, 0, stream>>>(qbuf, 0.08838834764831845f);  // 1/sqrt(128)
  k_rope<<<4096, 256, 0, stream>>>(kvbuf, 1.0f);
  k_tr<short><<<dim3(4, 64, 8), 256, 0, stream>>>(kvbuf + 2097152, vTbuf, 2048, 128);
  k_attn<<<dim3(32, 32), 256, 0, stream>>>(qbuf, kvbuf, vTbuf, encb);
  k_gemm<<<dim3(32, 16), 256, 0, stream>>>(encb, wvecT, d_out, nullptr, 4096, 2048, 2048, 2);
}

// Round 4
// 218.630 us; speedup vs baseline: 1.4863x; 1.0654x over previous
//
#include <hip/hip_runtime.h>
#include <hip/hip_bf16.h>

#define DEVINL static __device__ __forceinline__

typedef __attribute__((ext_vector_type(4))) float f32x4;
typedef __attribute__((ext_vector_type(8))) short bf16x8;

DEVINL short f2bf(float f) {
  __hip_bfloat16 h = __float2bfloat16(f);
  union { __hip_bfloat16 h; short s; } u; u.h = h; return u.s;
}
DEVINL float bf2f(short s) {
  union { unsigned u; float f; } v; v.u = ((unsigned)(unsigned short)s) << 16;
  return v.f;
}
DEVINL float ldf(float x) { return x; }
DEVINL float ldf(short x) { return bf2f(x); }

// ---------------- f32 -> bf16 convert, 4 elems/thread ----------------
__global__ void k_cvt(const float* __restrict__ in, short* __restrict__ out, int n4) {
  int i = blockIdx.x * blockDim.x + threadIdx.x;
  if (i >= n4) return;
  const float4 v = reinterpret_cast<const float4*>(in)[i];
  short4 o;
  o.x = f2bf(v.x); o.y = f2bf(v.y); o.z = f2bf(v.z); o.w = f2bf(v.w);
  reinterpret_cast<short4*>(out)[i] = o;
}

// ------- batched transpose [batch][R][C] -> [batch][C][R], out bf16 -------
template <typename Tin>
__global__ void k_tr(const Tin* __restrict__ in, short* __restrict__ out, int R, int C) {
  __shared__ float tile[32][33];
  const int bz = blockIdx.z;
  const int r0 = blockIdx.y * 32, c0 = blockIdx.x * 32;
  const int tx = threadIdx.x & 31, ty = threadIdx.x >> 5;  // ty in 0..7
  const Tin* ip = in + (size_t)bz * R * C;
  short* op = out + (size_t)bz * R * C;
#pragma unroll
  for (int k = 0; k < 4; k++)
    tile[ty + k * 8][tx] = ldf(ip[(size_t)(r0 + ty + k * 8) * C + c0 + tx]);
  __syncthreads();
#pragma unroll
  for (int k = 0; k < 4; k++)
    op[(size_t)(c0 + ty + k * 8) * R + r0 + tx] = f2bf(tile[tx][ty + k * 8]);
}

// =================== 256x256xK 8-phase MFMA GEMM (T2+T3+T4+T5) ===================
// C[M][N] = A[M][K] * Bt[N][K]^T ; 512 threads, 8 waves (2M x 4N, 16-stripe interleave)
// LDS 128KB dynamic: A0|A1|B0|B1, each [256][64] bf16, granule-XOR swizzled.
// mode 0: QKV scatter epilogue (bf16); mode 2: f32 row-major.

#define GBAR __builtin_amdgcn_s_barrier()
#define FEN asm volatile("" ::: "memory")
#define LGK { asm volatile("s_waitcnt lgkmcnt(0)"); __builtin_amdgcn_sched_barrier(0); }
#define VM4 asm volatile("s_waitcnt vmcnt(4)")
#define PR1 __builtin_amdgcn_s_setprio(1)
#define PR0 __builtin_amdgcn_s_setprio(0)

// stage one 16KB half-tile (128 rows x 64 cols bf16): 2 x global_load_lds(16B)/thread
#define STG(DST, HALF, SRC, KT)                                                        \
  { _Pragma("unroll")                                                                  \
    for (int L_ = 0; L_ < 2; L_++) {                                                   \
      const int loc_ = L_ * 8192 + tid * 16;                                           \
      const int row_ = loc_ >> 7;                                                      \
      const int gsw_ = ((loc_ >> 4) & 7) ^ (row_ & 7);                                 \
      __builtin_amdgcn_global_load_lds(                                                \
          (const __attribute__((address_space(1))) void*)(                             \
              (SRC) + (size_t)((HALF) * 128 + row_) * K + (KT) * 64 + gsw_ * 8),       \
          (__attribute__((address_space(3))) void*)((DST) + (HALF) * 16384 + loc_),    \
          16, 0, 0);                                                                   \
    } }

#define RDA(BUF, IH)                                                                   \
  { _Pragma("unroll")                                                                  \
    for (int kf_ = 0; kf_ < 4; kf_++) {                                                \
      _Pragma("unroll")                                                                \
      for (int kk_ = 0; kk_ < 2; kk_++) {                                              \
        const int row_ = ((IH) * 4 + kf_) * 32 + wr * 16 + lr;                         \
        a[kf_ * 2 + kk_] = *(const bf16x8*)((BUF) + row_ * 128 +                       \
                                            (((kk_ * 4 + lu) ^ (lr & 7)) << 4));       \
      } } }

#define RDB(BUF, JH)                                                                   \
  { _Pragma("unroll")                                                                  \
    for (int jf_ = 0; jf_ < 2; jf_++) {                                                \
      _Pragma("unroll")                                                                \
      for (int kk_ = 0; kk_ < 2; kk_++) {                                              \
        const int row_ = ((JH) * 2 + jf_) * 64 + wc * 16 + lr;                         \
        b[jf_ * 2 + kk_] = *(const bf16x8*)((BUF) + row_ * 128 +                       \
                                            (((kk_ * 4 + lu) ^ (lr & 7)) << 4));       \
      } } }

#define MF(IH, JH)                                                                     \
  { _Pragma("unroll")                                                                  \
    for (int kf_ = 0; kf_ < 4; kf_++)                                                  \
      { _Pragma("unroll")                                                              \
        for (int jf_ = 0; jf_ < 2; jf_++)                                              \
          { _Pragma("unroll")                                                          \
            for (int kk_ = 0; kk_ < 2; kk_++)                                          \
              acc[(IH) * 4 + kf_][(JH) * 2 + jf_] =                                    \
                  __builtin_amdgcn_mfma_f32_16x16x32_bf16(                             \
                      a[kf_ * 2 + kk_], b[jf_ * 2 + kk_],                              \
                      acc[(IH) * 4 + kf_][(JH) * 2 + jf_], 0, 0, 0);                   \
          } } }

__global__ __launch_bounds__(512, 2) void k_gemm256(
    const short* __restrict__ A, const short* __restrict__ Bt,
    void* __restrict__ Out0, void* __restrict__ Out1,
    int N, int K, int mode) {
  extern __shared__ __align__(16) char sm[];
  char* A0 = sm;
  char* A1 = sm + 32768;
  char* B0 = sm + 65536;
  char* B1 = sm + 98304;
  const int m0 = blockIdx.x * 256, n0 = blockIdx.y * 256;
  const int tid = threadIdx.x, lane = tid & 63, w = tid >> 6;
  const int wr = w & 1, wc = w >> 1;  // 2M x 4N waves, 16-row/16-col stripes
  const int lr = lane & 15, lu = lane >> 4;
  const short* Am = A + (size_t)m0 * K;
  const short* Bn = Bt + (size_t)n0 * K;
  f32x4 acc[8][4] = {};
  bf16x8 a[8], b[4];
  const int NIT = K >> 7;       // iterations of 2 K-tiles (BK=64)
  const int TMAX = (K >> 6) - 1;

  // prologue: t0 full + t1.{Ah0,Bh1}; wait t0 landed (leave t1's 4 loads)
  STG(A0, 0, Am, 0); STG(B0, 1, Bn, 0); STG(A0, 1, Am, 0); STG(B0, 0, Bn, 0);
  STG(A1, 0, Am, 1); STG(B1, 1, Bn, 1);
  VM4; FEN; GBAR;

  for (int it = 0; it < NIT; ++it) {
    const int t1 = 2 * it + 1;
    const int t2 = (2 * it + 2 < TMAX) ? 2 * it + 2 : TMAX;
    const int t3 = (2 * it + 3 < TMAX) ? 2 * it + 3 : TMAX;
    // Ph0: quadrant (0,0) of even tile
    RDA(A0, 0); RDB(B0, 0); STG(A1, 1, Am, t1);
    FEN; GBAR; LGK; PR1; MF(0, 0); PR0; FEN; GBAR;
    // Ph1: (0,1)
    RDB(B0, 1); STG(B1, 0, Bn, t1);
    FEN; GBAR; LGK; PR1; MF(0, 1); PR0; FEN; GBAR;
    // Ph2: (1,1)
    RDA(A0, 1); STG(A0, 0, Am, t2);
    FEN; GBAR; LGK; PR1; MF(1, 1); PR0; FEN; GBAR;
    // Ph3: (1,0)  [odd-tile buffers complete after this wait]
    RDB(B0, 0); STG(B0, 1, Bn, t2);
    FEN; GBAR; LGK; PR1; MF(1, 0); PR0; VM4; FEN; GBAR;
    // Ph4: (0,0) of odd tile
    RDA(A1, 0); RDB(B1, 0); STG(A0, 1, Am, t2);
    FEN; GBAR; LGK; PR1; MF(0, 0); PR0; FEN; GBAR;
    // Ph5: (0,1)
    RDB(B1, 1); STG(B0, 0, Bn, t2);
    FEN; GBAR; LGK; PR1; MF(0, 1); PR0; FEN; GBAR;
    // Ph6: (1,1)
    RDA(A1, 1); STG(A1, 0, Am, t3);
    FEN; GBAR; LGK; PR1; MF(1, 1); PR0; FEN; GBAR;
    // Ph7: (1,0)  [even-tile buffers complete after this wait]
    RDB(B1, 0); STG(B1, 1, Bn, t3);
    FEN; GBAR; LGK; PR1; MF(1, 0); PR0; VM4; FEN; GBAR;
  }

  // epilogue
#pragma unroll
  for (int k = 0; k < 8; k++)
#pragma unroll
    for (int j = 0; j < 4; j++)
#pragma unroll
      for (int r = 0; r < 4; r++) {
        const int m = m0 + k * 32 + wr * 16 + lu * 4 + r;
        const int n = n0 + j * 64 + wc * 16 + lr;
        const float v = acc[k][j][r];
        if (mode == 2) {
          ((float*)Out0)[(size_t)m * N + n] = v;
        } else {
          const int bb = m >> 11, t = m & 2047;
          if (n < 2048) {  // q: [b][head][t][h]
            ((short*)Out0)[(((size_t)(bb * 16 + (n >> 7))) << 18) + t * 128 + (n & 127)] = f2bf(v);
          } else {  // kv: [c][b][kv][t][h]
            const int nn = n - 2048;
            ((short*)Out1)[(((size_t)(((nn >> 9) * 2 + bb) * 4 + ((nn >> 7) & 3))) << 18) +
                           t * 128 + (nn & 127)] = f2bf(v);
          }
        }
      }
}

// ---------------- in-place RoPE on bf16 [rows][128]; t = row & 2047 ----------------
__global__ void k_rope(short* __restrict__ q, float scale) {
  const int gid = blockIdx.x * blockDim.x + threadIdx.x;
  const int i = gid & 63;
  const int row = gid >> 6;
  const int t = row & 2047;
  short* p = q + (size_t)row * 128;
  const float inv = __expf(-(float)i * (float)(9.210340371976184 / 64.0));  // 10000^{-i/64}
  const float ang = (float)t * inv;
  float sn, cs;
  sincosf(ang, &sn, &cs);
  const float x1 = bf2f(p[i]), x2 = bf2f(p[i + 64]);
  p[i] = f2bf((x1 * cs - x2 * sn) * scale);
  p[i + 64] = f2bf((x2 * cs + x1 * sn) * scale);
}

// ---------------- flash attention, sliding window + tanh soft-cap ----------------
__global__ __launch_bounds__(256) void k_attn(
    const short* __restrict__ q, const short* __restrict__ kk,
    const short* __restrict__ vT, short* __restrict__ enc) {
  __shared__ __align__(16) short lK[64 * 128];   // [s][h], byte ^= ((s&7)<<4)
  __shared__ __align__(16) short lV[128 * 64];   // [h][s], byte ^= ((h&7)<<4)
  __shared__ __align__(16) short lP[4][16 * 64]; // per-wave P [t][s], byte ^= ((t&7)<<4)
  const int bn = blockIdx.x, b = bn >> 4, n = bn & 15, kv = n >> 2;
  const int qt0 = (31 - blockIdx.y) * 64;  // heavy blocks dispatched first
  const int tid = threadIdx.x, lane = tid & 63, w = tid >> 6;
  const int lr = lane & 15, lu = lane >> 4;
  const short* qbase = q + (((size_t)(b * 16 + n)) << 18) + (size_t)(qt0 + w * 16) * 128;
  bf16x8 qa[4];
#pragma unroll
  for (int c = 0; c < 4; c++)
    qa[c] = *reinterpret_cast<const bf16x8*>(qbase + lr * 128 + c * 32 + lu * 8);
  f32x4 o[8] = {};
  float lsum[4] = {0.f, 0.f, 0.f, 0.f};
  const short* kbase = kk + (((size_t)(b * 4 + kv)) << 18);
  const short* vbase = vT + (((size_t)(b * 4 + kv)) << 18);
  char* lPw = (char*)lP[w];
  const int tw = qt0 + w * 16;
  const int t_row = tw + lu * 4;
  int st0 = qt0 - 1023; if (st0 < 0) st0 = 0;
  st0 >>= 6;
  const int stE = (qt0 + 63) >> 6;
  for (int st = st0; st <= stE; st++) {
    const int s0 = st << 6;
#pragma unroll
    for (int c = 0; c < 4; c++) {
      const int L = w * 4096 + c * 1024 + lane * 16;  // byte offset in 16 KiB tile
      {  // K tile: linear LDS dest, pre-swizzled global source
        const int s = L >> 8, slot = (L >> 4) & 15;
        const int sp = slot ^ (s & 7);
        __builtin_amdgcn_global_load_lds(
            (const __attribute__((address_space(1))) void*)(kbase + (size_t)(s0 + s) * 128 + sp * 8),
            (__attribute__((address_space(3))) void*)((char*)lK + L), 16, 0, 0);
      }
      {  // V tile
        const int h = L >> 7, slot = (L >> 4) & 7;
        const int u = slot ^ (h & 7);
        __builtin_amdgcn_global_load_lds(
            (const __attribute__((address_space(1))) void*)(vbase + (size_t)h * 2048 + s0 + u * 8),
            (__attribute__((address_space(3))) void*)((char*)lV + L), 16, 0, 0);
      }
    }
    __syncthreads();
    // ---- QK^T ----
    f32x4 sc[4];
    __builtin_amdgcn_s_setprio(1);
#pragma unroll
    for (int cg = 0; cg < 4; cg++) {
      sc[cg] = (f32x4){0.f, 0.f, 0.f, 0.f};
      const int s = cg * 16 + lr;
      const int sw = (s & 7) << 4;
#pragma unroll
      for (int c = 0; c < 4; c++) {
        bf16x8 kb = *reinterpret_cast<const bf16x8*>((char*)lK + s * 256 + (((c * 4 + lu) << 4) ^ sw));
        sc[cg] = __builtin_amdgcn_mfma_f32_16x16x32_bf16(qa[c], kb, sc[cg], 0, 0, 0);
      }
    }
    __builtin_amdgcn_s_setprio(0);
    // ---- soft-cap + exp (fixed max), write P to swizzled LDS ----
    const bool allv = (s0 + 63 <= tw) && (s0 + 1008 >= tw);
    if (allv) {
#pragma unroll
      for (int cg = 0; cg < 4; cg++)
#pragma unroll
        for (int r = 0; r < 4; r++) {
          const float rc = __builtin_amdgcn_rcpf(__expf(sc[cg][r] * 0.04f) + 1.f);
          const float p = __expf(__builtin_fmaf(rc, -100.f, 50.f));
          lsum[r] += p;
          const int row = lu * 4 + r;
          *(short*)(lPw + (row << 7) + ((((cg * 16 + lr) << 1)) ^ ((row & 7) << 4))) = f2bf(p);
        }
    } else {
#pragma unroll
      for (int cg = 0; cg < 4; cg++) {
        const int s = s0 + cg * 16 + lr;
#pragma unroll
        for (int r = 0; r < 4; r++) {
          const int t = t_row + r;
          const bool valid = (s <= t) & (s + 1024 > t);
          const float rc = __builtin_amdgcn_rcpf(__expf(sc[cg][r] * 0.04f) + 1.f);
          float p = __expf(__builtin_fmaf(rc, -100.f, 50.f));
          p = valid ? p : 0.f;
          lsum[r] += p;
          const int row = lu * 4 + r;
          *(short*)(lPw + (row << 7) + ((((cg * 16 + lr) << 1)) ^ ((row & 7) << 4))) = f2bf(p);
        }
      }
    }
    // ---- PV ----
#pragma unroll
    for (int ks = 0; ks < 2; ks++) {
      const bf16x8 pf = *reinterpret_cast<const bf16x8*>(
          lPw + (lr << 7) + ((ks * 64 + lu * 16) ^ ((lr & 7) << 4)));
      __builtin_amdgcn_s_setprio(1);
#pragma unroll
      for (int oc = 0; oc < 8; oc++) {
        const int h = oc * 16 + lr;
        bf16x8 vb = *reinterpret_cast<const bf16x8*>(
            (char*)lV + h * 128 + (((ks * 4 + lu) << 4) ^ ((h & 7) << 4)));
        o[oc] = __builtin_amdgcn_mfma_f32_16x16x32_bf16(pf, vb, o[oc], 0, 0, 0);
      }
      __builtin_amdgcn_s_setprio(0);
    }
    __syncthreads();
  }
  float rs[4];
#pragma unroll
  for (int r = 0; r < 4; r++) {
    float s = lsum[r];
    s += __shfl_xor(s, 1, 64);
    s += __shfl_xor(s, 2, 64);
    s += __shfl_xor(s, 4, 64);
    s += __shfl_xor(s, 8, 64);
    rs[r] = 1.f / s;
  }
#pragma unroll
  for (int oc = 0; oc < 8; oc++)
#pragma unroll
    for (int r = 0; r < 4; r++) {
      const int t = t_row + r;
      enc[((size_t)b * 2048 + t) * 2048 + n * 128 + oc * 16 + lr] = f2bf(o[oc][r] * rs[r]);
    }
}

extern "C" void kernel_launch(void* const* d_in, const int* in_sizes, int n_in,
                              void* d_out, int out_size, void* d_ws, size_t ws_size,
                              hipStream_t stream) {
  (void)in_sizes; (void)n_in; (void)out_size; (void)ws_size;
  const float* x    = (const float*)d_in[0];
  const float* wq   = (const float*)d_in[3];
  const float* wkv  = (const float*)d_in[4];
  const float* wvec = (const float*)d_in[5];
  char* ws = (char*)d_ws;
  size_t off = 0;
  short* xbf   = (short*)(ws + off); off += (size_t)8388608 * 2;            // x bf16 [B*T][D]
  short* wall  = (short*)(ws + off); off += (size_t)3072 * 2048 * 2;        // [wqT|wkT|wvT] rows x K
  short* wvecT = (short*)(ws + off); off += (size_t)2048 * 2048 * 2;        // [d][nh]
  short* qbuf  = (short*)(ws + off); off += (size_t)2 * 16 * 2048 * 128 * 2; // q bf16 [b][n][t][h]
  short* kvbuf = (short*)(ws + off); off += (size_t)2 * 2 * 4 * 2048 * 128 * 2; // [c][b][kv][t][h]
  short* vTbuf = (short*)(ws + off); off += (size_t)2 * 4 * 128 * 2048 * 2; // [b][kv][h][s]
  short* encb  = (short*)(ws + off); off += (size_t)2 * 2048 * 2048 * 2;    // [b][t][nh]

  hipFuncSetAttribute(reinterpret_cast<const void*>(k_gemm256),
                      hipFuncAttributeMaxDynamicSharedMemorySize, 131072);

  k_cvt<<<8192, 256, 0, stream>>>(x, xbf, 2097152);
  k_tr<float><<<dim3(4, 64, 16), 256, 0, stream>>>(wq, wall, 2048, 128);
  k_tr<float><<<dim3(4, 64, 4), 256, 0, stream>>>(wkv, wall + 4194304, 2048, 128);
  k_tr<float><<<dim3(4, 64, 4), 256, 0, stream>>>(wkv + 1048576, wall + 5242880, 2048, 128);
  k_tr<float><<<dim3(64, 64, 1), 256, 0, stream>>>(wvec, wvecT, 2048, 2048);
  k_gemm256<<<dim3(16, 12), 512, 131072, stream>>>(xbf, wall, qbuf, kvbuf, 3072, 2048, 0);
  k_rope<<<16384, 256, 0, stream>>>(qbuf, 0.08838834764831845f);  // 1/sqrt(128)
  k_rope<<<4096, 256, 0, stream>>>(kvbuf, 1.0f);
  k_tr<short><<<dim3(4, 64, 8), 256, 0, stream>>>(kvbuf + 2097152, vTbuf, 2048, 128);
  k_attn<<<dim3(32, 32), 256, 0, stream>>>(qbuf, kvbuf, vTbuf, encb);
  k_gemm256<<<dim3(16, 8), 512, 131072, stream>>>(encb, wvecT, d_out, nullptr, 2048, 2048, 2);
}

// Round 5
// 215.401 us; speedup vs baseline: 1.5086x; 1.0150x over previous
//
#include <hip/hip_runtime.h>
#include <hip/hip_bf16.h>

#define DEVINL static __device__ __forceinline__

typedef __attribute__((ext_vector_type(4))) float f32x4;
typedef __attribute__((ext_vector_type(8))) short bf16x8;

DEVINL short f2bf(float f) {
  __hip_bfloat16 h = __float2bfloat16(f);
  union { __hip_bfloat16 h; short s; } u; u.h = h; return u.s;
}
DEVINL float bf2f(short s) {
  union { unsigned u; float f; } v; v.u = ((unsigned)(unsigned short)s) << 16;
  return v.f;
}
DEVINL float ldf(float x) { return x; }
DEVINL float ldf(short x) { return bf2f(x); }

// ---------------- f32 -> bf16 convert, 4 elems/thread ----------------
__global__ void k_cvt(const float* __restrict__ in, short* __restrict__ out, int n4) {
  int i = blockIdx.x * blockDim.x + threadIdx.x;
  if (i >= n4) return;
  const float4 v = reinterpret_cast<const float4*>(in)[i];
  short4 o;
  o.x = f2bf(v.x); o.y = f2bf(v.y); o.z = f2bf(v.z); o.w = f2bf(v.w);
  reinterpret_cast<short4*>(out)[i] = o;
}

// ------- batched transpose [batch][R][C] -> [batch][C][R], out bf16 -------
template <typename Tin>
__global__ void k_tr(const Tin* __restrict__ in, short* __restrict__ out, int R, int C) {
  __shared__ float tile[32][33];
  const int bz = blockIdx.z;
  const int r0 = blockIdx.y * 32, c0 = blockIdx.x * 32;
  const int tx = threadIdx.x & 31, ty = threadIdx.x >> 5;  // ty in 0..7
  const Tin* ip = in + (size_t)bz * R * C;
  short* op = out + (size_t)bz * R * C;
#pragma unroll
  for (int k = 0; k < 4; k++)
    tile[ty + k * 8][tx] = ldf(ip[(size_t)(r0 + ty + k * 8) * C + c0 + tx]);
  __syncthreads();
#pragma unroll
  for (int k = 0; k < 4; k++)
    op[(size_t)(c0 + ty + k * 8) * R + r0 + tx] = f2bf(tile[tx][ty + k * 8]);
}

// =================== BMx256xK 8-phase MFMA GEMM (T2+T3+T4+T5) ===================
// C[M][N] = A[M][K] * Bt[N][K]^T ; 512 threads, 8 waves (2M x 4N, 16-stripe interleave)
// LDS dynamic: A0|A1|B0|B1; A buf = BM*128 B, B buf = 32 KB; granule-XOR swizzled.
// One barrier per phase; compiler-scheduled lgkm waits (C++ ds_reads are visible).
// mode 0: QKV scatter epilogue (q bf16 / k bf16 / v transposed bf16); mode 2: f32.

#define FEN asm volatile("" ::: "memory")
#define BARR { FEN; __builtin_amdgcn_s_barrier(); FEN; }
#define PR1 __builtin_amdgcn_s_setprio(1)
#define PR0 __builtin_amdgcn_s_setprio(0)
#define VMW { if constexpr (LPA == 2) asm volatile("s_waitcnt vmcnt(4)"); \
              else asm volatile("s_waitcnt vmcnt(3)"); }

// stage one half-tile: LN x global_load_lds(16B)/thread; LDS linear, src pre-swizzled
template <int LN>
DEVINL void stage(char* dst, const short* src, int K, int tid) {
#pragma unroll
  for (int L = 0; L < LN; L++) {
    const int loc = L * 8192 + tid * 16;
    const int row = loc >> 7;
    const int gsw = ((loc >> 4) & 7) ^ (row & 7);
    __builtin_amdgcn_global_load_lds(
        (const __attribute__((address_space(1))) void*)(src + (size_t)row * K + gsw * 8),
        (__attribute__((address_space(3))) void*)(dst + loc), 16, 0, 0);
  }
}

#define SA(BUF, HALF, KT) \
  stage<LPA>((BUF) + (HALF) * (ABY / 2), Am + (size_t)((HALF) * (BM / 2)) * K + (KT) * 64, K, tid)
#define SB(BUF, HALF, KT) \
  stage<2>((BUF) + (HALF) * 16384, Bn + (size_t)((HALF) * 128) * K + (KT) * 64, K, tid)

#define RDA(BUF, IH)                                                                   \
  { _Pragma("unroll")                                                                  \
    for (int kf_ = 0; kf_ < KFN; kf_++) {                                              \
      _Pragma("unroll")                                                                \
      for (int kk_ = 0; kk_ < 2; kk_++) {                                              \
        const int row_ = ((IH) * KFN + kf_) * 32 + wr * 16 + lr;                       \
        a[kf_ * 2 + kk_] = *(const bf16x8*)((BUF) + row_ * 128 +                       \
                                            (((kk_ * 4 + lu) ^ (lr & 7)) << 4));       \
      } } }

#define RDB(BUF, JH)                                                                   \
  { _Pragma("unroll")                                                                  \
    for (int jf_ = 0; jf_ < 2; jf_++) {                                                \
      _Pragma("unroll")                                                                \
      for (int kk_ = 0; kk_ < 2; kk_++) {                                              \
        const int row_ = ((JH) * 2 + jf_) * 64 + wc * 16 + lr;                         \
        b[jf_ * 2 + kk_] = *(const bf16x8*)((BUF) + row_ * 128 +                       \
                                            (((kk_ * 4 + lu) ^ (lr & 7)) << 4));       \
      } } }

#define MF(IH, JH)                                                                     \
  { _Pragma("unroll")                                                                  \
    for (int kf_ = 0; kf_ < KFN; kf_++)                                                \
      { _Pragma("unroll")                                                              \
        for (int jf_ = 0; jf_ < 2; jf_++)                                              \
          { _Pragma("unroll")                                                          \
            for (int kk_ = 0; kk_ < 2; kk_++)                                          \
              acc[(IH) * KFN + kf_][(JH) * 2 + jf_] =                                  \
                  __builtin_amdgcn_mfma_f32_16x16x32_bf16(                             \
                      a[kf_ * 2 + kk_], b[jf_ * 2 + kk_],                              \
                      acc[(IH) * KFN + kf_][(JH) * 2 + jf_], 0, 0, 0);                 \
          } } }

template <int BM>
__global__ __launch_bounds__(512, 2) void k_gemm256(
    const short* __restrict__ A, const short* __restrict__ Bt,
    void* __restrict__ Out0, void* __restrict__ Out1, void* __restrict__ Out2,
    int N, int K, int mode) {
  constexpr int LPA = BM / 128;   // loads/thread per A half-tile
  constexpr int KFN = BM / 64;    // 32-row groups per M-half
  constexpr int ABY = BM * 128;   // bytes per A buffer
  extern __shared__ __align__(16) char sm[];
  char* A0 = sm;
  char* A1 = sm + ABY;
  char* B0 = sm + 2 * ABY;
  char* B1 = sm + 2 * ABY + 32768;
  const int m0 = blockIdx.x * BM, n0 = blockIdx.y * 256;
  const int tid = threadIdx.x, lane = tid & 63, w = tid >> 6;
  const int wr = w & 1, wc = w >> 1;  // 2M x 4N waves, 16-row/16-col stripes
  const int lr = lane & 15, lu = lane >> 4;
  const short* Am = A + (size_t)m0 * K;
  const short* Bn = Bt + (size_t)n0 * K;
  f32x4 acc[KFN * 2][4] = {};
  bf16x8 a[KFN * 2], b[4];
  const int NIT = K >> 7;
  const int TMAX = (K >> 6) - 1;

  // prologue: t0 full + t1.{Ah0,Bh1}; wait t0 (leave t1's LPA+2 loads in flight)
  SA(A0, 0, 0); SB(B0, 1, 0); SA(A0, 1, 0); SB(B0, 0, 0);
  SA(A1, 0, 1); SB(B1, 1, 1);
  VMW; BARR;

  for (int it = 0; it < NIT; ++it) {
    const int t1 = 2 * it + 1;
    const int t2 = (2 * it + 2 < TMAX) ? 2 * it + 2 : TMAX;
    const int t3 = (2 * it + 3 < TMAX) ? 2 * it + 3 : TMAX;
    // Ph0: quadrant (0,0) of even tile
    RDA(A0, 0); RDB(B0, 0); SA(A1, 1, t1);
    PR1; MF(0, 0); PR0; BARR;
    // Ph1: (0,1)
    RDB(B0, 1); SB(B1, 0, t1);
    PR1; MF(0, 1); PR0; BARR;
    // Ph2: (1,1)
    RDA(A0, 1); SA(A0, 0, t2);
    PR1; MF(1, 1); PR0; BARR;
    // Ph3: (1,0)  [odd-tile buffers complete after this wait]
    RDB(B0, 0); SB(B0, 1, t2);
    PR1; MF(1, 0); PR0; VMW; BARR;
    // Ph4: (0,0) of odd tile
    RDA(A1, 0); RDB(B1, 0); SA(A0, 1, t2);
    PR1; MF(0, 0); PR0; BARR;
    // Ph5: (0,1)
    RDB(B1, 1); SB(B0, 0, t2);
    PR1; MF(0, 1); PR0; BARR;
    // Ph6: (1,1)
    RDA(A1, 1); SA(A1, 0, t3);
    PR1; MF(1, 1); PR0; BARR;
    // Ph7: (1,0)  [even-tile buffers complete after this wait]
    RDB(B1, 0); SB(B1, 1, t3);
    PR1; MF(1, 0); PR0; VMW; BARR;
  }

  // epilogue
#pragma unroll
  for (int k = 0; k < KFN * 2; k++)
#pragma unroll
    for (int j = 0; j < 4; j++)
#pragma unroll
      for (int r = 0; r < 4; r++) {
        const int m = m0 + k * 32 + wr * 16 + lu * 4 + r;
        const int n = n0 + j * 64 + wc * 16 + lr;
        const float v = acc[k][j][r];
        if (mode == 2) {
          ((float*)Out0)[(size_t)m * N + n] = v;
        } else {
          const int bb = m >> 11, t = m & 2047;
          if (n < 2048) {  // q: [b][head][t][h]
            ((short*)Out0)[(((size_t)(bb * 16 + (n >> 7))) << 18) + t * 128 + (n & 127)] = f2bf(v);
          } else if (n < 2560) {  // k: [b][kv][t][h]
            const int nn = n - 2048;
            ((short*)Out1)[(((size_t)(bb * 4 + (nn >> 7))) << 18) + t * 128 + (nn & 127)] = f2bf(v);
          } else {  // v, transposed: [b][kv][h][s]
            const int nn = n - 2560;
            ((short*)Out2)[((size_t)((bb * 4 + (nn >> 7)) * 128 + (nn & 127))) * 2048 + t] = f2bf(v);
          }
        }
      }
}

// ---------------- in-place RoPE on bf16 [rows][128]; t = row & 2047 ----------------
__global__ void k_rope(short* __restrict__ q, float scale) {
  const int gid = blockIdx.x * blockDim.x + threadIdx.x;
  const int i = gid & 63;
  const int row = gid >> 6;
  const int t = row & 2047;
  short* p = q + (size_t)row * 128;
  const float inv = __expf(-(float)i * (float)(9.210340371976184 / 64.0));  // 10000^{-i/64}
  const float ang = (float)t * inv;
  float sn, cs;
  sincosf(ang, &sn, &cs);
  const float x1 = bf2f(p[i]), x2 = bf2f(p[i + 64]);
  p[i] = f2bf((x1 * cs - x2 * sn) * scale);
  p[i + 64] = f2bf((x2 * cs + x1 * sn) * scale);
}

// ---------------- flash attention, sliding window + tanh soft-cap ----------------
__global__ __launch_bounds__(256) void k_attn(
    const short* __restrict__ q, const short* __restrict__ kk,
    const short* __restrict__ vT, short* __restrict__ enc) {
  __shared__ __align__(16) short lK[64 * 128];   // [s][h], byte ^= ((s&7)<<4)
  __shared__ __align__(16) short lV[128 * 64];   // [h][s], byte ^= ((h&7)<<4)
  __shared__ __align__(16) short lP[4][16 * 64]; // per-wave P [t][s], byte ^= ((t&7)<<4)
  const int bn = blockIdx.x, b = bn >> 4, n = bn & 15, kv = n >> 2;
  const int qt0 = (31 - blockIdx.y) * 64;  // heavy blocks dispatched first
  const int tid = threadIdx.x, lane = tid & 63, w = tid >> 6;
  const int lr = lane & 15, lu = lane >> 4;
  const short* qbase = q + (((size_t)(b * 16 + n)) << 18) + (size_t)(qt0 + w * 16) * 128;
  bf16x8 qa[4];
#pragma unroll
  for (int c = 0; c < 4; c++)
    qa[c] = *reinterpret_cast<const bf16x8*>(qbase + lr * 128 + c * 32 + lu * 8);
  f32x4 o[8] = {};
  float lsum[4] = {0.f, 0.f, 0.f, 0.f};
  const short* kbase = kk + (((size_t)(b * 4 + kv)) << 18);
  const short* vbase = vT + (((size_t)(b * 4 + kv)) << 18);
  char* lPw = (char*)lP[w];
  const int tw = qt0 + w * 16;
  const int t_row = tw + lu * 4;
  int st0 = qt0 - 1023; if (st0 < 0) st0 = 0;
  st0 >>= 6;
  const int stE = (qt0 + 63) >> 6;
  for (int st = st0; st <= stE; st++) {
    const int s0 = st << 6;
#pragma unroll
    for (int c = 0; c < 4; c++) {
      const int L = w * 4096 + c * 1024 + lane * 16;  // byte offset in 16 KiB tile
      {  // K tile: linear LDS dest, pre-swizzled global source
        const int s = L >> 8, slot = (L >> 4) & 15;
        const int sp = slot ^ (s & 7);
        __builtin_amdgcn_global_load_lds(
            (const __attribute__((address_space(1))) void*)(kbase + (size_t)(s0 + s) * 128 + sp * 8),
            (__attribute__((address_space(3))) void*)((char*)lK + L), 16, 0, 0);
      }
      {  // V tile
        const int h = L >> 7, slot = (L >> 4) & 7;
        const int u = slot ^ (h & 7);
        __builtin_amdgcn_global_load_lds(
            (const __attribute__((address_space(1))) void*)(vbase + (size_t)h * 2048 + s0 + u * 8),
            (__attribute__((address_space(3))) void*)((char*)lV + L), 16, 0, 0);
      }
    }
    __syncthreads();
    // ---- QK^T ----
    f32x4 sc[4];
    __builtin_amdgcn_s_setprio(1);
#pragma unroll
    for (int cg = 0; cg < 4; cg++) {
      sc[cg] = (f32x4){0.f, 0.f, 0.f, 0.f};
      const int s = cg * 16 + lr;
      const int sw = (s & 7) << 4;
#pragma unroll
      for (int c = 0; c < 4; c++) {
        bf16x8 kb = *reinterpret_cast<const bf16x8*>((char*)lK + s * 256 + (((c * 4 + lu) << 4) ^ sw));
        sc[cg] = __builtin_amdgcn_mfma_f32_16x16x32_bf16(qa[c], kb, sc[cg], 0, 0, 0);
      }
    }
    __builtin_amdgcn_s_setprio(0);
    // ---- soft-cap + exp (fixed max), write P to swizzled LDS ----
    const bool allv = (s0 + 63 <= tw) && (s0 + 1008 >= tw);
    if (allv) {
#pragma unroll
      for (int cg = 0; cg < 4; cg++)
#pragma unroll
        for (int r = 0; r < 4; r++) {
          const float rc = __builtin_amdgcn_rcpf(__expf(sc[cg][r] * 0.04f) + 1.f);
          const float p = __expf(__builtin_fmaf(rc, -100.f, 50.f));
          lsum[r] += p;
          const int row = lu * 4 + r;
          *(short*)(lPw + (row << 7) + ((((cg * 16 + lr) << 1)) ^ ((row & 7) << 4))) = f2bf(p);
        }
    } else {
#pragma unroll
      for (int cg = 0; cg < 4; cg++) {
        const int s = s0 + cg * 16 + lr;
#pragma unroll
        for (int r = 0; r < 4; r++) {
          const int t = t_row + r;
          const bool valid = (s <= t) & (s + 1024 > t);
          const float rc = __builtin_amdgcn_rcpf(__expf(sc[cg][r] * 0.04f) + 1.f);
          float p = __expf(__builtin_fmaf(rc, -100.f, 50.f));
          p = valid ? p : 0.f;
          lsum[r] += p;
          const int row = lu * 4 + r;
          *(short*)(lPw + (row << 7) + ((((cg * 16 + lr) << 1)) ^ ((row & 7) << 4))) = f2bf(p);
        }
      }
    }
    // ---- PV ----
#pragma unroll
    for (int ks = 0; ks < 2; ks++) {
      const bf16x8 pf = *reinterpret_cast<const bf16x8*>(
          lPw + (lr << 7) + ((ks * 64 + lu * 16) ^ ((lr & 7) << 4)));
      __builtin_amdgcn_s_setprio(1);
#pragma unroll
      for (int oc = 0; oc < 8; oc++) {
        const int h = oc * 16 + lr;
        bf16x8 vb = *reinterpret_cast<const bf16x8*>(
            (char*)lV + h * 128 + (((ks * 4 + lu) << 4) ^ ((h & 7) << 4)));
        o[oc] = __builtin_amdgcn_mfma_f32_16x16x32_bf16(pf, vb, o[oc], 0, 0, 0);
      }
      __builtin_amdgcn_s_setprio(0);
    }
    __syncthreads();
  }
  float rs[4];
#pragma unroll
  for (int r = 0; r < 4; r++) {
    float s = lsum[r];
    s += __shfl_xor(s, 1, 64);
    s += __shfl_xor(s, 2, 64);
    s += __shfl_xor(s, 4, 64);
    s += __shfl_xor(s, 8, 64);
    rs[r] = 1.f / s;
  }
#pragma unroll
  for (int oc = 0; oc < 8; oc++)
#pragma unroll
    for (int r = 0; r < 4; r++) {
      const int t = t_row + r;
      enc[((size_t)b * 2048 + t) * 2048 + n * 128 + oc * 16 + lr] = f2bf(o[oc][r] * rs[r]);
    }
}

extern "C" void kernel_launch(void* const* d_in, const int* in_sizes, int n_in,
                              void* d_out, int out_size, void* d_ws, size_t ws_size,
                              hipStream_t stream) {
  (void)in_sizes; (void)n_in; (void)out_size; (void)ws_size;
  const float* x    = (const float*)d_in[0];
  const float* wq   = (const float*)d_in[3];
  const float* wkv  = (const float*)d_in[4];
  const float* wvec = (const float*)d_in[5];
  char* ws = (char*)d_ws;
  size_t off = 0;
  short* xbf   = (short*)(ws + off); off += (size_t)8388608 * 2;            // x bf16 [B*T][D]
  short* wall  = (short*)(ws + off); off += (size_t)3072 * 2048 * 2;        // [wqT|wkT|wvT] rows x K
  short* wvecT = (short*)(ws + off); off += (size_t)2048 * 2048 * 2;        // [d][nh]
  short* qbuf  = (short*)(ws + off); off += (size_t)2 * 16 * 2048 * 128 * 2; // q bf16 [b][n][t][h]
  short* kbuf  = (short*)(ws + off); off += (size_t)2 * 4 * 2048 * 128 * 2;  // k bf16 [b][kv][t][h]
  short* vTbuf = (short*)(ws + off); off += (size_t)2 * 4 * 128 * 2048 * 2;  // v^T [b][kv][h][s]
  short* encb  = (short*)(ws + off); off += (size_t)2 * 2048 * 2048 * 2;     // [b][t][nh]

  hipFuncSetAttribute(reinterpret_cast<const void*>(&k_gemm256<256>),
                      hipFuncAttributeMaxDynamicSharedMemorySize, 131072);
  hipFuncSetAttribute(reinterpret_cast<const void*>(&k_gemm256<128>),
                      hipFuncAttributeMaxDynamicSharedMemorySize, 98304);

  k_cvt<<<8192, 256, 0, stream>>>(x, xbf, 2097152);
  k_tr<float><<<dim3(4, 64, 16), 256, 0, stream>>>(wq, wall, 2048, 128);
  k_tr<float><<<dim3(4, 64, 4), 256, 0, stream>>>(wkv, wall + 4194304, 2048, 128);
  k_tr<float><<<dim3(4, 64, 4), 256, 0, stream>>>(wkv + 1048576, wall + 5242880, 2048, 128);
  k_tr<float><<<dim3(64, 64, 1), 256, 0, stream>>>(wvec, wvecT, 2048, 2048);
  k_gemm256<256><<<dim3(16, 12), 512, 131072, stream>>>(xbf, wall, qbuf, kbuf, vTbuf,
                                                        3072, 2048, 0);
  k_rope<<<16384, 256, 0, stream>>>(qbuf, 0.08838834764831845f);  // 1/sqrt(128)
  k_rope<<<4096, 256, 0, stream>>>(kbuf, 1.0f);
  k_attn<<<dim3(32, 32), 256, 0, stream>>>(qbuf, kbuf, vTbuf, encb);
  k_gemm256<128><<<dim3(32, 8), 512, 98304, stream>>>(encb, wvecT, d_out, nullptr, nullptr,
                                                      2048, 2048, 2);
}

// Round 6
// 195.390 us; speedup vs baseline: 1.6631x; 1.1024x over previous
//
#include <hip/hip_runtime.h>
#include <hip/hip_bf16.h>

#define DEVINL static __device__ __forceinline__

typedef __attribute__((ext_vector_type(4))) float f32x4;
typedef __attribute__((ext_vector_type(8))) short bf16x8;

DEVINL short f2bf(float f) {
  __hip_bfloat16 h = __float2bfloat16(f);
  union { __hip_bfloat16 h; short s; } u; u.h = h; return u.s;
}
DEVINL float bf2f(short s) {
  union { unsigned u; float f; } v; v.u = ((unsigned)(unsigned short)s) << 16;
  return v.f;
}
DEVINL float ldf(float x) { return x; }
DEVINL float ldf(short x) { return bf2f(x); }

// ---------------- f32 -> bf16 convert, 4 elems/thread ----------------
__global__ void k_cvt(const float* __restrict__ in, short* __restrict__ out, int n4) {
  int i = blockIdx.x * blockDim.x + threadIdx.x;
  if (i >= n4) return;
  const float4 v = reinterpret_cast<const float4*>(in)[i];
  short4 o;
  o.x = f2bf(v.x); o.y = f2bf(v.y); o.z = f2bf(v.z); o.w = f2bf(v.w);
  reinterpret_cast<short4*>(out)[i] = o;
}

// ------- batched transpose [batch][R][C] -> [batch][C][R], out bf16 -------
template <typename Tin>
__global__ void k_tr(const Tin* __restrict__ in, short* __restrict__ out, int R, int C) {
  __shared__ float tile[32][33];
  const int bz = blockIdx.z;
  const int r0 = blockIdx.y * 32, c0 = blockIdx.x * 32;
  const int tx = threadIdx.x & 31, ty = threadIdx.x >> 5;  // ty in 0..7
  const Tin* ip = in + (size_t)bz * R * C;
  short* op = out + (size_t)bz * R * C;
#pragma unroll
  for (int k = 0; k < 4; k++)
    tile[ty + k * 8][tx] = ldf(ip[(size_t)(r0 + ty + k * 8) * C + c0 + tx]);
  __syncthreads();
#pragma unroll
  for (int k = 0; k < 4; k++)
    op[(size_t)(c0 + ty + k * 8) * R + r0 + tx] = f2bf(tile[tx][ty + k * 8]);
}

// =================== BMxBNxK 8-phase MFMA GEMM (T2+T3+T4+T5) ===================
// C[M][N] = A[M][K] * Bt[N][K]^T ; 512 threads, 8 waves (2M x 4N, 16-stripe interleave)
// LDS dynamic: A0|A1|B0|B1; granule-XOR swizzled; 2-barrier+LGK phase frame (m201).
// mode 0: QKV scatter epilogue (q bf16 / kv bf16); mode 2: f32 row-major.

#define FEN asm volatile("" ::: "memory")
#define GBAR __builtin_amdgcn_s_barrier()
#define LGK { asm volatile("s_waitcnt lgkmcnt(0)"); __builtin_amdgcn_sched_barrier(0); }
#define PR1 __builtin_amdgcn_s_setprio(1)
#define PR0 __builtin_amdgcn_s_setprio(0)
#define VMW { if constexpr (LPA + LPB == 4) asm volatile("s_waitcnt vmcnt(4)"); \
              else asm volatile("s_waitcnt vmcnt(3)"); }

// stage one half-tile: LN x global_load_lds(16B)/thread; LDS linear, src pre-swizzled
template <int LN>
DEVINL void stage(char* dst, const short* src, int K, int tid) {
#pragma unroll
  for (int L = 0; L < LN; L++) {
    const int loc = L * 8192 + tid * 16;
    const int row = loc >> 7;
    const int gsw = ((loc >> 4) & 7) ^ (row & 7);
    __builtin_amdgcn_global_load_lds(
        (const __attribute__((address_space(1))) void*)(src + (size_t)row * K + gsw * 8),
        (__attribute__((address_space(3))) void*)(dst + loc), 16, 0, 0);
  }
}

#define SA(BUF, HALF, KT) \
  stage<LPA>((BUF) + (HALF) * (ABY / 2), Am + (size_t)((HALF) * (BM / 2)) * K + (KT) * 64, K, tid)
#define SB(BUF, HALF, KT) \
  stage<LPB>((BUF) + (HALF) * (BBY / 2), Bn + (size_t)((HALF) * (BN / 2)) * K + (KT) * 64, K, tid)

#define RDA(BUF, IH)                                                                   \
  { _Pragma("unroll")                                                                  \
    for (int kf_ = 0; kf_ < KFN; kf_++) {                                              \
      _Pragma("unroll")                                                                \
      for (int kk_ = 0; kk_ < 2; kk_++) {                                              \
        const int row_ = ((IH) * KFN + kf_) * 32 + wr * 16 + lr;                       \
        a[kf_ * 2 + kk_] = *(const bf16x8*)((BUF) + row_ * 128 +                       \
                                            (((kk_ * 4 + lu) ^ (lr & 7)) << 4));       \
      } } }

#define RDB(BUF, JH)                                                                   \
  { _Pragma("unroll")                                                                  \
    for (int jf_ = 0; jf_ < JFN; jf_++) {                                              \
      _Pragma("unroll")                                                                \
      for (int kk_ = 0; kk_ < 2; kk_++) {                                              \
        const int row_ = ((JH) * JFN + jf_) * 64 + wc * 16 + lr;                       \
        b[jf_ * 2 + kk_] = *(const bf16x8*)((BUF) + row_ * 128 +                       \
                                            (((kk_ * 4 + lu) ^ (lr & 7)) << 4));       \
      } } }

#define MF(IH, JH)                                                                     \
  { _Pragma("unroll")                                                                  \
    for (int kf_ = 0; kf_ < KFN; kf_++)                                                \
      { _Pragma("unroll")                                                              \
        for (int jf_ = 0; jf_ < JFN; jf_++)                                            \
          { _Pragma("unroll")                                                          \
            for (int kk_ = 0; kk_ < 2; kk_++)                                          \
              acc[(IH) * KFN + kf_][(JH) * JFN + jf_] =                                \
                  __builtin_amdgcn_mfma_f32_16x16x32_bf16(                             \
                      a[kf_ * 2 + kk_], b[jf_ * 2 + kk_],                              \
                      acc[(IH) * KFN + kf_][(JH) * JFN + jf_], 0, 0, 0);               \
          } } }

template <int BM, int BN>
__global__ __launch_bounds__(512, 2) void k_gemm256(
    const short* __restrict__ A, const short* __restrict__ Bt,
    void* __restrict__ Out0, void* __restrict__ Out1,
    int N, int K, int mode) {
  constexpr int LPA = BM / 128;   // loads/thread per A half-tile
  constexpr int LPB = BN / 128;   // loads/thread per B half-tile
  constexpr int KFN = BM / 64;    // 32-row A groups per M-half
  constexpr int JFN = BN / 128;   // 64-row B groups per N-half
  constexpr int ABY = BM * 128;   // bytes per A buffer [BM][64]
  constexpr int BBY = BN * 128;   // bytes per B buffer [BN][64]
  extern __shared__ __align__(16) char sm[];
  char* A0 = sm;
  char* A1 = sm + ABY;
  char* B0 = sm + 2 * ABY;
  char* B1 = sm + 2 * ABY + BBY;
  const int m0 = blockIdx.x * BM, n0 = blockIdx.y * BN;
  const int tid = threadIdx.x, lane = tid & 63, w = tid >> 6;
  const int wr = w & 1, wc = w >> 1;  // 2M x 4N waves, 16-row/16-col stripes
  const int lr = lane & 15, lu = lane >> 4;
  const short* Am = A + (size_t)m0 * K;
  const short* Bn = Bt + (size_t)n0 * K;
  f32x4 acc[KFN * 2][JFN * 2] = {};
  bf16x8 a[KFN * 2], b[JFN * 2];
  const int NIT = K >> 7;
  const int TMAX = (K >> 6) - 1;

  // prologue: t0 full + t1.{Ah0,Bh1}; wait t0 (leave t1's LPA+LPB loads in flight)
  SA(A0, 0, 0); SB(B0, 1, 0); SA(A0, 1, 0); SB(B0, 0, 0);
  SA(A1, 0, 1); SB(B1, 1, 1);
  VMW; FEN; GBAR;

  for (int it = 0; it < NIT; ++it) {
    const int t1 = 2 * it + 1;
    const int t2 = (2 * it + 2 < TMAX) ? 2 * it + 2 : TMAX;
    const int t3 = (2 * it + 3 < TMAX) ? 2 * it + 3 : TMAX;
    // Ph0: quadrant (0,0) of even tile
    RDA(A0, 0); RDB(B0, 0); SA(A1, 1, t1);
    FEN; GBAR; LGK; PR1; MF(0, 0); PR0; FEN; GBAR;
    // Ph1: (0,1)
    RDB(B0, 1); SB(B1, 0, t1);
    FEN; GBAR; LGK; PR1; MF(0, 1); PR0; FEN; GBAR;
    // Ph2: (1,1)
    RDA(A0, 1); SA(A0, 0, t2);
    FEN; GBAR; LGK; PR1; MF(1, 1); PR0; FEN; GBAR;
    // Ph3: (1,0)  [odd-tile buffers complete after this wait]
    RDB(B0, 0); SB(B0, 1, t2);
    FEN; GBAR; LGK; PR1; MF(1, 0); PR0; VMW; FEN; GBAR;
    // Ph4: (0,0) of odd tile
    RDA(A1, 0); RDB(B1, 0); SA(A0, 1, t2);
    FEN; GBAR; LGK; PR1; MF(0, 0); PR0; FEN; GBAR;
    // Ph5: (0,1)
    RDB(B1, 1); SB(B0, 0, t2);
    FEN; GBAR; LGK; PR1; MF(0, 1); PR0; FEN; GBAR;
    // Ph6: (1,1)
    RDA(A1, 1); SA(A1, 0, t3);
    FEN; GBAR; LGK; PR1; MF(1, 1); PR0; FEN; GBAR;
    // Ph7: (1,0)  [even-tile buffers complete after this wait]
    RDB(B1, 0); SB(B1, 1, t3);
    FEN; GBAR; LGK; PR1; MF(1, 0); PR0; VMW; FEN; GBAR;
  }

  // epilogue
#pragma unroll
  for (int k = 0; k < KFN * 2; k++)
#pragma unroll
    for (int j = 0; j < JFN * 2; j++)
#pragma unroll
      for (int r = 0; r < 4; r++) {
        const int m = m0 + k * 32 + wr * 16 + lu * 4 + r;
        const int n = n0 + j * 64 + wc * 16 + lr;
        const float v = acc[k][j][r];
        if (mode == 2) {
          ((float*)Out0)[(size_t)m * N + n] = v;
        } else {
          const int bb = m >> 11, t = m & 2047;
          if (n < 2048) {  // q: [b][head][t][h]
            ((short*)Out0)[(((size_t)(bb * 16 + (n >> 7))) << 18) + t * 128 + (n & 127)] = f2bf(v);
          } else {  // kv: [c][b][kv][t][h]
            const int nn = n - 2048;
            ((short*)Out1)[(((size_t)(((nn >> 9) * 2 + bb) * 4 + ((nn >> 7) & 3))) << 18) +
                           t * 128 + (nn & 127)] = f2bf(v);
          }
        }
      }
}

// ---------------- in-place RoPE on bf16 [rows][128]; t = row & 2047 ----------------
__global__ void k_rope(short* __restrict__ q, float scale) {
  const int gid = blockIdx.x * blockDim.x + threadIdx.x;
  const int i = gid & 63;
  const int row = gid >> 6;
  const int t = row & 2047;
  short* p = q + (size_t)row * 128;
  const float inv = __expf(-(float)i * (float)(9.210340371976184 / 64.0));  // 10000^{-i/64}
  const float ang = (float)t * inv;
  float sn, cs;
  sincosf(ang, &sn, &cs);
  const float x1 = bf2f(p[i]), x2 = bf2f(p[i + 64]);
  p[i] = f2bf((x1 * cs - x2 * sn) * scale);
  p[i + 64] = f2bf((x2 * cs + x1 * sn) * scale);
}

// ---------------- flash attention, sliding window + tanh soft-cap ----------------
__global__ __launch_bounds__(256) void k_attn(
    const short* __restrict__ q, const short* __restrict__ kk,
    const short* __restrict__ vT, short* __restrict__ enc) {
  __shared__ __align__(16) short lK[64 * 128];   // [s][h], byte ^= ((s&7)<<4)
  __shared__ __align__(16) short lV[128 * 64];   // [h][s], byte ^= ((h&7)<<4)
  __shared__ __align__(16) short lP[4][16 * 64]; // per-wave P [t][s], byte ^= ((t&7)<<4)
  const int bn = blockIdx.x, b = bn >> 4, n = bn & 15, kv = n >> 2;
  const int qt0 = (31 - blockIdx.y) * 64;  // heavy blocks dispatched first
  const int tid = threadIdx.x, lane = tid & 63, w = tid >> 6;
  const int lr = lane & 15, lu = lane >> 4;
  const short* qbase = q + (((size_t)(b * 16 + n)) << 18) + (size_t)(qt0 + w * 16) * 128;
  bf16x8 qa[4];
#pragma unroll
  for (int c = 0; c < 4; c++)
    qa[c] = *reinterpret_cast<const bf16x8*>(qbase + lr * 128 + c * 32 + lu * 8);
  f32x4 o[8] = {};
  float lsum[4] = {0.f, 0.f, 0.f, 0.f};
  const short* kbase = kk + (((size_t)(b * 4 + kv)) << 18);
  const short* vbase = vT + (((size_t)(b * 4 + kv)) << 18);
  char* lPw = (char*)lP[w];
  const int tw = qt0 + w * 16;
  const int t_row = tw + lu * 4;
  int st0 = qt0 - 1023; if (st0 < 0) st0 = 0;
  st0 >>= 6;
  const int stE = (qt0 + 63) >> 6;
  for (int st = st0; st <= stE; st++) {
    const int s0 = st << 6;
#pragma unroll
    for (int c = 0; c < 4; c++) {
      const int L = w * 4096 + c * 1024 + lane * 16;  // byte offset in 16 KiB tile
      {  // K tile: linear LDS dest, pre-swizzled global source
        const int s = L >> 8, slot = (L >> 4) & 15;
        const int sp = slot ^ (s & 7);
        __builtin_amdgcn_global_load_lds(
            (const __attribute__((address_space(1))) void*)(kbase + (size_t)(s0 + s) * 128 + sp * 8),
            (__attribute__((address_space(3))) void*)((char*)lK + L), 16, 0, 0);
      }
      {  // V tile
        const int h = L >> 7, slot = (L >> 4) & 7;
        const int u = slot ^ (h & 7);
        __builtin_amdgcn_global_load_lds(
            (const __attribute__((address_space(1))) void*)(vbase + (size_t)h * 2048 + s0 + u * 8),
            (__attribute__((address_space(3))) void*)((char*)lV + L), 16, 0, 0);
      }
    }
    __syncthreads();
    // ---- QK^T ----
    f32x4 sc[4];
    __builtin_amdgcn_s_setprio(1);
#pragma unroll
    for (int cg = 0; cg < 4; cg++) {
      sc[cg] = (f32x4){0.f, 0.f, 0.f, 0.f};
      const int s = cg * 16 + lr;
      const int sw = (s & 7) << 4;
#pragma unroll
      for (int c = 0; c < 4; c++) {
        bf16x8 kb = *reinterpret_cast<const bf16x8*>((char*)lK + s * 256 + (((c * 4 + lu) << 4) ^ sw));
        sc[cg] = __builtin_amdgcn_mfma_f32_16x16x32_bf16(qa[c], kb, sc[cg], 0, 0, 0);
      }
    }
    __builtin_amdgcn_s_setprio(0);
    // ---- soft-cap + exp (fixed max), write P to swizzled LDS ----
    const bool allv = (s0 + 63 <= tw) && (s0 + 1008 >= tw);
    if (allv) {
#pragma unroll
      for (int cg = 0; cg < 4; cg++)
#pragma unroll
        for (int r = 0; r < 4; r++) {
          const float rc = __builtin_amdgcn_rcpf(__expf(sc[cg][r] * 0.04f) + 1.f);
          const float p = __expf(__builtin_fmaf(rc, -100.f, 50.f));
          lsum[r] += p;
          const int row = lu * 4 + r;
          *(short*)(lPw + (row << 7) + ((((cg * 16 + lr) << 1)) ^ ((row & 7) << 4))) = f2bf(p);
        }
    } else {
#pragma unroll
      for (int cg = 0; cg < 4; cg++) {
        const int s = s0 + cg * 16 + lr;
#pragma unroll
        for (int r = 0; r < 4; r++) {
          const int t = t_row + r;
          const bool valid = (s <= t) & (s + 1024 > t);
          const float rc = __builtin_amdgcn_rcpf(__expf(sc[cg][r] * 0.04f) + 1.f);
          float p = __expf(__builtin_fmaf(rc, -100.f, 50.f));
          p = valid ? p : 0.f;
          lsum[r] += p;
          const int row = lu * 4 + r;
          *(short*)(lPw + (row << 7) + ((((cg * 16 + lr) << 1)) ^ ((row & 7) << 4))) = f2bf(p);
        }
      }
    }
    // ---- PV ----
#pragma unroll
    for (int ks = 0; ks < 2; ks++) {
      const bf16x8 pf = *reinterpret_cast<const bf16x8*>(
          lPw + (lr << 7) + ((ks * 64 + lu * 16) ^ ((lr & 7) << 4)));
      __builtin_amdgcn_s_setprio(1);
#pragma unroll
      for (int oc = 0; oc < 8; oc++) {
        const int h = oc * 16 + lr;
        bf16x8 vb = *reinterpret_cast<const bf16x8*>(
            (char*)lV + h * 128 + (((ks * 4 + lu) << 4) ^ ((h & 7) << 4)));
        o[oc] = __builtin_amdgcn_mfma_f32_16x16x32_bf16(pf, vb, o[oc], 0, 0, 0);
      }
      __builtin_amdgcn_s_setprio(0);
    }
    __syncthreads();
  }
  float rs[4];
#pragma unroll
  for (int r = 0; r < 4; r++) {
    float s = lsum[r];
    s += __shfl_xor(s, 1, 64);
    s += __shfl_xor(s, 2, 64);
    s += __shfl_xor(s, 4, 64);
    s += __shfl_xor(s, 8, 64);
    rs[r] = 1.f / s;
  }
#pragma unroll
  for (int oc = 0; oc < 8; oc++)
#pragma unroll
    for (int r = 0; r < 4; r++) {
      const int t = t_row + r;
      enc[((size_t)b * 2048 + t) * 2048 + n * 128 + oc * 16 + lr] = f2bf(o[oc][r] * rs[r]);
    }
}

extern "C" void kernel_launch(void* const* d_in, const int* in_sizes, int n_in,
                              void* d_out, int out_size, void* d_ws, size_t ws_size,
                              hipStream_t stream) {
  (void)in_sizes; (void)n_in; (void)out_size; (void)ws_size;
  const float* x    = (const float*)d_in[0];
  const float* wq   = (const float*)d_in[3];
  const float* wkv  = (const float*)d_in[4];
  const float* wvec = (const float*)d_in[5];
  char* ws = (char*)d_ws;
  size_t off = 0;
  short* xbf   = (short*)(ws + off); off += (size_t)8388608 * 2;            // x bf16 [B*T][D]
  short* wall  = (short*)(ws + off); off += (size_t)3072 * 2048 * 2;        // [wqT|wkT|wvT] rows x K
  short* wvecT = (short*)(ws + off); off += (size_t)2048 * 2048 * 2;        // [d][nh]
  short* qbuf  = (short*)(ws + off); off += (size_t)2 * 16 * 2048 * 128 * 2; // q bf16 [b][n][t][h]
  short* kvbuf = (short*)(ws + off); off += (size_t)2 * 2 * 4 * 2048 * 128 * 2; // [c][b][kv][t][h]
  short* vTbuf = (short*)(ws + off); off += (size_t)2 * 4 * 128 * 2048 * 2; // v^T [b][kv][h][s]
  short* encb  = (short*)(ws + off); off += (size_t)2 * 2048 * 2048 * 2;    // [b][t][nh]

  hipFuncSetAttribute(reinterpret_cast<const void*>(&k_gemm256<128, 384>),
                      hipFuncAttributeMaxDynamicSharedMemorySize, 131072);
  hipFuncSetAttribute(reinterpret_cast<const void*>(&k_gemm256<128, 256>),
                      hipFuncAttributeMaxDynamicSharedMemorySize, 98304);

  k_cvt<<<8192, 256, 0, stream>>>(x, xbf, 2097152);
  k_tr<float><<<dim3(4, 64, 16), 256, 0, stream>>>(wq, wall, 2048, 128);
  k_tr<float><<<dim3(4, 64, 4), 256, 0, stream>>>(wkv, wall + 4194304, 2048, 128);
  k_tr<float><<<dim3(4, 64, 4), 256, 0, stream>>>(wkv + 1048576, wall + 5242880, 2048, 128);
  k_tr<float><<<dim3(64, 64, 1), 256, 0, stream>>>(wvec, wvecT, 2048, 2048);
  k_gemm256<128, 384><<<dim3(32, 8), 512, 131072, stream>>>(xbf, wall, qbuf, kvbuf,
                                                            3072, 2048, 0);
  k_rope<<<16384, 256, 0, stream>>>(qbuf, 0.08838834764831845f);  // 1/sqrt(128)
  k_rope<<<4096, 256, 0, stream>>>(kvbuf, 1.0f);
  k_tr<short><<<dim3(4, 64, 8), 256, 0, stream>>>(kvbuf + 2097152, vTbuf, 2048, 128);
  k_attn<<<dim3(32, 32), 256, 0, stream>>>(qbuf, kvbuf, vTbuf, encb);
  k_gemm256<128, 256><<<dim3(32, 8), 512, 98304, stream>>>(encb, wvecT, d_out, nullptr,
                                                           2048, 2048, 2);
}

// Round 7
// 191.425 us; speedup vs baseline: 1.6975x; 1.0207x over previous
//
#include <hip/hip_runtime.h>
#include <hip/hip_bf16.h>

#define DEVINL static __device__ __forceinline__

typedef __attribute__((ext_vector_type(4))) float f32x4;
typedef __attribute__((ext_vector_type(8))) short bf16x8;

DEVINL short f2bf(float f) {
  __hip_bfloat16 h = __float2bfloat16(f);
  union { __hip_bfloat16 h; short s; } u; u.h = h; return u.s;
}
DEVINL float bf2f(short s) {
  union { unsigned u; float f; } v; v.u = ((unsigned)(unsigned short)s) << 16;
  return v.f;
}
DEVINL float ldf(float x) { return x; }
DEVINL float ldf(short x) { return bf2f(x); }

// ---------------- f32 -> bf16 convert, 4 elems/thread ----------------
__global__ void k_cvt(const float* __restrict__ in, short* __restrict__ out, int n4) {
  int i = blockIdx.x * blockDim.x + threadIdx.x;
  if (i >= n4) return;
  const float4 v = reinterpret_cast<const float4*>(in)[i];
  short4 o;
  o.x = f2bf(v.x); o.y = f2bf(v.y); o.z = f2bf(v.z); o.w = f2bf(v.w);
  reinterpret_cast<short4*>(out)[i] = o;
}

// ------- batched transpose [batch][R][C] -> [batch][C][R], out bf16 -------
template <typename Tin>
__global__ void k_tr(const Tin* __restrict__ in, short* __restrict__ out, int R, int C) {
  __shared__ float tile[32][33];
  const int bz = blockIdx.z;
  const int r0 = blockIdx.y * 32, c0 = blockIdx.x * 32;
  const int tx = threadIdx.x & 31, ty = threadIdx.x >> 5;  // ty in 0..7
  const Tin* ip = in + (size_t)bz * R * C;
  short* op = out + (size_t)bz * R * C;
#pragma unroll
  for (int k = 0; k < 4; k++)
    tile[ty + k * 8][tx] = ldf(ip[(size_t)(r0 + ty + k * 8) * C + c0 + tx]);
  __syncthreads();
#pragma unroll
  for (int k = 0; k < 4; k++)
    op[(size_t)(c0 + ty + k * 8) * R + r0 + tx] = f2bf(tile[tx][ty + k * 8]);
}

// =================== BMxBNxK deep 8-phase MFMA GEMM (T2+T3+T4+T5) ===================
// C[M][N] = A[M][K] * Bt[N][K]^T ; 512 threads, 8 waves (WM x WN, 16-stripe interleave)
// B-halves held in regs (b0,b1) -> each LDS half read once; stage slot = half that
// died last phase. vmcnt ledger: prologue VM7; VM3 @ph3; VM7 @ph7 (3 halves in flight).
// mode 0: QKV scatter epilogue (q bf16 / kv bf16); mode 2: f32 row-major.

#define FEN asm volatile("" ::: "memory")
#define GBAR __builtin_amdgcn_s_barrier()
#define LGK { asm volatile("s_waitcnt lgkmcnt(0)"); __builtin_amdgcn_sched_barrier(0); }
#define PR1 __builtin_amdgcn_s_setprio(1)
#define PR0 __builtin_amdgcn_s_setprio(0)
#define VM3 { if constexpr (LPA + 2 * LPB == 6) asm volatile("s_waitcnt vmcnt(6)");       \
              else if constexpr (LPA + 2 * LPB == 4) asm volatile("s_waitcnt vmcnt(4)");  \
              else asm volatile("s_waitcnt vmcnt(0)"); }
#define VM7 { if constexpr (2 * LPA + 2 * LPB == 8) asm volatile("s_waitcnt vmcnt(8)");   \
              else if constexpr (2 * LPA + 2 * LPB == 6) asm volatile("s_waitcnt vmcnt(6)"); \
              else asm volatile("s_waitcnt vmcnt(0)"); }

// stage one half-tile: LN x global_load_lds(16B)/thread; LDS linear, src pre-swizzled
template <int LN>
DEVINL void stage(char* dst, const short* src, int K, int tid) {
#pragma unroll
  for (int L = 0; L < LN; L++) {
    const int loc = L * 8192 + tid * 16;
    const int row = loc >> 7;
    const int gsw = ((loc >> 4) & 7) ^ (row & 7);
    __builtin_amdgcn_global_load_lds(
        (const __attribute__((address_space(1))) void*)(src + (size_t)row * K + gsw * 8),
        (__attribute__((address_space(3))) void*)(dst + loc), 16, 0, 0);
  }
}

#define SA(BUF, HALF, KT) \
  stage<LPA>((BUF) + (HALF) * (ABY / 2), Am + (size_t)((HALF) * (BM / 2)) * K + (KT) * 64, K, tid)
#define SB(BUF, HALF, KT) \
  stage<LPB>((BUF) + (HALF) * (BBY / 2), Bn + (size_t)((HALF) * (BN / 2)) * K + (KT) * 64, K, tid)

#define RDA(BUF, IH)                                                                   \
  { _Pragma("unroll")                                                                  \
    for (int kf_ = 0; kf_ < KFN; kf_++) {                                              \
      _Pragma("unroll")                                                                \
      for (int kk_ = 0; kk_ < 2; kk_++) {                                              \
        const int row_ = ((IH) * KFN + kf_) * (WM * 16) + wr * 16 + lr;                \
        a[kf_ * 2 + kk_] = *(const bf16x8*)((BUF) + row_ * 128 +                       \
                                            (((kk_ * 4 + lu) ^ (lr & 7)) << 4));       \
      } } }

#define RDB(BUF, JH, BR)                                                               \
  { _Pragma("unroll")                                                                  \
    for (int jf_ = 0; jf_ < JFN; jf_++) {                                              \
      _Pragma("unroll")                                                                \
      for (int kk_ = 0; kk_ < 2; kk_++) {                                              \
        const int row_ = ((JH) * JFN + jf_) * (WN * 16) + wc * 16 + lr;                \
        BR[jf_ * 2 + kk_] = *(const bf16x8*)((BUF) + row_ * 128 +                      \
                                             (((kk_ * 4 + lu) ^ (lr & 7)) << 4));      \
      } } }

#define MF(IH, JH, BR)                                                                 \
  { _Pragma("unroll")                                                                  \
    for (int kf_ = 0; kf_ < KFN; kf_++)                                                \
      { _Pragma("unroll")                                                              \
        for (int jf_ = 0; jf_ < JFN; jf_++)                                            \
          { _Pragma("unroll")                                                          \
            for (int kk_ = 0; kk_ < 2; kk_++)                                          \
              acc[(IH) * KFN + kf_][(JH) * JFN + jf_] =                                \
                  __builtin_amdgcn_mfma_f32_16x16x32_bf16(                             \
                      a[kf_ * 2 + kk_], BR[jf_ * 2 + kk_],                             \
                      acc[(IH) * KFN + kf_][(JH) * JFN + jf_], 0, 0, 0);               \
          } } }

template <int BM, int BN, int WM>
__global__ __launch_bounds__(512, 2) void k_gemm256(
    const short* __restrict__ A, const short* __restrict__ Bt,
    void* __restrict__ Out0, void* __restrict__ Out1,
    int N, int K, int mode) {
  constexpr int WN = 8 / WM;
  constexpr int LPA = BM / 128;       // loads/thread per A half-tile
  constexpr int LPB = BN / 128;       // loads/thread per B half-tile
  constexpr int KFN = (BM / 2) / (WM * 16);
  constexpr int JFN = (BN / 2) / (WN * 16);
  constexpr int ABY = BM * 128;       // bytes per A buffer [BM][64]
  constexpr int BBY = BN * 128;       // bytes per B buffer [BN][64]
  extern __shared__ __align__(16) char sm[];
  char* A0 = sm;
  char* A1 = sm + ABY;
  char* B0 = sm + 2 * ABY;
  char* B1 = sm + 2 * ABY + BBY;
  const int m0 = blockIdx.x * BM, n0 = blockIdx.y * BN;
  const int tid = threadIdx.x, lane = tid & 63, w = tid >> 6;
  const int wr = w % WM, wc = w / WM;
  const int lr = lane & 15, lu = lane >> 4;
  const short* Am = A + (size_t)m0 * K;
  const short* Bn = Bt + (size_t)n0 * K;
  f32x4 acc[KFN * 2][JFN * 2] = {};
  bf16x8 a[KFN * 2], b0[JFN * 2], b1[JFN * 2];
  const int NIT = K >> 7;
  const int TMAX = (K >> 6) - 1;

  // prologue: stage T0 (A0,B0) then T1 (A1,B1); wait T0 landed (T1 in flight)
  SA(A0, 0, 0); SA(A0, 1, 0); SB(B0, 0, 0); SB(B0, 1, 0);
  SA(A1, 0, 1); SA(A1, 1, 1); SB(B1, 0, 1); SB(B1, 1, 1);
  VM7; FEN; GBAR;

  for (int it = 0; it < NIT; ++it) {
    const int t2 = (2 * it + 2 < TMAX) ? 2 * it + 2 : TMAX;
    const int t3 = (2 * it + 3 < TMAX) ? 2 * it + 3 : TMAX;
    // Ph0: (0,0) even; A0h0+B0h0 die (b0 holds B0h0 in regs)
    RDA(A0, 0); RDB(B0, 0, b0);
    FEN; GBAR; LGK; PR1; MF(0, 0, b0); PR0; FEN; GBAR;
    // Ph1: (0,1); B0h1 dies into regs b1; stage into dead A0h0
    RDB(B0, 1, b1); SA(A0, 0, t2);
    FEN; GBAR; LGK; PR1; MF(0, 1, b1); PR0; FEN; GBAR;
    // Ph2: (1,1); A0h1 dies; stage into dead B0h0
    RDA(A0, 1); SB(B0, 0, t2);
    FEN; GBAR; LGK; PR1; MF(1, 1, b1); PR0; FEN; GBAR;
    // Ph3: (1,0) from regs (no ds_read); stage into dead B0h1; T1 complete after wait
    SB(B0, 1, t2);
    FEN; GBAR; PR1; MF(1, 0, b0); PR0; VM3; FEN; GBAR;
    // Ph4: (0,0) odd; stage into dead A0h1
    RDA(A1, 0); RDB(B1, 0, b0); SA(A0, 1, t2);
    FEN; GBAR; LGK; PR1; MF(0, 0, b0); PR0; FEN; GBAR;
    // Ph5: (0,1)
    RDB(B1, 1, b1); SA(A1, 0, t3);
    FEN; GBAR; LGK; PR1; MF(0, 1, b1); PR0; FEN; GBAR;
    // Ph6: (1,1)
    RDA(A1, 1); SB(B1, 0, t3);
    FEN; GBAR; LGK; PR1; MF(1, 1, b1); PR0; FEN; GBAR;
    // Ph7: (1,0) from regs; stage dead B1h1 + dead A1h1; T2 complete after wait
    SB(B1, 1, t3); SA(A1, 1, t3);
    FEN; GBAR; PR1; MF(1, 0, b0); PR0; VM7; FEN; GBAR;
  }

  // epilogue
#pragma unroll
  for (int k = 0; k < KFN * 2; k++)
#pragma unroll
    for (int j = 0; j < JFN * 2; j++)
#pragma unroll
      for (int r = 0; r < 4; r++) {
        const int m = m0 + k * (WM * 16) + wr * 16 + lu * 4 + r;
        const int n = n0 + j * (WN * 16) + wc * 16 + lr;
        const float v = acc[k][j][r];
        if (mode == 2) {
          ((float*)Out0)[(size_t)m * N + n] = v;
        } else {
          const int bb = m >> 11, t = m & 2047;
          if (n < 2048) {  // q: [b][head][t][h]
            ((short*)Out0)[(((size_t)(bb * 16 + (n >> 7))) << 18) + t * 128 + (n & 127)] = f2bf(v);
          } else {  // kv: [c][b][kv][t][h]
            const int nn = n - 2048;
            ((short*)Out1)[(((size_t)(((nn >> 9) * 2 + bb) * 4 + ((nn >> 7) & 3))) << 18) +
                           t * 128 + (nn & 127)] = f2bf(v);
          }
        }
      }
}

// ---------------- in-place RoPE on bf16 [rows][128]; t = row & 2047 ----------------
__global__ void k_rope(short* __restrict__ q, float scale) {
  const int gid = blockIdx.x * blockDim.x + threadIdx.x;
  const int i = gid & 63;
  const int row = gid >> 6;
  const int t = row & 2047;
  short* p = q + (size_t)row * 128;
  const float inv = __expf(-(float)i * (float)(9.210340371976184 / 64.0));  // 10000^{-i/64}
  const float ang = (float)t * inv;
  float sn, cs;
  sincosf(ang, &sn, &cs);
  const float x1 = bf2f(p[i]), x2 = bf2f(p[i + 64]);
  p[i] = f2bf((x1 * cs - x2 * sn) * scale);
  p[i + 64] = f2bf((x2 * cs + x1 * sn) * scale);
}

// ---------------- flash attention, sliding window + tanh soft-cap ----------------
// Swapped QK^T: sc = mfma(K,Q) -> sc[cg][r] = S[s=s0+cg*16+lu*4+r][t=tw+lr].
// Soft-cap via cubic: 50*tanh(x/50) ~= x - x^3/7500 (err < 2e-3 at |x|=10).
// Fixed-max softmax (cap bounds logits): p = exp(cap); scalar lsum per lane.
__global__ __launch_bounds__(256) void k_attn(
    const short* __restrict__ q, const short* __restrict__ kk,
    const short* __restrict__ vT, short* __restrict__ enc) {
  __shared__ __align__(16) short lK[64 * 128];   // [s][h], byte ^= ((s&7)<<4)
  __shared__ __align__(16) short lV[128 * 64];   // [h][s], byte ^= ((h&7)<<4)
  __shared__ __align__(16) short lP[4][16 * 64]; // per-wave P [t][s], byte ^= ((t&7)<<4)
  const int bn = blockIdx.x, b = bn >> 4, n = bn & 15, kv = n >> 2;
  const int qt0 = (31 - blockIdx.y) * 64;  // heavy blocks dispatched first
  const int tid = threadIdx.x, lane = tid & 63, w = tid >> 6;
  const int lr = lane & 15, lu = lane >> 4;
  const short* qbase = q + (((size_t)(b * 16 + n)) << 18) + (size_t)(qt0 + w * 16) * 128;
  bf16x8 qa[4];
#pragma unroll
  for (int c = 0; c < 4; c++)
    qa[c] = *reinterpret_cast<const bf16x8*>(qbase + lr * 128 + c * 32 + lu * 8);
  f32x4 o[8] = {};
  float lsum = 0.f;
  const short* kbase = kk + (((size_t)(b * 4 + kv)) << 18);
  const short* vbase = vT + (((size_t)(b * 4 + kv)) << 18);
  char* lPw = (char*)lP[w];
  const int tw = qt0 + w * 16;
  const int t_row = tw + lu * 4;
  int st0 = qt0 - 1023; if (st0 < 0) st0 = 0;
  st0 >>= 6;
  const int stE = (qt0 + 63) >> 6;
  for (int st = st0; st <= stE; st++) {
    const int s0 = st << 6;
#pragma unroll
    for (int c = 0; c < 4; c++) {
      const int L = w * 4096 + c * 1024 + lane * 16;  // byte offset in 16 KiB tile
      {  // K tile: linear LDS dest, pre-swizzled global source
        const int s = L >> 8, slot = (L >> 4) & 15;
        const int sp = slot ^ (s & 7);
        __builtin_amdgcn_global_load_lds(
            (const __attribute__((address_space(1))) void*)(kbase + (size_t)(s0 + s) * 128 + sp * 8),
            (__attribute__((address_space(3))) void*)((char*)lK + L), 16, 0, 0);
      }
      {  // V tile
        const int h = L >> 7, slot = (L >> 4) & 7;
        const int u = slot ^ (h & 7);
        __builtin_amdgcn_global_load_lds(
            (const __attribute__((address_space(1))) void*)(vbase + (size_t)h * 2048 + s0 + u * 8),
            (__attribute__((address_space(3))) void*)((char*)lV + L), 16, 0, 0);
      }
    }
    __syncthreads();
    // ---- QK^T (swapped): sc[cg][r] = S[s=cg*16+lu*4+r][t=lr] ----
    f32x4 sc[4];
    __builtin_amdgcn_s_setprio(1);
#pragma unroll
    for (int cg = 0; cg < 4; cg++) {
      sc[cg] = (f32x4){0.f, 0.f, 0.f, 0.f};
      const int s = cg * 16 + lr;
      const int sw = (s & 7) << 4;
#pragma unroll
      for (int c = 0; c < 4; c++) {
        bf16x8 kb = *reinterpret_cast<const bf16x8*>((char*)lK + s * 256 + (((c * 4 + lu) << 4) ^ sw));
        sc[cg] = __builtin_amdgcn_mfma_f32_16x16x32_bf16(kb, qa[c], sc[cg], 0, 0, 0);
      }
    }
    __builtin_amdgcn_s_setprio(0);
    // ---- cubic soft-cap + exp, pack pairs, write P (b32) ----
    const bool allv = (s0 + 63 <= tw) && (s0 + 1008 >= tw);
    if (allv) {
#pragma unroll
      for (int cg = 0; cg < 4; cg++) {
        float pr[4];
#pragma unroll
        for (int r = 0; r < 4; r++) {
          const float x = sc[cg][r];
          const float cap = __builtin_fmaf(x * x * x, -1.3333333e-4f, x);
          const float p = __expf(cap);
          lsum += p;
          pr[r] = p;
        }
        unsigned w0, w1;
        asm("v_cvt_pk_bf16_f32 %0, %1, %2" : "=v"(w0) : "v"(pr[0]), "v"(pr[1]));
        asm("v_cvt_pk_bf16_f32 %0, %1, %2" : "=v"(w1) : "v"(pr[2]), "v"(pr[3]));
        const int sb = (cg * 16 + lu * 4) << 1;  // byte offset of s-pair base
        *(unsigned*)(lPw + (lr << 7) + (sb ^ ((lr & 7) << 4))) = w0;
        *(unsigned*)(lPw + (lr << 7) + ((sb + 4) ^ ((lr & 7) << 4))) = w1;
      }
    } else {
      const int t = tw + lr;
#pragma unroll
      for (int cg = 0; cg < 4; cg++) {
        float pr[4];
#pragma unroll
        for (int r = 0; r < 4; r++) {
          const int s = s0 + cg * 16 + lu * 4 + r;
          const bool valid = (s <= t) & (s + 1024 > t);
          const float x = sc[cg][r];
          const float cap = __builtin_fmaf(x * x * x, -1.3333333e-4f, x);
          float p = __expf(cap);
          p = valid ? p : 0.f;
          lsum += p;
          pr[r] = p;
        }
        unsigned w0, w1;
        asm("v_cvt_pk_bf16_f32 %0, %1, %2" : "=v"(w0) : "v"(pr[0]), "v"(pr[1]));
        asm("v_cvt_pk_bf16_f32 %0, %1, %2" : "=v"(w1) : "v"(pr[2]), "v"(pr[3]));
        const int sb = (cg * 16 + lu * 4) << 1;
        *(unsigned*)(lPw + (lr << 7) + (sb ^ ((lr & 7) << 4))) = w0;
        *(unsigned*)(lPw + (lr << 7) + ((sb + 4) ^ ((lr & 7) << 4))) = w1;
      }
    }
    // ---- PV: o[oc] += P[t][s] * V[s][h] (orientation unchanged) ----
#pragma unroll
    for (int ks = 0; ks < 2; ks++) {
      const bf16x8 pf = *reinterpret_cast<const bf16x8*>(
          lPw + (lr << 7) + ((ks * 64 + lu * 16) ^ ((lr & 7) << 4)));
      __builtin_amdgcn_s_setprio(1);
#pragma unroll
      for (int oc = 0; oc < 8; oc++) {
        const int h = oc * 16 + lr;
        bf16x8 vb = *reinterpret_cast<const bf16x8*>(
            (char*)lV + h * 128 + (((ks * 4 + lu) << 4) ^ ((h & 7) << 4)));
        o[oc] = __builtin_amdgcn_mfma_f32_16x16x32_bf16(pf, vb, o[oc], 0, 0, 0);
      }
      __builtin_amdgcn_s_setprio(0);
    }
    __syncthreads();
  }
  // ---- reduce: lane holds partial sum for column t=tw+lr ----
  float tot = lsum;
  tot += __shfl_xor(tot, 16, 64);
  tot += __shfl_xor(tot, 32, 64);
  float rs[4];
#pragma unroll
  for (int r = 0; r < 4; r++)
    rs[r] = 1.f / __shfl(tot, lu * 4 + r, 64);  // sum for t=tw+lu*4+r held at lane lu*4+r
#pragma unroll
  for (int oc = 0; oc < 8; oc++)
#pragma unroll
    for (int r = 0; r < 4; r++) {
      const int t = t_row + r;
      enc[((size_t)b * 2048 + t) * 2048 + n * 128 + oc * 16 + lr] = f2bf(o[oc][r] * rs[r]);
    }
}

extern "C" void kernel_launch(void* const* d_in, const int* in_sizes, int n_in,
                              void* d_out, int out_size, void* d_ws, size_t ws_size,
                              hipStream_t stream) {
  (void)in_sizes; (void)n_in; (void)out_size; (void)ws_size;
  const float* x    = (const float*)d_in[0];
  const float* wq   = (const float*)d_in[3];
  const float* wkv  = (const float*)d_in[4];
  const float* wvec = (const float*)d_in[5];
  char* ws = (char*)d_ws;
  size_t off = 0;
  short* xbf   = (short*)(ws + off); off += (size_t)8388608 * 2;            // x bf16 [B*T][D]
  short* wall  = (short*)(ws + off); off += (size_t)3072 * 2048 * 2;        // [wqT|wkT|wvT] rows x K
  short* wvecT = (short*)(ws + off); off += (size_t)2048 * 2048 * 2;        // [d][nh]
  short* qbuf  = (short*)(ws + off); off += (size_t)2 * 16 * 2048 * 128 * 2; // q bf16 [b][n][t][h]
  short* kvbuf = (short*)(ws + off); off += (size_t)2 * 2 * 4 * 2048 * 128 * 2; // [c][b][kv][t][h]
  short* vTbuf = (short*)(ws + off); off += (size_t)2 * 4 * 128 * 2048 * 2; // v^T [b][kv][h][s]
  short* encb  = (short*)(ws + off); off += (size_t)2 * 2048 * 2048 * 2;    // [b][t][nh]

  hipFuncSetAttribute(reinterpret_cast<const void*>(&k_gemm256<256, 256, 2>),
                      hipFuncAttributeMaxDynamicSharedMemorySize, 131072);
  hipFuncSetAttribute(reinterpret_cast<const void*>(&k_gemm256<256, 128, 4>),
                      hipFuncAttributeMaxDynamicSharedMemorySize, 98304);

  k_cvt<<<8192, 256, 0, stream>>>(x, xbf, 2097152);
  k_tr<float><<<dim3(4, 64, 16), 256, 0, stream>>>(wq, wall, 2048, 128);
  k_tr<float><<<dim3(4, 64, 4), 256, 0, stream>>>(wkv, wall + 4194304, 2048, 128);
  k_tr<float><<<dim3(4, 64, 4), 256, 0, stream>>>(wkv + 1048576, wall + 5242880, 2048, 128);
  k_tr<float><<<dim3(64, 64, 1), 256, 0, stream>>>(wvec, wvecT, 2048, 2048);
  k_gemm256<256, 256, 2><<<dim3(16, 12), 512, 131072, stream>>>(xbf, wall, qbuf, kvbuf,
                                                                3072, 2048, 0);
  k_rope<<<16384, 256, 0, stream>>>(qbuf, 0.08838834764831845f);  // 1/sqrt(128)
  k_rope<<<4096, 256, 0, stream>>>(kvbuf, 1.0f);
  k_tr<short><<<dim3(4, 64, 8), 256, 0, stream>>>(kvbuf + 2097152, vTbuf, 2048, 128);
  k_attn<<<dim3(32, 32), 256, 0, stream>>>(qbuf, kvbuf, vTbuf, encb);
  k_gemm256<256, 128, 4><<<dim3(16, 16), 512, 98304, stream>>>(encb, wvecT, d_out, nullptr,
                                                               2048, 2048, 2);
}

// Round 8
// 188.769 us; speedup vs baseline: 1.7214x; 1.0141x over previous
//
#include <hip/hip_runtime.h>
#include <hip/hip_bf16.h>

#define DEVINL static __device__ __forceinline__

typedef __attribute__((ext_vector_type(4))) float f32x4;
typedef __attribute__((ext_vector_type(8))) short bf16x8;

DEVINL short f2bf(float f) {
  __hip_bfloat16 h = __float2bfloat16(f);
  union { __hip_bfloat16 h; short s; } u; u.h = h; return u.s;
}
DEVINL float bf2f(short s) {
  union { unsigned u; float f; } v; v.u = ((unsigned)(unsigned short)s) << 16;
  return v.f;
}
DEVINL float ldf(float x) { return x; }
DEVINL float ldf(short x) { return bf2f(x); }

// ---------------- f32 -> bf16 convert, 4 elems/thread ----------------
__global__ void k_cvt(const float* __restrict__ in, short* __restrict__ out, int n4) {
  int i = blockIdx.x * blockDim.x + threadIdx.x;
  if (i >= n4) return;
  const float4 v = reinterpret_cast<const float4*>(in)[i];
  short4 o;
  o.x = f2bf(v.x); o.y = f2bf(v.y); o.z = f2bf(v.z); o.w = f2bf(v.w);
  reinterpret_cast<short4*>(out)[i] = o;
}

// ------- batched transpose [batch][R][C] -> [batch][C][R], out bf16 -------
template <typename Tin>
__global__ void k_tr(const Tin* __restrict__ in, short* __restrict__ out, int R, int C) {
  __shared__ float tile[32][33];
  const int bz = blockIdx.z;
  const int r0 = blockIdx.y * 32, c0 = blockIdx.x * 32;
  const int tx = threadIdx.x & 31, ty = threadIdx.x >> 5;  // ty in 0..7
  const Tin* ip = in + (size_t)bz * R * C;
  short* op = out + (size_t)bz * R * C;
#pragma unroll
  for (int k = 0; k < 4; k++)
    tile[ty + k * 8][tx] = ldf(ip[(size_t)(r0 + ty + k * 8) * C + c0 + tx]);
  __syncthreads();
#pragma unroll
  for (int k = 0; k < 4; k++)
    op[(size_t)(c0 + ty + k * 8) * R + r0 + tx] = f2bf(tile[tx][ty + k * 8]);
}

// =================== BMxBNxK 8-phase MFMA GEMM (T2+T3+T4+T5+T1) ===================
// C[M][N] = A[M][K] * Bt[N][K]^T ; 512 threads, 8 waves (2M x 4N, 16-stripe interleave)
// LDS dynamic: A0|A1|B0|B1; granule-XOR swizzled; 2-barrier+LGK phase frame (m201).
// Grid MUST be (x, 8); XCD swizzle: y = lin%8 (one B-panel per XCD L2), x = lin/8.
// mode 0: QKV scatter epilogue (q bf16 / kv bf16); mode 2: f32 row-major.

#define FEN asm volatile("" ::: "memory")
#define GBAR __builtin_amdgcn_s_barrier()
#define LGK { asm volatile("s_waitcnt lgkmcnt(0)"); __builtin_amdgcn_sched_barrier(0); }
#define PR1 __builtin_amdgcn_s_setprio(1)
#define PR0 __builtin_amdgcn_s_setprio(0)
#define VMW { if constexpr (LPA + LPB == 4) asm volatile("s_waitcnt vmcnt(4)"); \
              else asm volatile("s_waitcnt vmcnt(3)"); }

// stage one half-tile: LN x global_load_lds(16B)/thread; LDS linear, src pre-swizzled
template <int LN>
DEVINL void stage(char* dst, const short* src, int K, int tid) {
#pragma unroll
  for (int L = 0; L < LN; L++) {
    const int loc = L * 8192 + tid * 16;
    const int row = loc >> 7;
    const int gsw = ((loc >> 4) & 7) ^ (row & 7);
    __builtin_amdgcn_global_load_lds(
        (const __attribute__((address_space(1))) void*)(src + (size_t)row * K + gsw * 8),
        (__attribute__((address_space(3))) void*)(dst + loc), 16, 0, 0);
  }
}

#define SA(BUF, HALF, KT) \
  stage<LPA>((BUF) + (HALF) * (ABY / 2), Am + (size_t)((HALF) * (BM / 2)) * K + (KT) * 64, K, tid)
#define SB(BUF, HALF, KT) \
  stage<LPB>((BUF) + (HALF) * (BBY / 2), Bn + (size_t)((HALF) * (BN / 2)) * K + (KT) * 64, K, tid)

#define RDA(BUF, IH)                                                                   \
  { _Pragma("unroll")                                                                  \
    for (int kf_ = 0; kf_ < KFN; kf_++) {                                              \
      _Pragma("unroll")                                                                \
      for (int kk_ = 0; kk_ < 2; kk_++) {                                              \
        const int row_ = ((IH) * KFN + kf_) * 32 + wr * 16 + lr;                       \
        a[kf_ * 2 + kk_] = *(const bf16x8*)((BUF) + row_ * 128 +                       \
                                            (((kk_ * 4 + lu) ^ (lr & 7)) << 4));       \
      } } }

#define RDB(BUF, JH)                                                                   \
  { _Pragma("unroll")                                                                  \
    for (int jf_ = 0; jf_ < JFN; jf_++) {                                              \
      _Pragma("unroll")                                                                \
      for (int kk_ = 0; kk_ < 2; kk_++) {                                              \
        const int row_ = ((JH) * JFN + jf_) * 64 + wc * 16 + lr;                       \
        b[jf_ * 2 + kk_] = *(const bf16x8*)((BUF) + row_ * 128 +                       \
                                            (((kk_ * 4 + lu) ^ (lr & 7)) << 4));       \
      } } }

#define MF(IH, JH)                                                                     \
  { _Pragma("unroll")                                                                  \
    for (int kf_ = 0; kf_ < KFN; kf_++)                                                \
      { _Pragma("unroll")                                                              \
        for (int jf_ = 0; jf_ < JFN; jf_++)                                            \
          { _Pragma("unroll")                                                          \
            for (int kk_ = 0; kk_ < 2; kk_++)                                          \
              acc[(IH) * KFN + kf_][(JH) * JFN + jf_] =                                \
                  __builtin_amdgcn_mfma_f32_16x16x32_bf16(                             \
                      a[kf_ * 2 + kk_], b[jf_ * 2 + kk_],                              \
                      acc[(IH) * KFN + kf_][(JH) * JFN + jf_], 0, 0, 0);               \
          } } }

template <int BM, int BN>
__global__ __launch_bounds__(512, 2) void k_gemm256(
    const short* __restrict__ A, const short* __restrict__ Bt,
    void* __restrict__ Out0, void* __restrict__ Out1,
    int N, int K, int mode) {
  constexpr int LPA = BM / 128;   // loads/thread per A half-tile
  constexpr int LPB = BN / 128;   // loads/thread per B half-tile
  constexpr int KFN = BM / 64;    // 32-row A groups per M-half
  constexpr int JFN = BN / 128;   // 64-row B groups per N-half
  constexpr int ABY = BM * 128;   // bytes per A buffer [BM][64]
  constexpr int BBY = BN * 128;   // bytes per B buffer [BN][64]
  extern __shared__ __align__(16) char sm[];
  char* A0 = sm;
  char* A1 = sm + ABY;
  char* B0 = sm + 2 * ABY;
  char* B1 = sm + 2 * ABY + BBY;
  // T1: XCD swizzle. Dispatch round-robins lin%8 across XCDs -> give each XCD one
  // n-column (B panel L2-resident), m varies within XCD.
  const int lin = blockIdx.x + gridDim.x * blockIdx.y;
  const int m0 = (lin >> 3) * BM, n0 = (lin & 7) * BN;
  const int tid = threadIdx.x, lane = tid & 63, w = tid >> 6;
  const int wr = w & 1, wc = w >> 1;  // 2M x 4N waves, 16-row/16-col stripes
  const int lr = lane & 15, lu = lane >> 4;
  const short* Am = A + (size_t)m0 * K;
  const short* Bn = Bt + (size_t)n0 * K;
  f32x4 acc[KFN * 2][JFN * 2] = {};
  bf16x8 a[KFN * 2], b[JFN * 2];
  const int NIT = K >> 7;
  const int TMAX = (K >> 6) - 1;

  // prologue: t0 full + t1.{Ah0,Bh1}; wait t0 (leave t1's LPA+LPB loads in flight)
  SA(A0, 0, 0); SB(B0, 1, 0); SA(A0, 1, 0); SB(B0, 0, 0);
  SA(A1, 0, 1); SB(B1, 1, 1);
  VMW; FEN; GBAR;

  for (int it = 0; it < NIT; ++it) {
    const int t1 = 2 * it + 1;
    const int t2 = (2 * it + 2 < TMAX) ? 2 * it + 2 : TMAX;
    const int t3 = (2 * it + 3 < TMAX) ? 2 * it + 3 : TMAX;
    // Ph0: quadrant (0,0) of even tile
    RDA(A0, 0); RDB(B0, 0); SA(A1, 1, t1);
    FEN; GBAR; LGK; PR1; MF(0, 0); PR0; FEN; GBAR;
    // Ph1: (0,1)
    RDB(B0, 1); SB(B1, 0, t1);
    FEN; GBAR; LGK; PR1; MF(0, 1); PR0; FEN; GBAR;
    // Ph2: (1,1)
    RDA(A0, 1); SA(A0, 0, t2);
    FEN; GBAR; LGK; PR1; MF(1, 1); PR0; FEN; GBAR;
    // Ph3: (1,0)  [odd-tile buffers complete after this wait]
    RDB(B0, 0); SB(B0, 1, t2);
    FEN; GBAR; LGK; PR1; MF(1, 0); PR0; VMW; FEN; GBAR;
    // Ph4: (0,0) of odd tile
    RDA(A1, 0); RDB(B1, 0); SA(A0, 1, t2);
    FEN; GBAR; LGK; PR1; MF(0, 0); PR0; FEN; GBAR;
    // Ph5: (0,1)
    RDB(B1, 1); SB(B0, 0, t2);
    FEN; GBAR; LGK; PR1; MF(0, 1); PR0; FEN; GBAR;
    // Ph6: (1,1)
    RDA(A1, 1); SA(A1, 0, t3);
    FEN; GBAR; LGK; PR1; MF(1, 1); PR0; FEN; GBAR;
    // Ph7: (1,0)  [even-tile buffers complete after this wait]
    RDB(B1, 0); SB(B1, 1, t3);
    FEN; GBAR; LGK; PR1; MF(1, 0); PR0; VMW; FEN; GBAR;
  }

  // epilogue
#pragma unroll
  for (int k = 0; k < KFN * 2; k++)
#pragma unroll
    for (int j = 0; j < JFN * 2; j++)
#pragma unroll
      for (int r = 0; r < 4; r++) {
        const int m = m0 + k * 32 + wr * 16 + lu * 4 + r;
        const int n = n0 + j * 64 + wc * 16 + lr;
        const float v = acc[k][j][r];
        if (mode == 2) {
          ((float*)Out0)[(size_t)m * N + n] = v;
        } else {
          const int bb = m >> 11, t = m & 2047;
          if (n < 2048) {  // q: [b][head][t][h]
            ((short*)Out0)[(((size_t)(bb * 16 + (n >> 7))) << 18) + t * 128 + (n & 127)] = f2bf(v);
          } else {  // kv: [c][b][kv][t][h]
            const int nn = n - 2048;
            ((short*)Out1)[(((size_t)(((nn >> 9) * 2 + bb) * 4 + ((nn >> 7) & 3))) << 18) +
                           t * 128 + (nn & 127)] = f2bf(v);
          }
        }
      }
}

// ---------------- in-place RoPE on bf16 [rows][128]; t = row & 2047 ----------------
__global__ void k_rope(short* __restrict__ q, float scale) {
  const int gid = blockIdx.x * blockDim.x + threadIdx.x;
  const int i = gid & 63;
  const int row = gid >> 6;
  const int t = row & 2047;
  short* p = q + (size_t)row * 128;
  const float inv = __expf(-(float)i * (float)(9.210340371976184 / 64.0));  // 10000^{-i/64}
  const float ang = (float)t * inv;
  float sn, cs;
  sincosf(ang, &sn, &cs);
  const float x1 = bf2f(p[i]), x2 = bf2f(p[i + 64]);
  p[i] = f2bf((x1 * cs - x2 * sn) * scale);
  p[i + 64] = f2bf((x2 * cs + x1 * sn) * scale);
}

// ---------------- flash attention, sliding window + tanh soft-cap ----------------
// Swapped QK^T: sc = mfma(K,Q) -> sc[cg][r] = S[s=s0+cg*16+lu*4+r][t=tw+lr].
// Soft-cap via cubic: 50*tanh(x/50) ~= x - x^3/7500 (err < 2e-3 at |x|=10).
// Fixed-max softmax (cap bounds logits): p = exp(cap); scalar lsum per lane.
__global__ __launch_bounds__(256) void k_attn(
    const short* __restrict__ q, const short* __restrict__ kk,
    const short* __restrict__ vT, short* __restrict__ enc) {
  __shared__ __align__(16) short lK[64 * 128];   // [s][h], byte ^= ((s&7)<<4)
  __shared__ __align__(16) short lV[128 * 64];   // [h][s], byte ^= ((h&7)<<4)
  __shared__ __align__(16) short lP[4][16 * 64]; // per-wave P [t][s], byte ^= ((t&7)<<4)
  const int bn = blockIdx.x, b = bn >> 4, n = bn & 15, kv = n >> 2;
  const int qt0 = (31 - blockIdx.y) * 64;  // heavy blocks dispatched first
  const int tid = threadIdx.x, lane = tid & 63, w = tid >> 6;
  const int lr = lane & 15, lu = lane >> 4;
  const short* qbase = q + (((size_t)(b * 16 + n)) << 18) + (size_t)(qt0 + w * 16) * 128;
  bf16x8 qa[4];
#pragma unroll
  for (int c = 0; c < 4; c++)
    qa[c] = *reinterpret_cast<const bf16x8*>(qbase + lr * 128 + c * 32 + lu * 8);
  f32x4 o[8] = {};
  float lsum = 0.f;
  const short* kbase = kk + (((size_t)(b * 4 + kv)) << 18);
  const short* vbase = vT + (((size_t)(b * 4 + kv)) << 18);
  char* lPw = (char*)lP[w];
  const int tw = qt0 + w * 16;
  const int t_row = tw + lu * 4;
  int st0 = qt0 - 1023; if (st0 < 0) st0 = 0;
  st0 >>= 6;
  const int stE = (qt0 + 63) >> 6;
  for (int st = st0; st <= stE; st++) {
    const int s0 = st << 6;
#pragma unroll
    for (int c = 0; c < 4; c++) {
      const int L = w * 4096 + c * 1024 + lane * 16;  // byte offset in 16 KiB tile
      {  // K tile: linear LDS dest, pre-swizzled global source
        const int s = L >> 8, slot = (L >> 4) & 15;
        const int sp = slot ^ (s & 7);
        __builtin_amdgcn_global_load_lds(
            (const __attribute__((address_space(1))) void*)(kbase + (size_t)(s0 + s) * 128 + sp * 8),
            (__attribute__((address_space(3))) void*)((char*)lK + L), 16, 0, 0);
      }
      {  // V tile
        const int h = L >> 7, slot = (L >> 4) & 7;
        const int u = slot ^ (h & 7);
        __builtin_amdgcn_global_load_lds(
            (const __attribute__((address_space(1))) void*)(vbase + (size_t)h * 2048 + s0 + u * 8),
            (__attribute__((address_space(3))) void*)((char*)lV + L), 16, 0, 0);
      }
    }
    __syncthreads();
    // ---- QK^T (swapped): sc[cg][r] = S[s=cg*16+lu*4+r][t=lr] ----
    f32x4 sc[4];
    __builtin_amdgcn_s_setprio(1);
#pragma unroll
    for (int cg = 0; cg < 4; cg++) {
      sc[cg] = (f32x4){0.f, 0.f, 0.f, 0.f};
      const int s = cg * 16 + lr;
      const int sw = (s & 7) << 4;
#pragma unroll
      for (int c = 0; c < 4; c++) {
        bf16x8 kb = *reinterpret_cast<const bf16x8*>((char*)lK + s * 256 + (((c * 4 + lu) << 4) ^ sw));
        sc[cg] = __builtin_amdgcn_mfma_f32_16x16x32_bf16(kb, qa[c], sc[cg], 0, 0, 0);
      }
    }
    __builtin_amdgcn_s_setprio(0);
    // ---- cubic soft-cap + exp, pack pairs, write P (b32) ----
    const bool allv = (s0 + 63 <= tw) && (s0 + 1008 >= tw);
    if (allv) {
#pragma unroll
      for (int cg = 0; cg < 4; cg++) {
        float pr[4];
#pragma unroll
        for (int r = 0; r < 4; r++) {
          const float x = sc[cg][r];
          const float cap = __builtin_fmaf(x * x * x, -1.3333333e-4f, x);
          const float p = __expf(cap);
          lsum += p;
          pr[r] = p;
        }
        unsigned w0, w1;
        asm("v_cvt_pk_bf16_f32 %0, %1, %2" : "=v"(w0) : "v"(pr[0]), "v"(pr[1]));
        asm("v_cvt_pk_bf16_f32 %0, %1, %2" : "=v"(w1) : "v"(pr[2]), "v"(pr[3]));
        const int sb = (cg * 16 + lu * 4) << 1;  // byte offset of s-pair base
        *(unsigned*)(lPw + (lr << 7) + (sb ^ ((lr & 7) << 4))) = w0;
        *(unsigned*)(lPw + (lr << 7) + ((sb + 4) ^ ((lr & 7) << 4))) = w1;
      }
    } else {
      const int t = tw + lr;
#pragma unroll
      for (int cg = 0; cg < 4; cg++) {
        float pr[4];
#pragma unroll
        for (int r = 0; r < 4; r++) {
          const int s = s0 + cg * 16 + lu * 4 + r;
          const bool valid = (s <= t) & (s + 1024 > t);
          const float x = sc[cg][r];
          const float cap = __builtin_fmaf(x * x * x, -1.3333333e-4f, x);
          float p = __expf(cap);
          p = valid ? p : 0.f;
          lsum += p;
          pr[r] = p;
        }
        unsigned w0, w1;
        asm("v_cvt_pk_bf16_f32 %0, %1, %2" : "=v"(w0) : "v"(pr[0]), "v"(pr[1]));
        asm("v_cvt_pk_bf16_f32 %0, %1, %2" : "=v"(w1) : "v"(pr[2]), "v"(pr[3]));
        const int sb = (cg * 16 + lu * 4) << 1;
        *(unsigned*)(lPw + (lr << 7) + (sb ^ ((lr & 7) << 4))) = w0;
        *(unsigned*)(lPw + (lr << 7) + ((sb + 4) ^ ((lr & 7) << 4))) = w1;
      }
    }
    // ---- PV: o[oc] += P[t][s] * V[s][h] (orientation unchanged) ----
#pragma unroll
    for (int ks = 0; ks < 2; ks++) {
      const bf16x8 pf = *reinterpret_cast<const bf16x8*>(
          lPw + (lr << 7) + ((ks * 64 + lu * 16) ^ ((lr & 7) << 4)));
      __builtin_amdgcn_s_setprio(1);
#pragma unroll
      for (int oc = 0; oc < 8; oc++) {
        const int h = oc * 16 + lr;
        bf16x8 vb = *reinterpret_cast<const bf16x8*>(
            (char*)lV + h * 128 + (((ks * 4 + lu) << 4) ^ ((h & 7) << 4)));
        o[oc] = __builtin_amdgcn_mfma_f32_16x16x32_bf16(pf, vb, o[oc], 0, 0, 0);
      }
      __builtin_amdgcn_s_setprio(0);
    }
    __syncthreads();
  }
  // ---- reduce: lane holds partial sum for column t=tw+lr ----
  float tot = lsum;
  tot += __shfl_xor(tot, 16, 64);
  tot += __shfl_xor(tot, 32, 64);
  float rs[4];
#pragma unroll
  for (int r = 0; r < 4; r++)
    rs[r] = 1.f / __shfl(tot, lu * 4 + r, 64);  // sum for t=tw+lu*4+r held at lane lu*4+r
#pragma unroll
  for (int oc = 0; oc < 8; oc++)
#pragma unroll
    for (int r = 0; r < 4; r++) {
      const int t = t_row + r;
      enc[((size_t)b * 2048 + t) * 2048 + n * 128 + oc * 16 + lr] = f2bf(o[oc][r] * rs[r]);
    }
}

extern "C" void kernel_launch(void* const* d_in, const int* in_sizes, int n_in,
                              void* d_out, int out_size, void* d_ws, size_t ws_size,
                              hipStream_t stream) {
  (void)in_sizes; (void)n_in; (void)out_size; (void)ws_size;
  const float* x    = (const float*)d_in[0];
  const float* wq   = (const float*)d_in[3];
  const float* wkv  = (const float*)d_in[4];
  const float* wvec = (const float*)d_in[5];
  char* ws = (char*)d_ws;
  size_t off = 0;
  short* xbf   = (short*)(ws + off); off += (size_t)8388608 * 2;            // x bf16 [B*T][D]
  short* wall  = (short*)(ws + off); off += (size_t)3072 * 2048 * 2;        // [wqT|wkT|wvT] rows x K
  short* wvecT = (short*)(ws + off); off += (size_t)2048 * 2048 * 2;        // [d][nh]
  short* qbuf  = (short*)(ws + off); off += (size_t)2 * 16 * 2048 * 128 * 2; // q bf16 [b][n][t][h]
  short* kvbuf = (short*)(ws + off); off += (size_t)2 * 2 * 4 * 2048 * 128 * 2; // [c][b][kv][t][h]
  short* vTbuf = (short*)(ws + off); off += (size_t)2 * 4 * 128 * 2048 * 2; // v^T [b][kv][h][s]
  short* encb  = (short*)(ws + off); off += (size_t)2 * 2048 * 2048 * 2;    // [b][t][nh]

  hipFuncSetAttribute(reinterpret_cast<const void*>(&k_gemm256<128, 384>),
                      hipFuncAttributeMaxDynamicSharedMemorySize, 131072);
  hipFuncSetAttribute(reinterpret_cast<const void*>(&k_gemm256<128, 256>),
                      hipFuncAttributeMaxDynamicSharedMemorySize, 98304);

  k_cvt<<<8192, 256, 0, stream>>>(x, xbf, 2097152);
  k_tr<float><<<dim3(4, 64, 16), 256, 0, stream>>>(wq, wall, 2048, 128);
  k_tr<float><<<dim3(4, 64, 4), 256, 0, stream>>>(wkv, wall + 4194304, 2048, 128);
  k_tr<float><<<dim3(4, 64, 4), 256, 0, stream>>>(wkv + 1048576, wall + 5242880, 2048, 128);
  k_tr<float><<<dim3(64, 64, 1), 256, 0, stream>>>(wvec, wvecT, 2048, 2048);
  k_gemm256<128, 384><<<dim3(32, 8), 512, 131072, stream>>>(xbf, wall, qbuf, kvbuf,
                                                            3072, 2048, 0);
  k_rope<<<16384, 256, 0, stream>>>(qbuf, 0.08838834764831845f);  // 1/sqrt(128)
  k_rope<<<4096, 256, 0, stream>>>(kvbuf, 1.0f);
  k_tr<short><<<dim3(4, 64, 8), 256, 0, stream>>>(kvbuf + 2097152, vTbuf, 2048, 128);
  k_attn<<<dim3(32, 32), 256, 0, stream>>>(qbuf, kvbuf, vTbuf, encb);
  k_gemm256<128, 256><<<dim3(32, 8), 512, 98304, stream>>>(encb, wvecT, d_out, nullptr,
                                                           2048, 2048, 2);
}

// Round 9
// 176.839 us; speedup vs baseline: 1.8375x; 1.0675x over previous
//
#include <hip/hip_runtime.h>
#include <hip/hip_bf16.h>

#define DEVINL static __device__ __forceinline__

typedef __attribute__((ext_vector_type(4))) float f32x4;
typedef __attribute__((ext_vector_type(8))) short bf16x8;

DEVINL short f2bf(float f) {
  __hip_bfloat16 h = __float2bfloat16(f);
  union { __hip_bfloat16 h; short s; } u; u.h = h; return u.s;
}
DEVINL float bf2f(short s) {
  union { unsigned u; float f; } v; v.u = ((unsigned)(unsigned short)s) << 16;
  return v.f;
}
DEVINL float ldf(float x) { return x; }
DEVINL float ldf(short x) { return bf2f(x); }

// ---------------- f32 -> bf16 convert, 4 elems/thread ----------------
__global__ void k_cvt(const float* __restrict__ in, short* __restrict__ out, int n4) {
  int i = blockIdx.x * blockDim.x + threadIdx.x;
  if (i >= n4) return;
  const float4 v = reinterpret_cast<const float4*>(in)[i];
  short4 o;
  o.x = f2bf(v.x); o.y = f2bf(v.y); o.z = f2bf(v.z); o.w = f2bf(v.w);
  reinterpret_cast<short4*>(out)[i] = o;
}

// ------- batched transpose [batch][R][C] -> [batch][C][R], out bf16 -------
template <typename Tin>
__global__ void k_tr(const Tin* __restrict__ in, short* __restrict__ out, int R, int C) {
  __shared__ float tile[32][33];
  const int bz = blockIdx.z;
  const int r0 = blockIdx.y * 32, c0 = blockIdx.x * 32;
  const int tx = threadIdx.x & 31, ty = threadIdx.x >> 5;  // ty in 0..7
  const Tin* ip = in + (size_t)bz * R * C;
  short* op = out + (size_t)bz * R * C;
#pragma unroll
  for (int k = 0; k < 4; k++)
    tile[ty + k * 8][tx] = ldf(ip[(size_t)(r0 + ty + k * 8) * C + c0 + tx]);
  __syncthreads();
#pragma unroll
  for (int k = 0; k < 4; k++)
    op[(size_t)(c0 + ty + k * 8) * R + r0 + tx] = f2bf(tile[tx][ty + k * 8]);
}

// =================== BMxBNxK 8-phase MFMA GEMM (T2+T3+T4+T5+T1) ===================
// C[M][N] = A[M][K] * Bt[N][K]^T ; 512 threads, 8 waves (2M x 4N, 16-stripe interleave)
// LDS dynamic: A0|A1|B0|B1; granule-XOR swizzled; 2-barrier+LGK phase frame (m201).
// Grid MUST be (x, 8); XCD swizzle: y = lin%8 (one B-panel per XCD L2), x = lin/8.
// mode 0: QKV scatter epilogue with FUSED RoPE (q scale+rotate / k rotate / v pass);
// mode 2: f32 row-major.

#define FEN asm volatile("" ::: "memory")
#define GBAR __builtin_amdgcn_s_barrier()
#define LGK { asm volatile("s_waitcnt lgkmcnt(0)"); __builtin_amdgcn_sched_barrier(0); }
#define PR1 __builtin_amdgcn_s_setprio(1)
#define PR0 __builtin_amdgcn_s_setprio(0)
#define VMW { if constexpr (LPA + LPB == 4) asm volatile("s_waitcnt vmcnt(4)"); \
              else asm volatile("s_waitcnt vmcnt(3)"); }

// stage one half-tile: LN x global_load_lds(16B)/thread; LDS linear, src pre-swizzled
template <int LN>
DEVINL void stage(char* dst, const short* src, int K, int tid) {
#pragma unroll
  for (int L = 0; L < LN; L++) {
    const int loc = L * 8192 + tid * 16;
    const int row = loc >> 7;
    const int gsw = ((loc >> 4) & 7) ^ (row & 7);
    __builtin_amdgcn_global_load_lds(
        (const __attribute__((address_space(1))) void*)(src + (size_t)row * K + gsw * 8),
        (__attribute__((address_space(3))) void*)(dst + loc), 16, 0, 0);
  }
}

#define SA(BUF, HALF, KT) \
  stage<LPA>((BUF) + (HALF) * (ABY / 2), Am + (size_t)((HALF) * (BM / 2)) * K + (KT) * 64, K, tid)
#define SB(BUF, HALF, KT) \
  stage<LPB>((BUF) + (HALF) * (BBY / 2), Bn + (size_t)((HALF) * (BN / 2)) * K + (KT) * 64, K, tid)

#define RDA(BUF, IH)                                                                   \
  { _Pragma("unroll")                                                                  \
    for (int kf_ = 0; kf_ < KFN; kf_++) {                                              \
      _Pragma("unroll")                                                                \
      for (int kk_ = 0; kk_ < 2; kk_++) {                                              \
        const int row_ = ((IH) * KFN + kf_) * 32 + wr * 16 + lr;                       \
        a[kf_ * 2 + kk_] = *(const bf16x8*)((BUF) + row_ * 128 +                       \
                                            (((kk_ * 4 + lu) ^ (lr & 7)) << 4));       \
      } } }

#define RDB(BUF, JH)                                                                   \
  { _Pragma("unroll")                                                                  \
    for (int jf_ = 0; jf_ < JFN; jf_++) {                                              \
      _Pragma("unroll")                                                                \
      for (int kk_ = 0; kk_ < 2; kk_++) {                                              \
        const int row_ = ((JH) * JFN + jf_) * 64 + wc * 16 + lr;                       \
        b[jf_ * 2 + kk_] = *(const bf16x8*)((BUF) + row_ * 128 +                       \
                                            (((kk_ * 4 + lu) ^ (lr & 7)) << 4));       \
      } } }

#define MF(IH, JH)                                                                     \
  { _Pragma("unroll")                                                                  \
    for (int kf_ = 0; kf_ < KFN; kf_++)                                                \
      { _Pragma("unroll")                                                              \
        for (int jf_ = 0; jf_ < JFN; jf_++)                                            \
          { _Pragma("unroll")                                                          \
            for (int kk_ = 0; kk_ < 2; kk_++)                                          \
              acc[(IH) * KFN + kf_][(JH) * JFN + jf_] =                                \
                  __builtin_amdgcn_mfma_f32_16x16x32_bf16(                             \
                      a[kf_ * 2 + kk_], b[jf_ * 2 + kk_],                              \
                      acc[(IH) * KFN + kf_][(JH) * JFN + jf_], 0, 0, 0);               \
          } } }

template <int BM, int BN>
__global__ __launch_bounds__(512, 2) void k_gemm256(
    const short* __restrict__ A, const short* __restrict__ Bt,
    void* __restrict__ Out0, void* __restrict__ Out1,
    int N, int K, int mode) {
  constexpr int LPA = BM / 128;   // loads/thread per A half-tile
  constexpr int LPB = BN / 128;   // loads/thread per B half-tile
  constexpr int KFN = BM / 64;    // 32-row A groups per M-half
  constexpr int JFN = BN / 128;   // 64-row B groups per N-half
  constexpr int ABY = BM * 128;   // bytes per A buffer [BM][64]
  constexpr int BBY = BN * 128;   // bytes per B buffer [BN][64]
  extern __shared__ __align__(16) char sm[];
  char* A0 = sm;
  char* A1 = sm + ABY;
  char* B0 = sm + 2 * ABY;
  char* B1 = sm + 2 * ABY + BBY;
  // T1: XCD swizzle. Dispatch round-robins lin%8 across XCDs -> give each XCD one
  // n-column (B panel L2-resident), m varies within XCD.
  const int lin = blockIdx.x + gridDim.x * blockIdx.y;
  const int m0 = (lin >> 3) * BM, n0 = (lin & 7) * BN;
  const int tid = threadIdx.x, lane = tid & 63, w = tid >> 6;
  const int wr = w & 1, wc = w >> 1;  // 2M x 4N waves, 16-row/16-col stripes
  const int lr = lane & 15, lu = lane >> 4;
  const short* Am = A + (size_t)m0 * K;
  const short* Bn = Bt + (size_t)n0 * K;
  f32x4 acc[KFN * 2][JFN * 2] = {};
  bf16x8 a[KFN * 2], b[JFN * 2];
  const int NIT = K >> 7;
  const int TMAX = (K >> 6) - 1;

  // prologue: t0 full + t1.{Ah0,Bh1}; wait t0 (leave t1's LPA+LPB loads in flight)
  SA(A0, 0, 0); SB(B0, 1, 0); SA(A0, 1, 0); SB(B0, 0, 0);
  SA(A1, 0, 1); SB(B1, 1, 1);
  VMW; FEN; GBAR;

  for (int it = 0; it < NIT; ++it) {
    const int t1 = 2 * it + 1;
    const int t2 = (2 * it + 2 < TMAX) ? 2 * it + 2 : TMAX;
    const int t3 = (2 * it + 3 < TMAX) ? 2 * it + 3 : TMAX;
    // Ph0: quadrant (0,0) of even tile
    RDA(A0, 0); RDB(B0, 0); SA(A1, 1, t1);
    FEN; GBAR; LGK; PR1; MF(0, 0); PR0; FEN; GBAR;
    // Ph1: (0,1)
    RDB(B0, 1); SB(B1, 0, t1);
    FEN; GBAR; LGK; PR1; MF(0, 1); PR0; FEN; GBAR;
    // Ph2: (1,1)
    RDA(A0, 1); SA(A0, 0, t2);
    FEN; GBAR; LGK; PR1; MF(1, 1); PR0; FEN; GBAR;
    // Ph3: (1,0)  [odd-tile buffers complete after this wait]
    RDB(B0, 0); SB(B0, 1, t2);
    FEN; GBAR; LGK; PR1; MF(1, 0); PR0; VMW; FEN; GBAR;
    // Ph4: (0,0) of odd tile
    RDA(A1, 0); RDB(B1, 0); SA(A0, 1, t2);
    FEN; GBAR; LGK; PR1; MF(0, 0); PR0; FEN; GBAR;
    // Ph5: (0,1)
    RDB(B1, 1); SB(B0, 0, t2);
    FEN; GBAR; LGK; PR1; MF(0, 1); PR0; FEN; GBAR;
    // Ph6: (1,1)
    RDA(A1, 1); SA(A1, 0, t3);
    FEN; GBAR; LGK; PR1; MF(1, 1); PR0; FEN; GBAR;
    // Ph7: (1,0)  [even-tile buffers complete after this wait]
    RDB(B1, 0); SB(B1, 1, t3);
    FEN; GBAR; LGK; PR1; MF(1, 0); PR0; VMW; FEN; GBAR;
  }

  // ---------------- epilogue ----------------
  if (mode == 2) {
#pragma unroll
    for (int k = 0; k < KFN * 2; k++)
#pragma unroll
      for (int j = 0; j < JFN * 2; j++)
#pragma unroll
        for (int r = 0; r < 4; r++) {
          const int m = m0 + k * 32 + wr * 16 + lu * 4 + r;
          const int n = n0 + j * 64 + wc * 16 + lr;
          ((float*)Out0)[(size_t)m * N + n] = acc[k][j][r];
        }
  } else {
    // Fused RoPE: fragment pair (j=2u, j=2u+1) holds (h, h+64) for same t.
    // Per-thread rotation index i = wc*16+lr is constant.
    const int i_rope = wc * 16 + lr;
    const float inv = __expf(-(float)i_rope * (float)(9.210340371976184 / 64.0));
#pragma unroll
    for (int k = 0; k < KFN * 2; k++) {
      float sn[4], cs[4];
#pragma unroll
      for (int r = 0; r < 4; r++) {
        const int m = m0 + k * 32 + wr * 16 + lu * 4 + r;
        sincosf((float)(m & 2047) * inv, &sn[r], &cs[r]);
      }
#pragma unroll
      for (int u = 0; u < JFN; u++) {
        const int n_lo = n0 + (2 * u) * 64 + wc * 16 + lr;  // h = i_rope (<64)
        const int reg = (n_lo < 2048) ? 0 : ((n_lo < 2560) ? 1 : 2);  // q/k/v
#pragma unroll
        for (int r = 0; r < 4; r++) {
          const int m = m0 + k * 32 + wr * 16 + lu * 4 + r;
          const int bb = m >> 11, t = m & 2047;
          float lo = acc[k][2 * u][r], hi = acc[k][2 * u + 1][r];
          if (reg < 2) {  // rotate
            const float l2 = lo * cs[r] - hi * sn[r];
            const float h2 = hi * cs[r] + lo * sn[r];
            const float sc = (reg == 0) ? 0.08838834764831845f : 1.0f;
            lo = l2 * sc; hi = h2 * sc;
          }
#pragma unroll
          for (int p = 0; p < 2; p++) {
            const int n = n_lo + p * 64;
            const float v = p ? hi : lo;
            if (n < 2048) {  // q: [b][head][t][h]
              ((short*)Out0)[(((size_t)(bb * 16 + (n >> 7))) << 18) + t * 128 + (n & 127)] =
                  f2bf(v);
            } else {  // kv: [c][b][kv][t][h]
              const int nn = n - 2048;
              ((short*)Out1)[(((size_t)(((nn >> 9) * 2 + bb) * 4 + ((nn >> 7) & 3))) << 18) +
                             t * 128 + (nn & 127)] = f2bf(v);
            }
          }
        }
      }
    }
  }
}

// ---------------- flash attention, sliding window + tanh soft-cap ----------------
// Swapped QK^T: sc = mfma(K,Q) -> sc[cg][r] = S[s=s0+cg*16+lu*4+r][t=tw+lr].
// Soft-cap via cubic: 50*tanh(x/50) ~= x - x^3/7500 (err < 2e-3 at |x|=10).
// Fixed-max softmax (cap bounds logits): p = exp(cap); scalar lsum per lane.
__global__ __launch_bounds__(256) void k_attn(
    const short* __restrict__ q, const short* __restrict__ kk,
    const short* __restrict__ vT, short* __restrict__ enc) {
  __shared__ __align__(16) short lK[64 * 128];   // [s][h], byte ^= ((s&7)<<4)
  __shared__ __align__(16) short lV[128 * 64];   // [h][s], byte ^= ((h&7)<<4)
  __shared__ __align__(16) short lP[4][16 * 64]; // per-wave P [t][s], byte ^= ((t&7)<<4)
  const int bn = blockIdx.x, b = bn >> 4, n = bn & 15, kv = n >> 2;
  const int qt0 = (31 - blockIdx.y) * 64;  // heavy blocks dispatched first
  const int tid = threadIdx.x, lane = tid & 63, w = tid >> 6;
  const int lr = lane & 15, lu = lane >> 4;
  const short* qbase = q + (((size_t)(b * 16 + n)) << 18) + (size_t)(qt0 + w * 16) * 128;
  bf16x8 qa[4];
#pragma unroll
  for (int c = 0; c < 4; c++)
    qa[c] = *reinterpret_cast<const bf16x8*>(qbase + lr * 128 + c * 32 + lu * 8);
  f32x4 o[8] = {};
  float lsum = 0.f;
  const short* kbase = kk + (((size_t)(b * 4 + kv)) << 18);
  const short* vbase = vT + (((size_t)(b * 4 + kv)) << 18);
  char* lPw = (char*)lP[w];
  const int tw = qt0 + w * 16;
  const int t_row = tw + lu * 4;
  int st0 = qt0 - 1023; if (st0 < 0) st0 = 0;
  st0 >>= 6;
  const int stE = (qt0 + 63) >> 6;
  for (int st = st0; st <= stE; st++) {
    const int s0 = st << 6;
#pragma unroll
    for (int c = 0; c < 4; c++) {
      const int L = w * 4096 + c * 1024 + lane * 16;  // byte offset in 16 KiB tile
      {  // K tile: linear LDS dest, pre-swizzled global source
        const int s = L >> 8, slot = (L >> 4) & 15;
        const int sp = slot ^ (s & 7);
        __builtin_amdgcn_global_load_lds(
            (const __attribute__((address_space(1))) void*)(kbase + (size_t)(s0 + s) * 128 + sp * 8),
            (__attribute__((address_space(3))) void*)((char*)lK + L), 16, 0, 0);
      }
      {  // V tile
        const int h = L >> 7, slot = (L >> 4) & 7;
        const int u = slot ^ (h & 7);
        __builtin_amdgcn_global_load_lds(
            (const __attribute__((address_space(1))) void*)(vbase + (size_t)h * 2048 + s0 + u * 8),
            (__attribute__((address_space(3))) void*)((char*)lV + L), 16, 0, 0);
      }
    }
    __syncthreads();
    // ---- QK^T (swapped): sc[cg][r] = S[s=cg*16+lu*4+r][t=lr] ----
    f32x4 sc[4];
    __builtin_amdgcn_s_setprio(1);
#pragma unroll
    for (int cg = 0; cg < 4; cg++) {
      sc[cg] = (f32x4){0.f, 0.f, 0.f, 0.f};
      const int s = cg * 16 + lr;
      const int sw = (s & 7) << 4;
#pragma unroll
      for (int c = 0; c < 4; c++) {
        bf16x8 kb = *reinterpret_cast<const bf16x8*>((char*)lK + s * 256 + (((c * 4 + lu) << 4) ^ sw));
        sc[cg] = __builtin_amdgcn_mfma_f32_16x16x32_bf16(kb, qa[c], sc[cg], 0, 0, 0);
      }
    }
    __builtin_amdgcn_s_setprio(0);
    // ---- cubic soft-cap + exp, pack pairs, write P (b32) ----
    const bool allv = (s0 + 63 <= tw) && (s0 + 1008 >= tw);
    if (allv) {
#pragma unroll
      for (int cg = 0; cg < 4; cg++) {
        float pr[4];
#pragma unroll
        for (int r = 0; r < 4; r++) {
          const float x = sc[cg][r];
          const float cap = __builtin_fmaf(x * x * x, -1.3333333e-4f, x);
          const float p = __expf(cap);
          lsum += p;
          pr[r] = p;
        }
        unsigned w0, w1;
        asm("v_cvt_pk_bf16_f32 %0, %1, %2" : "=v"(w0) : "v"(pr[0]), "v"(pr[1]));
        asm("v_cvt_pk_bf16_f32 %0, %1, %2" : "=v"(w1) : "v"(pr[2]), "v"(pr[3]));
        const int sb = (cg * 16 + lu * 4) << 1;  // byte offset of s-pair base
        *(unsigned*)(lPw + (lr << 7) + (sb ^ ((lr & 7) << 4))) = w0;
        *(unsigned*)(lPw + (lr << 7) + ((sb + 4) ^ ((lr & 7) << 4))) = w1;
      }
    } else {
      const int t = tw + lr;
#pragma unroll
      for (int cg = 0; cg < 4; cg++) {
        float pr[4];
#pragma unroll
        for (int r = 0; r < 4; r++) {
          const int s = s0 + cg * 16 + lu * 4 + r;
          const bool valid = (s <= t) & (s + 1024 > t);
          const float x = sc[cg][r];
          const float cap = __builtin_fmaf(x * x * x, -1.3333333e-4f, x);
          float p = __expf(cap);
          p = valid ? p : 0.f;
          lsum += p;
          pr[r] = p;
        }
        unsigned w0, w1;
        asm("v_cvt_pk_bf16_f32 %0, %1, %2" : "=v"(w0) : "v"(pr[0]), "v"(pr[1]));
        asm("v_cvt_pk_bf16_f32 %0, %1, %2" : "=v"(w1) : "v"(pr[2]), "v"(pr[3]));
        const int sb = (cg * 16 + lu * 4) << 1;
        *(unsigned*)(lPw + (lr << 7) + (sb ^ ((lr & 7) << 4))) = w0;
        *(unsigned*)(lPw + (lr << 7) + ((sb + 4) ^ ((lr & 7) << 4))) = w1;
      }
    }
    // ---- PV: o[oc] += P[t][s] * V[s][h] (orientation unchanged) ----
#pragma unroll
    for (int ks = 0; ks < 2; ks++) {
      const bf16x8 pf = *reinterpret_cast<const bf16x8*>(
          lPw + (lr << 7) + ((ks * 64 + lu * 16) ^ ((lr & 7) << 4)));
      __builtin_amdgcn_s_setprio(1);
#pragma unroll
      for (int oc = 0; oc < 8; oc++) {
        const int h = oc * 16 + lr;
        bf16x8 vb = *reinterpret_cast<const bf16x8*>(
            (char*)lV + h * 128 + (((ks * 4 + lu) << 4) ^ ((h & 7) << 4)));
        o[oc] = __builtin_amdgcn_mfma_f32_16x16x32_bf16(pf, vb, o[oc], 0, 0, 0);
      }
      __builtin_amdgcn_s_setprio(0);
    }
    __syncthreads();
  }
  // ---- reduce: lane holds partial sum for column t=tw+lr ----
  float tot = lsum;
  tot += __shfl_xor(tot, 16, 64);
  tot += __shfl_xor(tot, 32, 64);
  float rs[4];
#pragma unroll
  for (int r = 0; r < 4; r++)
    rs[r] = 1.f / __shfl(tot, lu * 4 + r, 64);  // sum for t=tw+lu*4+r held at lane lu*4+r
#pragma unroll
  for (int oc = 0; oc < 8; oc++)
#pragma unroll
    for (int r = 0; r < 4; r++) {
      const int t = t_row + r;
      enc[((size_t)b * 2048 + t) * 2048 + n * 128 + oc * 16 + lr] = f2bf(o[oc][r] * rs[r]);
    }
}

extern "C" void kernel_launch(void* const* d_in, const int* in_sizes, int n_in,
                              void* d_out, int out_size, void* d_ws, size_t ws_size,
                              hipStream_t stream) {
  (void)in_sizes; (void)n_in; (void)out_size; (void)ws_size;
  const float* x    = (const float*)d_in[0];
  const float* wq   = (const float*)d_in[3];
  const float* wkv  = (const float*)d_in[4];
  const float* wvec = (const float*)d_in[5];
  char* ws = (char*)d_ws;
  size_t off = 0;
  short* xbf   = (short*)(ws + off); off += (size_t)8388608 * 2;            // x bf16 [B*T][D]
  short* wall  = (short*)(ws + off); off += (size_t)3072 * 2048 * 2;        // [wqT|wkT|wvT] rows x K
  short* wvecT = (short*)(ws + off); off += (size_t)2048 * 2048 * 2;        // [d][nh]
  short* qbuf  = (short*)(ws + off); off += (size_t)2 * 16 * 2048 * 128 * 2; // q bf16 [b][n][t][h]
  short* kvbuf = (short*)(ws + off); off += (size_t)2 * 2 * 4 * 2048 * 128 * 2; // [c][b][kv][t][h]
  short* vTbuf = (short*)(ws + off); off += (size_t)2 * 4 * 128 * 2048 * 2; // v^T [b][kv][h][s]
  short* encb  = (short*)(ws + off); off += (size_t)2 * 2048 * 2048 * 2;    // [b][t][nh]

  hipFuncSetAttribute(reinterpret_cast<const void*>(&k_gemm256<128, 384>),
                      hipFuncAttributeMaxDynamicSharedMemorySize, 131072);
  hipFuncSetAttribute(reinterpret_cast<const void*>(&k_gemm256<128, 256>),
                      hipFuncAttributeMaxDynamicSharedMemorySize, 98304);

  k_cvt<<<8192, 256, 0, stream>>>(x, xbf, 2097152);
  k_tr<float><<<dim3(4, 64, 16), 256, 0, stream>>>(wq, wall, 2048, 128);
  k_tr<float><<<dim3(4, 64, 4), 256, 0, stream>>>(wkv, wall + 4194304, 2048, 128);
  k_tr<float><<<dim3(4, 64, 4), 256, 0, stream>>>(wkv + 1048576, wall + 5242880, 2048, 128);
  k_tr<float><<<dim3(64, 64, 1), 256, 0, stream>>>(wvec, wvecT, 2048, 2048);
  k_gemm256<128, 384><<<dim3(32, 8), 512, 131072, stream>>>(xbf, wall, qbuf, kvbuf,
                                                            3072, 2048, 0);
  k_tr<short><<<dim3(4, 64, 8), 256, 0, stream>>>(kvbuf + 2097152, vTbuf, 2048, 128);
  k_attn<<<dim3(32, 32), 256, 0, stream>>>(qbuf, kvbuf, vTbuf, encb);
  k_gemm256<128, 256><<<dim3(32, 8), 512, 98304, stream>>>(encb, wvecT, d_out, nullptr,
                                                           2048, 2048, 2);
}

// Round 10
// 176.779 us; speedup vs baseline: 1.8382x; 1.0003x over previous
//
#include <hip/hip_runtime.h>
#include <hip/hip_bf16.h>

#define DEVINL static __device__ __forceinline__

typedef __attribute__((ext_vector_type(4))) float f32x4;
typedef __attribute__((ext_vector_type(8))) short bf16x8;

DEVINL short f2bf(float f) {
  __hip_bfloat16 h = __float2bfloat16(f);
  union { __hip_bfloat16 h; short s; } u; u.h = h; return u.s;
}
DEVINL float bf2f(short s) {
  union { unsigned u; float f; } v; v.u = ((unsigned)(unsigned short)s) << 16;
  return v.f;
}
DEVINL float ldf(float x) { return x; }
DEVINL float ldf(short x) { return bf2f(x); }

// ---------------- f32 -> bf16 convert, 4 elems/thread ----------------
__global__ void k_cvt(const float* __restrict__ in, short* __restrict__ out, int n4) {
  int i = blockIdx.x * blockDim.x + threadIdx.x;
  if (i >= n4) return;
  const float4 v = reinterpret_cast<const float4*>(in)[i];
  short4 o;
  o.x = f2bf(v.x); o.y = f2bf(v.y); o.z = f2bf(v.z); o.w = f2bf(v.w);
  reinterpret_cast<short4*>(out)[i] = o;
}

// ------- batched transpose [batch][R][C] -> [batch][C][R], out bf16 -------
template <typename Tin>
__global__ void k_tr(const Tin* __restrict__ in, short* __restrict__ out, int R, int C) {
  __shared__ float tile[32][33];
  const int bz = blockIdx.z;
  const int r0 = blockIdx.y * 32, c0 = blockIdx.x * 32;
  const int tx = threadIdx.x & 31, ty = threadIdx.x >> 5;  // ty in 0..7
  const Tin* ip = in + (size_t)bz * R * C;
  short* op = out + (size_t)bz * R * C;
#pragma unroll
  for (int k = 0; k < 4; k++)
    tile[ty + k * 8][tx] = ldf(ip[(size_t)(r0 + ty + k * 8) * C + c0 + tx]);
  __syncthreads();
#pragma unroll
  for (int k = 0; k < 4; k++)
    op[(size_t)(c0 + ty + k * 8) * R + r0 + tx] = f2bf(tile[tx][ty + k * 8]);
}

// =================== BMxBNxK 8-phase MFMA GEMM (T2+T3+T4+T5+T1) ===================
// C[M][N] = A[M][K] * Bt[N][K]^T ; 512 threads, 8 waves (2M x 4N, 16-stripe interleave)
// LDS dynamic: A0|A1|B0|B1; granule-XOR swizzled. Phase frame = m201 verified form:
// {reads, stage} ; barrier ; lgkmcnt(0) ; setprio1 ; MFMA ; setprio0 ; barrier
// (no sched_barrier, no compiler memory fences — C++ ds_reads are compiler-visible).
// Grid MUST be (x, 8); XCD swizzle: y = lin%8 (one B-panel per XCD L2), x = lin/8.
// mode 0: QKV scatter epilogue with FUSED RoPE; mode 2: f32 row-major.

#define GBAR __builtin_amdgcn_s_barrier()
#define LGK asm volatile("s_waitcnt lgkmcnt(0)")
#define PR1 __builtin_amdgcn_s_setprio(1)
#define PR0 __builtin_amdgcn_s_setprio(0)
#define VMW { if constexpr (LPA + LPB == 4) asm volatile("s_waitcnt vmcnt(4)"); \
              else asm volatile("s_waitcnt vmcnt(3)"); }

// stage one half-tile: LN x global_load_lds(16B)/thread; LDS linear, src pre-swizzled
template <int LN>
DEVINL void stage(char* dst, const short* src, int K, int tid) {
#pragma unroll
  for (int L = 0; L < LN; L++) {
    const int loc = L * 8192 + tid * 16;
    const int row = loc >> 7;
    const int gsw = ((loc >> 4) & 7) ^ (row & 7);
    __builtin_amdgcn_global_load_lds(
        (const __attribute__((address_space(1))) void*)(src + (size_t)row * K + gsw * 8),
        (__attribute__((address_space(3))) void*)(dst + loc), 16, 0, 0);
  }
}

#define SA(BUF, HALF, KT) \
  stage<LPA>((BUF) + (HALF) * (ABY / 2), Am + (size_t)((HALF) * (BM / 2)) * K + (KT) * 64, K, tid)
#define SB(BUF, HALF, KT) \
  stage<LPB>((BUF) + (HALF) * (BBY / 2), Bn + (size_t)((HALF) * (BN / 2)) * K + (KT) * 64, K, tid)

#define RDA(BUF, IH)                                                                   \
  { _Pragma("unroll")                                                                  \
    for (int kf_ = 0; kf_ < KFN; kf_++) {                                              \
      _Pragma("unroll")                                                                \
      for (int kk_ = 0; kk_ < 2; kk_++) {                                              \
        const int row_ = ((IH) * KFN + kf_) * 32 + wr * 16 + lr;                       \
        a[kf_ * 2 + kk_] = *(const bf16x8*)((BUF) + row_ * 128 +                       \
                                            (((kk_ * 4 + lu) ^ (lr & 7)) << 4));       \
      } } }

#define RDB(BUF, JH)                                                                   \
  { _Pragma("unroll")                                                                  \
    for (int jf_ = 0; jf_ < JFN; jf_++) {                                              \
      _Pragma("unroll")                                                                \
      for (int kk_ = 0; kk_ < 2; kk_++) {                                              \
        const int row_ = ((JH) * JFN + jf_) * 64 + wc * 16 + lr;                       \
        b[jf_ * 2 + kk_] = *(const bf16x8*)((BUF) + row_ * 128 +                       \
                                            (((kk_ * 4 + lu) ^ (lr & 7)) << 4));       \
      } } }

#define MF(IH, JH)                                                                     \
  { _Pragma("unroll")                                                                  \
    for (int kf_ = 0; kf_ < KFN; kf_++)                                                \
      { _Pragma("unroll")                                                              \
        for (int jf_ = 0; jf_ < JFN; jf_++)                                            \
          { _Pragma("unroll")                                                          \
            for (int kk_ = 0; kk_ < 2; kk_++)                                          \
              acc[(IH) * KFN + kf_][(JH) * JFN + jf_] =                                \
                  __builtin_amdgcn_mfma_f32_16x16x32_bf16(                             \
                      a[kf_ * 2 + kk_], b[jf_ * 2 + kk_],                              \
                      acc[(IH) * KFN + kf_][(JH) * JFN + jf_], 0, 0, 0);               \
          } } }

template <int BM, int BN>
__global__ __launch_bounds__(512, 2) void k_gemm256(
    const short* __restrict__ A, const short* __restrict__ Bt,
    void* __restrict__ Out0, void* __restrict__ Out1,
    int N, int K, int mode) {
  constexpr int LPA = BM / 128;   // loads/thread per A half-tile
  constexpr int LPB = BN / 128;   // loads/thread per B half-tile
  constexpr int KFN = BM / 64;    // 32-row A groups per M-half
  constexpr int JFN = BN / 128;   // 64-row B groups per N-half
  constexpr int ABY = BM * 128;   // bytes per A buffer [BM][64]
  constexpr int BBY = BN * 128;   // bytes per B buffer [BN][64]
  extern __shared__ __align__(16) char sm[];
  char* A0 = sm;
  char* A1 = sm + ABY;
  char* B0 = sm + 2 * ABY;
  char* B1 = sm + 2 * ABY + BBY;
  // T1: XCD swizzle. Dispatch round-robins lin%8 across XCDs -> give each XCD one
  // n-column (B panel L2-resident), m varies within XCD.
  const int lin = blockIdx.x + gridDim.x * blockIdx.y;
  const int m0 = (lin >> 3) * BM, n0 = (lin & 7) * BN;
  const int tid = threadIdx.x, lane = tid & 63, w = tid >> 6;
  const int wr = w & 1, wc = w >> 1;  // 2M x 4N waves, 16-row/16-col stripes
  const int lr = lane & 15, lu = lane >> 4;
  const short* Am = A + (size_t)m0 * K;
  const short* Bn = Bt + (size_t)n0 * K;
  f32x4 acc[KFN * 2][JFN * 2] = {};
  bf16x8 a[KFN * 2], b[JFN * 2];
  const int NIT = K >> 7;
  const int TMAX = (K >> 6) - 1;

  // prologue: t0 full + t1.{Ah0,Bh1}; wait t0 (leave t1's LPA+LPB loads in flight)
  SA(A0, 0, 0); SB(B0, 1, 0); SA(A0, 1, 0); SB(B0, 0, 0);
  SA(A1, 0, 1); SB(B1, 1, 1);
  VMW; GBAR;

  for (int it = 0; it < NIT; ++it) {
    const int t1 = 2 * it + 1;
    const int t2 = (2 * it + 2 < TMAX) ? 2 * it + 2 : TMAX;
    const int t3 = (2 * it + 3 < TMAX) ? 2 * it + 3 : TMAX;
    // Ph0: quadrant (0,0) of even tile
    RDA(A0, 0); RDB(B0, 0); SA(A1, 1, t1);
    GBAR; LGK; PR1; MF(0, 0); PR0; GBAR;
    // Ph1: (0,1)
    RDB(B0, 1); SB(B1, 0, t1);
    GBAR; LGK; PR1; MF(0, 1); PR0; GBAR;
    // Ph2: (1,1)
    RDA(A0, 1); SA(A0, 0, t2);
    GBAR; LGK; PR1; MF(1, 1); PR0; GBAR;
    // Ph3: (1,0)  [odd-tile buffers complete after this wait]
    RDB(B0, 0); SB(B0, 1, t2);
    GBAR; LGK; PR1; MF(1, 0); PR0; VMW; GBAR;
    // Ph4: (0,0) of odd tile
    RDA(A1, 0); RDB(B1, 0); SA(A0, 1, t2);
    GBAR; LGK; PR1; MF(0, 0); PR0; GBAR;
    // Ph5: (0,1)
    RDB(B1, 1); SB(B0, 0, t2);
    GBAR; LGK; PR1; MF(0, 1); PR0; GBAR;
    // Ph6: (1,1)
    RDA(A1, 1); SA(A1, 0, t3);
    GBAR; LGK; PR1; MF(1, 1); PR0; GBAR;
    // Ph7: (1,0)  [even-tile buffers complete after this wait]
    RDB(B1, 0); SB(B1, 1, t3);
    GBAR; LGK; PR1; MF(1, 0); PR0; VMW; GBAR;
  }

  // ---------------- epilogue ----------------
  if (mode == 2) {
#pragma unroll
    for (int k = 0; k < KFN * 2; k++)
#pragma unroll
      for (int j = 0; j < JFN * 2; j++)
#pragma unroll
        for (int r = 0; r < 4; r++) {
          const int m = m0 + k * 32 + wr * 16 + lu * 4 + r;
          const int n = n0 + j * 64 + wc * 16 + lr;
          ((float*)Out0)[(size_t)m * N + n] = acc[k][j][r];
        }
  } else {
    // Fused RoPE: fragment pair (j=2u, j=2u+1) holds (h, h+64) for same t.
    // Per-thread rotation index i = wc*16+lr is constant.
    const int i_rope = wc * 16 + lr;
    const float inv = __expf(-(float)i_rope * (float)(9.210340371976184 / 64.0));
#pragma unroll
    for (int k = 0; k < KFN * 2; k++) {
      float sn[4], cs[4];
#pragma unroll
      for (int r = 0; r < 4; r++) {
        const int m = m0 + k * 32 + wr * 16 + lu * 4 + r;
        sincosf((float)(m & 2047) * inv, &sn[r], &cs[r]);
      }
#pragma unroll
      for (int u = 0; u < JFN; u++) {
        const int n_lo = n0 + (2 * u) * 64 + wc * 16 + lr;  // h = i_rope (<64)
        const int reg = (n_lo < 2048) ? 0 : ((n_lo < 2560) ? 1 : 2);  // q/k/v
#pragma unroll
        for (int r = 0; r < 4; r++) {
          const int m = m0 + k * 32 + wr * 16 + lu * 4 + r;
          const int bb = m >> 11, t = m & 2047;
          float lo = acc[k][2 * u][r], hi = acc[k][2 * u + 1][r];
          if (reg < 2) {  // rotate
            const float l2 = lo * cs[r] - hi * sn[r];
            const float h2 = hi * cs[r] + lo * sn[r];
            const float sc = (reg == 0) ? 0.08838834764831845f : 1.0f;
            lo = l2 * sc; hi = h2 * sc;
          }
#pragma unroll
          for (int p = 0; p < 2; p++) {
            const int n = n_lo + p * 64;
            const float v = p ? hi : lo;
            if (n < 2048) {  // q: [b][head][t][h]
              ((short*)Out0)[(((size_t)(bb * 16 + (n >> 7))) << 18) + t * 128 + (n & 127)] =
                  f2bf(v);
            } else {  // kv: [c][b][kv][t][h]
              const int nn = n - 2048;
              ((short*)Out1)[(((size_t)(((nn >> 9) * 2 + bb) * 4 + ((nn >> 7) & 3))) << 18) +
                             t * 128 + (nn & 127)] = f2bf(v);
            }
          }
        }
      }
    }
  }
}

// ---------------- flash attention, sliding window + tanh soft-cap ----------------
// Swapped QK^T: sc = mfma(K,Q) -> sc[cg][r] = S[s=s0+cg*16+lu*4+r][t=tw+lr].
// Soft-cap via cubic: 50*tanh(x/50) ~= x - x^3/7500 (err < 2e-3 at |x|=10).
// Fixed-max softmax (cap bounds logits): p = exp(cap); scalar lsum per lane.
__global__ __launch_bounds__(256) void k_attn(
    const short* __restrict__ q, const short* __restrict__ kk,
    const short* __restrict__ vT, short* __restrict__ enc) {
  __shared__ __align__(16) short lK[64 * 128];   // [s][h], byte ^= ((s&7)<<4)
  __shared__ __align__(16) short lV[128 * 64];   // [h][s], byte ^= ((h&7)<<4)
  __shared__ __align__(16) short lP[4][16 * 64]; // per-wave P [t][s], byte ^= ((t&7)<<4)
  const int bn = blockIdx.x, b = bn >> 4, n = bn & 15, kv = n >> 2;
  const int qt0 = (31 - blockIdx.y) * 64;  // heavy blocks dispatched first
  const int tid = threadIdx.x, lane = tid & 63, w = tid >> 6;
  const int lr = lane & 15, lu = lane >> 4;
  const short* qbase = q + (((size_t)(b * 16 + n)) << 18) + (size_t)(qt0 + w * 16) * 128;
  bf16x8 qa[4];
#pragma unroll
  for (int c = 0; c < 4; c++)
    qa[c] = *reinterpret_cast<const bf16x8*>(qbase + lr * 128 + c * 32 + lu * 8);
  f32x4 o[8] = {};
  float lsum = 0.f;
  const short* kbase = kk + (((size_t)(b * 4 + kv)) << 18);
  const short* vbase = vT + (((size_t)(b * 4 + kv)) << 18);
  char* lPw = (char*)lP[w];
  const int tw = qt0 + w * 16;
  const int t_row = tw + lu * 4;
  int st0 = qt0 - 1023; if (st0 < 0) st0 = 0;
  st0 >>= 6;
  const int stE = (qt0 + 63) >> 6;
  for (int st = st0; st <= stE; st++) {
    const int s0 = st << 6;
#pragma unroll
    for (int c = 0; c < 4; c++) {
      const int L = w * 4096 + c * 1024 + lane * 16;  // byte offset in 16 KiB tile
      {  // K tile: linear LDS dest, pre-swizzled global source
        const int s = L >> 8, slot = (L >> 4) & 15;
        const int sp = slot ^ (s & 7);
        __builtin_amdgcn_global_load_lds(
            (const __attribute__((address_space(1))) void*)(kbase + (size_t)(s0 + s) * 128 + sp * 8),
            (__attribute__((address_space(3))) void*)((char*)lK + L), 16, 0, 0);
      }
      {  // V tile
        const int h = L >> 7, slot = (L >> 4) & 7;
        const int u = slot ^ (h & 7);
        __builtin_amdgcn_global_load_lds(
            (const __attribute__((address_space(1))) void*)(vbase + (size_t)h * 2048 + s0 + u * 8),
            (__attribute__((address_space(3))) void*)((char*)lV + L), 16, 0, 0);
      }
    }
    __syncthreads();
    // ---- QK^T (swapped): sc[cg][r] = S[s=cg*16+lu*4+r][t=lr] ----
    f32x4 sc[4];
    __builtin_amdgcn_s_setprio(1);
#pragma unroll
    for (int cg = 0; cg < 4; cg++) {
      sc[cg] = (f32x4){0.f, 0.f, 0.f, 0.f};
      const int s = cg * 16 + lr;
      const int sw = (s & 7) << 4;
#pragma unroll
      for (int c = 0; c < 4; c++) {
        bf16x8 kb = *reinterpret_cast<const bf16x8*>((char*)lK + s * 256 + (((c * 4 + lu) << 4) ^ sw));
        sc[cg] = __builtin_amdgcn_mfma_f32_16x16x32_bf16(kb, qa[c], sc[cg], 0, 0, 0);
      }
    }
    __builtin_amdgcn_s_setprio(0);
    // ---- cubic soft-cap + exp, pack pairs, write P (b32) ----
    const bool allv = (s0 + 63 <= tw) && (s0 + 1008 >= tw);
    if (allv) {
#pragma unroll
      for (int cg = 0; cg < 4; cg++) {
        float pr[4];
#pragma unroll
        for (int r = 0; r < 4; r++) {
          const float x = sc[cg][r];
          const float cap = __builtin_fmaf(x * x * x, -1.3333333e-4f, x);
          const float p = __expf(cap);
          lsum += p;
          pr[r] = p;
        }
        unsigned w0, w1;
        asm("v_cvt_pk_bf16_f32 %0, %1, %2" : "=v"(w0) : "v"(pr[0]), "v"(pr[1]));
        asm("v_cvt_pk_bf16_f32 %0, %1, %2" : "=v"(w1) : "v"(pr[2]), "v"(pr[3]));
        const int sb = (cg * 16 + lu * 4) << 1;  // byte offset of s-pair base
        *(unsigned*)(lPw + (lr << 7) + (sb ^ ((lr & 7) << 4))) = w0;
        *(unsigned*)(lPw + (lr << 7) + ((sb + 4) ^ ((lr & 7) << 4))) = w1;
      }
    } else {
      const int t = tw + lr;
#pragma unroll
      for (int cg = 0; cg < 4; cg++) {
        float pr[4];
#pragma unroll
        for (int r = 0; r < 4; r++) {
          const int s = s0 + cg * 16 + lu * 4 + r;
          const bool valid = (s <= t) & (s + 1024 > t);
          const float x = sc[cg][r];
          const float cap = __builtin_fmaf(x * x * x, -1.3333333e-4f, x);
          float p = __expf(cap);
          p = valid ? p : 0.f;
          lsum += p;
          pr[r] = p;
        }
        unsigned w0, w1;
        asm("v_cvt_pk_bf16_f32 %0, %1, %2" : "=v"(w0) : "v"(pr[0]), "v"(pr[1]));
        asm("v_cvt_pk_bf16_f32 %0, %1, %2" : "=v"(w1) : "v"(pr[2]), "v"(pr[3]));
        const int sb = (cg * 16 + lu * 4) << 1;
        *(unsigned*)(lPw + (lr << 7) + (sb ^ ((lr & 7) << 4))) = w0;
        *(unsigned*)(lPw + (lr << 7) + ((sb + 4) ^ ((lr & 7) << 4))) = w1;
      }
    }
    // ---- PV: o[oc] += P[t][s] * V[s][h] (orientation unchanged) ----
#pragma unroll
    for (int ks = 0; ks < 2; ks++) {
      const bf16x8 pf = *reinterpret_cast<const bf16x8*>(
          lPw + (lr << 7) + ((ks * 64 + lu * 16) ^ ((lr & 7) << 4)));
      __builtin_amdgcn_s_setprio(1);
#pragma unroll
      for (int oc = 0; oc < 8; oc++) {
        const int h = oc * 16 + lr;
        bf16x8 vb = *reinterpret_cast<const bf16x8*>(
            (char*)lV + h * 128 + (((ks * 4 + lu) << 4) ^ ((h & 7) << 4)));
        o[oc] = __builtin_amdgcn_mfma_f32_16x16x32_bf16(pf, vb, o[oc], 0, 0, 0);
      }
      __builtin_amdgcn_s_setprio(0);
    }
    __syncthreads();
  }
  // ---- reduce: lane holds partial sum for column t=tw+lr ----
  float tot = lsum;
  tot += __shfl_xor(tot, 16, 64);
  tot += __shfl_xor(tot, 32, 64);
  float rs[4];
#pragma unroll
  for (int r = 0; r < 4; r++)
    rs[r] = 1.f / __shfl(tot, lu * 4 + r, 64);  // sum for t=tw+lu*4+r held at lane lu*4+r
#pragma unroll
  for (int oc = 0; oc < 8; oc++)
#pragma unroll
    for (int r = 0; r < 4; r++) {
      const int t = t_row + r;
      enc[((size_t)b * 2048 + t) * 2048 + n * 128 + oc * 16 + lr] = f2bf(o[oc][r] * rs[r]);
    }
}

extern "C" void kernel_launch(void* const* d_in, const int* in_sizes, int n_in,
                              void* d_out, int out_size, void* d_ws, size_t ws_size,
                              hipStream_t stream) {
  (void)in_sizes; (void)n_in; (void)out_size; (void)ws_size;
  const float* x    = (const float*)d_in[0];
  const float* wq   = (const float*)d_in[3];
  const float* wkv  = (const float*)d_in[4];
  const float* wvec = (const float*)d_in[5];
  char* ws = (char*)d_ws;
  size_t off = 0;
  short* xbf   = (short*)(ws + off); off += (size_t)8388608 * 2;            // x bf16 [B*T][D]
  short* wall  = (short*)(ws + off); off += (size_t)3072 * 2048 * 2;        // [wqT|wkT|wvT] rows x K
  short* wvecT = (short*)(ws + off); off += (size_t)2048 * 2048 * 2;        // [d][nh]
  short* qbuf  = (short*)(ws + off); off += (size_t)2 * 16 * 2048 * 128 * 2; // q bf16 [b][n][t][h]
  short* kvbuf = (short*)(ws + off); off += (size_t)2 * 2 * 4 * 2048 * 128 * 2; // [c][b][kv][t][h]
  short* vTbuf = (short*)(ws + off); off += (size_t)2 * 4 * 128 * 2048 * 2; // v^T [b][kv][h][s]
  short* encb  = (short*)(ws + off); off += (size_t)2 * 2048 * 2048 * 2;    // [b][t][nh]

  hipFuncSetAttribute(reinterpret_cast<const void*>(&k_gemm256<128, 384>),
                      hipFuncAttributeMaxDynamicSharedMemorySize, 131072);
  hipFuncSetAttribute(reinterpret_cast<const void*>(&k_gemm256<128, 256>),
                      hipFuncAttributeMaxDynamicSharedMemorySize, 98304);

  k_cvt<<<8192, 256, 0, stream>>>(x, xbf, 2097152);
  k_tr<float><<<dim3(4, 64, 16), 256, 0, stream>>>(wq, wall, 2048, 128);
  k_tr<float><<<dim3(4, 64, 4), 256, 0, stream>>>(wkv, wall + 4194304, 2048, 128);
  k_tr<float><<<dim3(4, 64, 4), 256, 0, stream>>>(wkv + 1048576, wall + 5242880, 2048, 128);
  k_tr<float><<<dim3(64, 64, 1), 256, 0, stream>>>(wvec, wvecT, 2048, 2048);
  k_gemm256<128, 384><<<dim3(32, 8), 512, 131072, stream>>>(xbf, wall, qbuf, kvbuf,
                                                            3072, 2048, 0);
  k_tr<short><<<dim3(4, 64, 8), 256, 0, stream>>>(kvbuf + 2097152, vTbuf, 2048, 128);
  k_attn<<<dim3(32, 32), 256, 0, stream>>>(qbuf, kvbuf, vTbuf, encb);
  k_gemm256<128, 256><<<dim3(32, 8), 512, 98304, stream>>>(encb, wvecT, d_out, nullptr,
                                                           2048, 2048, 2);
}

// Round 11
// 174.774 us; speedup vs baseline: 1.8593x; 1.0115x over previous
//
#include <hip/hip_runtime.h>
#include <hip/hip_bf16.h>

#define DEVINL static __device__ __forceinline__

typedef __attribute__((ext_vector_type(4))) float f32x4;
typedef __attribute__((ext_vector_type(8))) short bf16x8;

DEVINL short f2bf(float f) {
  __hip_bfloat16 h = __float2bfloat16(f);
  union { __hip_bfloat16 h; short s; } u; u.h = h; return u.s;
}
DEVINL float bf2f(short s) {
  union { unsigned u; float f; } v; v.u = ((unsigned)(unsigned short)s) << 16;
  return v.f;
}
DEVINL float ldf(float x) { return x; }
DEVINL float ldf(short x) { return bf2f(x); }

// ---------------- f32 -> bf16 convert, 4 elems/thread ----------------
__global__ void k_cvt(const float* __restrict__ in, short* __restrict__ out, int n4) {
  int i = blockIdx.x * blockDim.x + threadIdx.x;
  if (i >= n4) return;
  const float4 v = reinterpret_cast<const float4*>(in)[i];
  short4 o;
  o.x = f2bf(v.x); o.y = f2bf(v.y); o.z = f2bf(v.z); o.w = f2bf(v.w);
  reinterpret_cast<short4*>(out)[i] = o;
}

// ------- batched transpose [batch][R][C] -> [batch][C][R], out bf16 -------
template <typename Tin>
__global__ void k_tr(const Tin* __restrict__ in, short* __restrict__ out, int R, int C) {
  __shared__ float tile[32][33];
  const int bz = blockIdx.z;
  const int r0 = blockIdx.y * 32, c0 = blockIdx.x * 32;
  const int tx = threadIdx.x & 31, ty = threadIdx.x >> 5;  // ty in 0..7
  const Tin* ip = in + (size_t)bz * R * C;
  short* op = out + (size_t)bz * R * C;
#pragma unroll
  for (int k = 0; k < 4; k++)
    tile[ty + k * 8][tx] = ldf(ip[(size_t)(r0 + ty + k * 8) * C + c0 + tx]);
  __syncthreads();
#pragma unroll
  for (int k = 0; k < 4; k++)
    op[(size_t)(c0 + ty + k * 8) * R + r0 + tx] = f2bf(tile[tx][ty + k * 8]);
}

// =================== BMxBNxK 8-phase MFMA GEMM (T2+T3+T4+T5+T1) ===================
// C[M][N] = A[M][K] * Bt[N][K]^T ; 512 threads, 8 waves (2M x 4N, 16-stripe interleave)
// LDS dynamic: A0|A1|B0|B1; granule-XOR swizzled; m201 phase frame.
// JH0 B-fragments held in registers across the K-tile (bJ0) -> Ph3/Ph7 do no ds_read,
// cutting LDS-read traffic 23% (the measured roofline of this schedule).
// Grid MUST be (x, 8); XCD swizzle: y = lin%8 (one B-panel per XCD L2), x = lin/8.
// mode 0: QKV scatter epilogue with FUSED RoPE; mode 2: f32 row-major.

#define GBAR __builtin_amdgcn_s_barrier()
#define LGK asm volatile("s_waitcnt lgkmcnt(0)")
#define PR1 __builtin_amdgcn_s_setprio(1)
#define PR0 __builtin_amdgcn_s_setprio(0)
#define VMW { if constexpr (LPA + LPB == 4) asm volatile("s_waitcnt vmcnt(4)"); \
              else asm volatile("s_waitcnt vmcnt(3)"); }

// stage one half-tile: LN x global_load_lds(16B)/thread; LDS linear, src pre-swizzled
template <int LN>
DEVINL void stage(char* dst, const short* src, int K, int tid) {
#pragma unroll
  for (int L = 0; L < LN; L++) {
    const int loc = L * 8192 + tid * 16;
    const int row = loc >> 7;
    const int gsw = ((loc >> 4) & 7) ^ (row & 7);
    __builtin_amdgcn_global_load_lds(
        (const __attribute__((address_space(1))) void*)(src + (size_t)row * K + gsw * 8),
        (__attribute__((address_space(3))) void*)(dst + loc), 16, 0, 0);
  }
}

#define SA(BUF, HALF, KT) \
  stage<LPA>((BUF) + (HALF) * (ABY / 2), Am + (size_t)((HALF) * (BM / 2)) * K + (KT) * 64, K, tid)
#define SB(BUF, HALF, KT) \
  stage<LPB>((BUF) + (HALF) * (BBY / 2), Bn + (size_t)((HALF) * (BN / 2)) * K + (KT) * 64, K, tid)

#define RDA(BUF, IH)                                                                   \
  { _Pragma("unroll")                                                                  \
    for (int kf_ = 0; kf_ < KFN; kf_++) {                                              \
      _Pragma("unroll")                                                                \
      for (int kk_ = 0; kk_ < 2; kk_++) {                                              \
        const int row_ = ((IH) * KFN + kf_) * 32 + wr * 16 + lr;                       \
        a[kf_ * 2 + kk_] = *(const bf16x8*)((BUF) + row_ * 128 +                       \
                                            (((kk_ * 4 + lu) ^ (lr & 7)) << 4));       \
      } } }

#define RDB(BUF, JH, ARR)                                                              \
  { _Pragma("unroll")                                                                  \
    for (int jf_ = 0; jf_ < JFN; jf_++) {                                              \
      _Pragma("unroll")                                                                \
      for (int kk_ = 0; kk_ < 2; kk_++) {                                              \
        const int row_ = ((JH) * JFN + jf_) * 64 + wc * 16 + lr;                       \
        ARR[jf_ * 2 + kk_] = *(const bf16x8*)((BUF) + row_ * 128 +                     \
                                              (((kk_ * 4 + lu) ^ (lr & 7)) << 4));     \
      } } }

#define MF(IH, JH, ARR)                                                                \
  { _Pragma("unroll")                                                                  \
    for (int kf_ = 0; kf_ < KFN; kf_++)                                                \
      { _Pragma("unroll")                                                              \
        for (int jf_ = 0; jf_ < JFN; jf_++)                                            \
          { _Pragma("unroll")                                                          \
            for (int kk_ = 0; kk_ < 2; kk_++)                                          \
              acc[(IH) * KFN + kf_][(JH) * JFN + jf_] =                                \
                  __builtin_amdgcn_mfma_f32_16x16x32_bf16(                             \
                      a[kf_ * 2 + kk_], ARR[jf_ * 2 + kk_],                            \
                      acc[(IH) * KFN + kf_][(JH) * JFN + jf_], 0, 0, 0);               \
          } } }

template <int BM, int BN>
__global__ __launch_bounds__(512, 2) void k_gemm256(
    const short* __restrict__ A, const short* __restrict__ Bt,
    void* __restrict__ Out0, void* __restrict__ Out1,
    int N, int K, int mode) {
  constexpr int LPA = BM / 128;   // loads/thread per A half-tile
  constexpr int LPB = BN / 128;   // loads/thread per B half-tile
  constexpr int KFN = BM / 64;    // 32-row A groups per M-half
  constexpr int JFN = BN / 128;   // 64-row B groups per N-half
  constexpr int ABY = BM * 128;   // bytes per A buffer [BM][64]
  constexpr int BBY = BN * 128;   // bytes per B buffer [BN][64]
  extern __shared__ __align__(16) char sm[];
  char* A0 = sm;
  char* A1 = sm + ABY;
  char* B0 = sm + 2 * ABY;
  char* B1 = sm + 2 * ABY + BBY;
  // T1: XCD swizzle. Dispatch round-robins lin%8 across XCDs -> give each XCD one
  // n-column (B panel L2-resident), m varies within XCD.
  const int lin = blockIdx.x + gridDim.x * blockIdx.y;
  const int m0 = (lin >> 3) * BM, n0 = (lin & 7) * BN;
  const int tid = threadIdx.x, lane = tid & 63, w = tid >> 6;
  const int wr = w & 1, wc = w >> 1;  // 2M x 4N waves, 16-row/16-col stripes
  const int lr = lane & 15, lu = lane >> 4;
  const short* Am = A + (size_t)m0 * K;
  const short* Bn = Bt + (size_t)n0 * K;
  f32x4 acc[KFN * 2][JFN * 2] = {};
  bf16x8 a[KFN * 2], bJ0[JFN * 2], bJ1[JFN * 2];
  const int NIT = K >> 7;
  const int TMAX = (K >> 6) - 1;

  // prologue: t0 full + t1.{Ah0,Bh1}; wait t0 (leave t1's LPA+LPB loads in flight)
  SA(A0, 0, 0); SB(B0, 1, 0); SA(A0, 1, 0); SB(B0, 0, 0);
  SA(A1, 0, 1); SB(B1, 1, 1);
  VMW; GBAR;

  for (int it = 0; it < NIT; ++it) {
    const int t1 = 2 * it + 1;
    const int t2 = (2 * it + 2 < TMAX) ? 2 * it + 2 : TMAX;
    const int t3 = (2 * it + 3 < TMAX) ? 2 * it + 3 : TMAX;
    // Ph0: quadrant (0,0) of even tile; B JH0 -> bJ0 (held through Ph3)
    RDA(A0, 0); RDB(B0, 0, bJ0); SA(A1, 1, t1);
    GBAR; LGK; PR1; MF(0, 0, bJ0); PR0; GBAR;
    // Ph1: (0,1)
    RDB(B0, 1, bJ1); SB(B1, 0, t1);
    GBAR; LGK; PR1; MF(0, 1, bJ1); PR0; GBAR;
    // Ph2: (1,1)
    RDA(A0, 1); SA(A0, 0, t2);
    GBAR; LGK; PR1; MF(1, 1, bJ1); PR0; GBAR;
    // Ph3: (1,0) from held bJ0 — no ds_read  [odd-tile buffers complete after wait]
    SB(B0, 1, t2);
    GBAR; PR1; MF(1, 0, bJ0); PR0; VMW; GBAR;
    // Ph4: (0,0) of odd tile
    RDA(A1, 0); RDB(B1, 0, bJ0); SA(A0, 1, t2);
    GBAR; LGK; PR1; MF(0, 0, bJ0); PR0; GBAR;
    // Ph5: (0,1)
    RDB(B1, 1, bJ1); SB(B0, 0, t2);
    GBAR; LGK; PR1; MF(0, 1, bJ1); PR0; GBAR;
    // Ph6: (1,1)
    RDA(A1, 1); SA(A1, 0, t3);
    GBAR; LGK; PR1; MF(1, 1, bJ1); PR0; GBAR;
    // Ph7: (1,0) from held bJ0  [even-tile buffers complete after this wait]
    SB(B1, 1, t3);
    GBAR; PR1; MF(1, 0, bJ0); PR0; VMW; GBAR;
  }

  // ---------------- epilogue ----------------
  if (mode == 2) {
#pragma unroll
    for (int k = 0; k < KFN * 2; k++)
#pragma unroll
      for (int j = 0; j < JFN * 2; j++)
#pragma unroll
        for (int r = 0; r < 4; r++) {
          const int m = m0 + k * 32 + wr * 16 + lu * 4 + r;
          const int n = n0 + j * 64 + wc * 16 + lr;
          ((float*)Out0)[(size_t)m * N + n] = acc[k][j][r];
        }
  } else {
    // Fused RoPE: fragment pair (j=2u, j=2u+1) holds (h, h+64) for same t.
    // Per-thread rotation index i = wc*16+lr is constant.
    const int i_rope = wc * 16 + lr;
    const float inv = __expf(-(float)i_rope * (float)(9.210340371976184 / 64.0));
#pragma unroll
    for (int k = 0; k < KFN * 2; k++) {
      float sn[4], cs[4];
#pragma unroll
      for (int r = 0; r < 4; r++) {
        const int m = m0 + k * 32 + wr * 16 + lu * 4 + r;
        sincosf((float)(m & 2047) * inv, &sn[r], &cs[r]);
      }
#pragma unroll
      for (int u = 0; u < JFN; u++) {
        const int n_lo = n0 + (2 * u) * 64 + wc * 16 + lr;  // h = i_rope (<64)
        const int reg = (n_lo < 2048) ? 0 : ((n_lo < 2560) ? 1 : 2);  // q/k/v
#pragma unroll
        for (int r = 0; r < 4; r++) {
          const int m = m0 + k * 32 + wr * 16 + lu * 4 + r;
          const int bb = m >> 11, t = m & 2047;
          float lo = acc[k][2 * u][r], hi = acc[k][2 * u + 1][r];
          if (reg < 2) {  // rotate
            const float l2 = lo * cs[r] - hi * sn[r];
            const float h2 = hi * cs[r] + lo * sn[r];
            const float sc = (reg == 0) ? 0.08838834764831845f : 1.0f;
            lo = l2 * sc; hi = h2 * sc;
          }
#pragma unroll
          for (int p = 0; p < 2; p++) {
            const int n = n_lo + p * 64;
            const float v = p ? hi : lo;
            if (n < 2048) {  // q: [b][head][t][h]
              ((short*)Out0)[(((size_t)(bb * 16 + (n >> 7))) << 18) + t * 128 + (n & 127)] =
                  f2bf(v);
            } else {  // kv: [c][b][kv][t][h]
              const int nn = n - 2048;
              ((short*)Out1)[(((size_t)(((nn >> 9) * 2 + bb) * 4 + ((nn >> 7) & 3))) << 18) +
                             t * 128 + (nn & 127)] = f2bf(v);
            }
          }
        }
      }
    }
  }
}

// ---------------- flash attention, sliding window + tanh soft-cap ----------------
// Swapped QK^T: sc = mfma(K,Q) -> sc[cg][r] = S[s=s0+cg*16+lu*4+r][t=tw+lr].
// Soft-cap via cubic: 50*tanh(x/50) ~= x - x^3/7500 (err < 2e-3 at |x|=10).
// Fixed-max softmax (cap bounds logits): p = exp(cap); scalar lsum per lane.
__global__ __launch_bounds__(256) void k_attn(
    const short* __restrict__ q, const short* __restrict__ kk,
    const short* __restrict__ vT, short* __restrict__ enc) {
  __shared__ __align__(16) short lK[64 * 128];   // [s][h], byte ^= ((s&7)<<4)
  __shared__ __align__(16) short lV[128 * 64];   // [h][s], byte ^= ((h&7)<<4)
  __shared__ __align__(16) short lP[4][16 * 64]; // per-wave P [t][s], byte ^= ((t&7)<<4)
  const int bn = blockIdx.x, b = bn >> 4, n = bn & 15, kv = n >> 2;
  const int qt0 = (31 - blockIdx.y) * 64;  // heavy blocks dispatched first
  const int tid = threadIdx.x, lane = tid & 63, w = tid >> 6;
  const int lr = lane & 15, lu = lane >> 4;
  const short* qbase = q + (((size_t)(b * 16 + n)) << 18) + (size_t)(qt0 + w * 16) * 128;
  bf16x8 qa[4];
#pragma unroll
  for (int c = 0; c < 4; c++)
    qa[c] = *reinterpret_cast<const bf16x8*>(qbase + lr * 128 + c * 32 + lu * 8);
  f32x4 o[8] = {};
  float lsum = 0.f;
  const short* kbase = kk + (((size_t)(b * 4 + kv)) << 18);
  const short* vbase = vT + (((size_t)(b * 4 + kv)) << 18);
  char* lPw = (char*)lP[w];
  const int tw = qt0 + w * 16;
  const int t_row = tw + lu * 4;
  int st0 = qt0 - 1023; if (st0 < 0) st0 = 0;
  st0 >>= 6;
  const int stE = (qt0 + 63) >> 6;
  for (int st = st0; st <= stE; st++) {
    const int s0 = st << 6;
#pragma unroll
    for (int c = 0; c < 4; c++) {
      const int L = w * 4096 + c * 1024 + lane * 16;  // byte offset in 16 KiB tile
      {  // K tile: linear LDS dest, pre-swizzled global source
        const int s = L >> 8, slot = (L >> 4) & 15;
        const int sp = slot ^ (s & 7);
        __builtin_amdgcn_global_load_lds(
            (const __attribute__((address_space(1))) void*)(kbase + (size_t)(s0 + s) * 128 + sp * 8),
            (__attribute__((address_space(3))) void*)((char*)lK + L), 16, 0, 0);
      }
      {  // V tile
        const int h = L >> 7, slot = (L >> 4) & 7;
        const int u = slot ^ (h & 7);
        __builtin_amdgcn_global_load_lds(
            (const __attribute__((address_space(1))) void*)(vbase + (size_t)h * 2048 + s0 + u * 8),
            (__attribute__((address_space(3))) void*)((char*)lV + L), 16, 0, 0);
      }
    }
    __syncthreads();
    // ---- QK^T (swapped): sc[cg][r] = S[s=cg*16+lu*4+r][t=lr] ----
    f32x4 sc[4];
    __builtin_amdgcn_s_setprio(1);
#pragma unroll
    for (int cg = 0; cg < 4; cg++) {
      sc[cg] = (f32x4){0.f, 0.f, 0.f, 0.f};
      const int s = cg * 16 + lr;
      const int sw = (s & 7) << 4;
#pragma unroll
      for (int c = 0; c < 4; c++) {
        bf16x8 kb = *reinterpret_cast<const bf16x8*>((char*)lK + s * 256 + (((c * 4 + lu) << 4) ^ sw));
        sc[cg] = __builtin_amdgcn_mfma_f32_16x16x32_bf16(kb, qa[c], sc[cg], 0, 0, 0);
      }
    }
    __builtin_amdgcn_s_setprio(0);
    // ---- cubic soft-cap + exp, pack pairs, write P (b32) ----
    const bool allv = (s0 + 63 <= tw) && (s0 + 1008 >= tw);
    if (allv) {
#pragma unroll
      for (int cg = 0; cg < 4; cg++) {
        float pr[4];
#pragma unroll
        for (int r = 0; r < 4; r++) {
          const float x = sc[cg][r];
          const float cap = __builtin_fmaf(x * x * x, -1.3333333e-4f, x);
          const float p = __expf(cap);
          lsum += p;
          pr[r] = p;
        }
        unsigned w0, w1;
        asm("v_cvt_pk_bf16_f32 %0, %1, %2" : "=v"(w0) : "v"(pr[0]), "v"(pr[1]));
        asm("v_cvt_pk_bf16_f32 %0, %1, %2" : "=v"(w1) : "v"(pr[2]), "v"(pr[3]));
        const int sb = (cg * 16 + lu * 4) << 1;  // byte offset of s-pair base
        *(unsigned*)(lPw + (lr << 7) + (sb ^ ((lr & 7) << 4))) = w0;
        *(unsigned*)(lPw + (lr << 7) + ((sb + 4) ^ ((lr & 7) << 4))) = w1;
      }
    } else {
      const int t = tw + lr;
#pragma unroll
      for (int cg = 0; cg < 4; cg++) {
        float pr[4];
#pragma unroll
        for (int r = 0; r < 4; r++) {
          const int s = s0 + cg * 16 + lu * 4 + r;
          const bool valid = (s <= t) & (s + 1024 > t);
          const float x = sc[cg][r];
          const float cap = __builtin_fmaf(x * x * x, -1.3333333e-4f, x);
          float p = __expf(cap);
          p = valid ? p : 0.f;
          lsum += p;
          pr[r] = p;
        }
        unsigned w0, w1;
        asm("v_cvt_pk_bf16_f32 %0, %1, %2" : "=v"(w0) : "v"(pr[0]), "v"(pr[1]));
        asm("v_cvt_pk_bf16_f32 %0, %1, %2" : "=v"(w1) : "v"(pr[2]), "v"(pr[3]));
        const int sb = (cg * 16 + lu * 4) << 1;
        *(unsigned*)(lPw + (lr << 7) + (sb ^ ((lr & 7) << 4))) = w0;
        *(unsigned*)(lPw + (lr << 7) + ((sb + 4) ^ ((lr & 7) << 4))) = w1;
      }
    }
    // ---- PV: o[oc] += P[t][s] * V[s][h] (orientation unchanged) ----
#pragma unroll
    for (int ks = 0; ks < 2; ks++) {
      const bf16x8 pf = *reinterpret_cast<const bf16x8*>(
          lPw + (lr << 7) + ((ks * 64 + lu * 16) ^ ((lr & 7) << 4)));
      __builtin_amdgcn_s_setprio(1);
#pragma unroll
      for (int oc = 0; oc < 8; oc++) {
        const int h = oc * 16 + lr;
        bf16x8 vb = *reinterpret_cast<const bf16x8*>(
            (char*)lV + h * 128 + (((ks * 4 + lu) << 4) ^ ((h & 7) << 4)));
        o[oc] = __builtin_amdgcn_mfma_f32_16x16x32_bf16(pf, vb, o[oc], 0, 0, 0);
      }
      __builtin_amdgcn_s_setprio(0);
    }
    __syncthreads();
  }
  // ---- reduce: lane holds partial sum for column t=tw+lr ----
  float tot = lsum;
  tot += __shfl_xor(tot, 16, 64);
  tot += __shfl_xor(tot, 32, 64);
  float rs[4];
#pragma unroll
  for (int r = 0; r < 4; r++)
    rs[r] = 1.f / __shfl(tot, lu * 4 + r, 64);  // sum for t=tw+lu*4+r held at lane lu*4+r
#pragma unroll
  for (int oc = 0; oc < 8; oc++)
#pragma unroll
    for (int r = 0; r < 4; r++) {
      const int t = t_row + r;
      enc[((size_t)b * 2048 + t) * 2048 + n * 128 + oc * 16 + lr] = f2bf(o[oc][r] * rs[r]);
    }
}

extern "C" void kernel_launch(void* const* d_in, const int* in_sizes, int n_in,
                              void* d_out, int out_size, void* d_ws, size_t ws_size,
                              hipStream_t stream) {
  (void)in_sizes; (void)n_in; (void)out_size; (void)ws_size;
  const float* x    = (const float*)d_in[0];
  const float* wq   = (const float*)d_in[3];
  const float* wkv  = (const float*)d_in[4];
  const float* wvec = (const float*)d_in[5];
  char* ws = (char*)d_ws;
  size_t off = 0;
  short* xbf   = (short*)(ws + off); off += (size_t)8388608 * 2;            // x bf16 [B*T][D]
  short* wall  = (short*)(ws + off); off += (size_t)3072 * 2048 * 2;        // [wqT|wkT|wvT] rows x K
  short* wvecT = (short*)(ws + off); off += (size_t)2048 * 2048 * 2;        // [d][nh]
  short* qbuf  = (short*)(ws + off); off += (size_t)2 * 16 * 2048 * 128 * 2; // q bf16 [b][n][t][h]
  short* kvbuf = (short*)(ws + off); off += (size_t)2 * 2 * 4 * 2048 * 128 * 2; // [c][b][kv][t][h]
  short* vTbuf = (short*)(ws + off); off += (size_t)2 * 4 * 128 * 2048 * 2; // v^T [b][kv][h][s]
  short* encb  = (short*)(ws + off); off += (size_t)2 * 2048 * 2048 * 2;    // [b][t][nh]

  hipFuncSetAttribute(reinterpret_cast<const void*>(&k_gemm256<128, 384>),
                      hipFuncAttributeMaxDynamicSharedMemorySize, 131072);
  hipFuncSetAttribute(reinterpret_cast<const void*>(&k_gemm256<128, 256>),
                      hipFuncAttributeMaxDynamicSharedMemorySize, 98304);

  k_cvt<<<8192, 256, 0, stream>>>(x, xbf, 2097152);
  k_tr<float><<<dim3(4, 64, 16), 256, 0, stream>>>(wq, wall, 2048, 128);
  k_tr<float><<<dim3(4, 64, 4), 256, 0, stream>>>(wkv, wall + 4194304, 2048, 128);
  k_tr<float><<<dim3(4, 64, 4), 256, 0, stream>>>(wkv + 1048576, wall + 5242880, 2048, 128);
  k_tr<float><<<dim3(64, 64, 1), 256, 0, stream>>>(wvec, wvecT, 2048, 2048);
  k_gemm256<128, 384><<<dim3(32, 8), 512, 131072, stream>>>(xbf, wall, qbuf, kvbuf,
                                                            3072, 2048, 0);
  k_tr<short><<<dim3(4, 64, 8), 256, 0, stream>>>(kvbuf + 2097152, vTbuf, 2048, 128);
  k_attn<<<dim3(32, 32), 256, 0, stream>>>(qbuf, kvbuf, vTbuf, encb);
  k_gemm256<128, 256><<<dim3(32, 8), 512, 98304, stream>>>(encb, wvecT, d_out, nullptr,
                                                           2048, 2048, 2);
}

// Round 12
// 173.017 us; speedup vs baseline: 1.8781x; 1.0102x over previous
//
#include <hip/hip_runtime.h>
#include <hip/hip_bf16.h>

#define DEVINL static __device__ __forceinline__

typedef __attribute__((ext_vector_type(4))) float f32x4;
typedef __attribute__((ext_vector_type(8))) short bf16x8;

DEVINL short f2bf(float f) {
  __hip_bfloat16 h = __float2bfloat16(f);
  union { __hip_bfloat16 h; short s; } u; u.h = h; return u.s;
}
DEVINL float bf2f(short s) {
  union { unsigned u; float f; } v; v.u = ((unsigned)(unsigned short)s) << 16;
  return v.f;
}
DEVINL float ldf(float x) { return x; }
DEVINL float ldf(short x) { return bf2f(x); }

// ---------------- f32 -> bf16 convert, 4 elems/thread ----------------
__global__ void k_cvt(const float* __restrict__ in, short* __restrict__ out, int n4) {
  int i = blockIdx.x * blockDim.x + threadIdx.x;
  if (i >= n4) return;
  const float4 v = reinterpret_cast<const float4*>(in)[i];
  short4 o;
  o.x = f2bf(v.x); o.y = f2bf(v.y); o.z = f2bf(v.z); o.w = f2bf(v.w);
  reinterpret_cast<short4*>(out)[i] = o;
}

// ------- batched transpose [batch][R][C] -> [batch][C][R], out bf16 -------
template <typename Tin>
__global__ void k_tr(const Tin* __restrict__ in, short* __restrict__ out, int R, int C) {
  __shared__ float tile[32][33];
  const int bz = blockIdx.z;
  const int r0 = blockIdx.y * 32, c0 = blockIdx.x * 32;
  const int tx = threadIdx.x & 31, ty = threadIdx.x >> 5;  // ty in 0..7
  const Tin* ip = in + (size_t)bz * R * C;
  short* op = out + (size_t)bz * R * C;
#pragma unroll
  for (int k = 0; k < 4; k++)
    tile[ty + k * 8][tx] = ldf(ip[(size_t)(r0 + ty + k * 8) * C + c0 + tx]);
  __syncthreads();
#pragma unroll
  for (int k = 0; k < 4; k++)
    op[(size_t)(c0 + ty + k * 8) * R + r0 + tx] = f2bf(tile[tx][ty + k * 8]);
}

// =================== BMxBNxK 4-phase MFMA GEMM (T2+T3+T4+T5+T1) ===================
// C[M][N] = A[M][K] * Bt[N][K]^T ; 512 threads, 8 waves (2M x 4N, 16-stripe interleave)
// LDS dynamic: A0|A1|B0|B1; granule-XOR swizzled.
// 4 merged phases per 2-K-tile iter (24 MFMA each) — halves barrier count vs 8-phase;
// slot discipline and counted-vmcnt ledger preserved (stages precede reads by >=2
// phases with a VMW between; write-after-read barrier-separated).
// Grid MUST be (x, 8); XCD swizzle: y = lin%8 (one B-panel per XCD L2), x = lin/8.
// mode 0: QKV scatter epilogue with FUSED RoPE; mode 2: f32 row-major.

#define GBAR __builtin_amdgcn_s_barrier()
#define LGK asm volatile("s_waitcnt lgkmcnt(0)")
#define PR1 __builtin_amdgcn_s_setprio(1)
#define PR0 __builtin_amdgcn_s_setprio(0)
#define VMW { if constexpr (LPA + LPB == 4) asm volatile("s_waitcnt vmcnt(4)"); \
              else asm volatile("s_waitcnt vmcnt(3)"); }

// stage one half-tile: LN x global_load_lds(16B)/thread; LDS linear, src pre-swizzled
template <int LN>
DEVINL void stage(char* dst, const short* src, int K, int tid) {
#pragma unroll
  for (int L = 0; L < LN; L++) {
    const int loc = L * 8192 + tid * 16;
    const int row = loc >> 7;
    const int gsw = ((loc >> 4) & 7) ^ (row & 7);
    __builtin_amdgcn_global_load_lds(
        (const __attribute__((address_space(1))) void*)(src + (size_t)row * K + gsw * 8),
        (__attribute__((address_space(3))) void*)(dst + loc), 16, 0, 0);
  }
}

#define SA(BUF, HALF, KT) \
  stage<LPA>((BUF) + (HALF) * (ABY / 2), Am + (size_t)((HALF) * (BM / 2)) * K + (KT) * 64, K, tid)
#define SB(BUF, HALF, KT) \
  stage<LPB>((BUF) + (HALF) * (BBY / 2), Bn + (size_t)((HALF) * (BN / 2)) * K + (KT) * 64, K, tid)

#define RDA(BUF, IH)                                                                   \
  { _Pragma("unroll")                                                                  \
    for (int kf_ = 0; kf_ < KFN; kf_++) {                                              \
      _Pragma("unroll")                                                                \
      for (int kk_ = 0; kk_ < 2; kk_++) {                                              \
        const int row_ = ((IH) * KFN + kf_) * 32 + wr * 16 + lr;                       \
        a[kf_ * 2 + kk_] = *(const bf16x8*)((BUF) + row_ * 128 +                       \
                                            (((kk_ * 4 + lu) ^ (lr & 7)) << 4));       \
      } } }

#define RDB(BUF, JH, ARR)                                                              \
  { _Pragma("unroll")                                                                  \
    for (int jf_ = 0; jf_ < JFN; jf_++) {                                              \
      _Pragma("unroll")                                                                \
      for (int kk_ = 0; kk_ < 2; kk_++) {                                              \
        const int row_ = ((JH) * JFN + jf_) * 64 + wc * 16 + lr;                       \
        ARR[jf_ * 2 + kk_] = *(const bf16x8*)((BUF) + row_ * 128 +                     \
                                              (((kk_ * 4 + lu) ^ (lr & 7)) << 4));     \
      } } }

#define MF(IH, JH, ARR)                                                                \
  { _Pragma("unroll")                                                                  \
    for (int kf_ = 0; kf_ < KFN; kf_++)                                                \
      { _Pragma("unroll")                                                              \
        for (int jf_ = 0; jf_ < JFN; jf_++)                                            \
          { _Pragma("unroll")                                                          \
            for (int kk_ = 0; kk_ < 2; kk_++)                                          \
              acc[(IH) * KFN + kf_][(JH) * JFN + jf_] =                                \
                  __builtin_amdgcn_mfma_f32_16x16x32_bf16(                             \
                      a[kf_ * 2 + kk_], ARR[jf_ * 2 + kk_],                            \
                      acc[(IH) * KFN + kf_][(JH) * JFN + jf_], 0, 0, 0);               \
          } } }

template <int BM, int BN>
__global__ __launch_bounds__(512, 2) void k_gemm256(
    const short* __restrict__ A, const short* __restrict__ Bt,
    void* __restrict__ Out0, void* __restrict__ Out1,
    int N, int K, int mode) {
  constexpr int LPA = BM / 128;   // loads/thread per A half-tile
  constexpr int LPB = BN / 128;   // loads/thread per B half-tile
  constexpr int KFN = BM / 64;    // 32-row A groups per M-half
  constexpr int JFN = BN / 128;   // 64-row B groups per N-half
  constexpr int ABY = BM * 128;   // bytes per A buffer [BM][64]
  constexpr int BBY = BN * 128;   // bytes per B buffer [BN][64]
  extern __shared__ __align__(16) char sm[];
  char* A0 = sm;
  char* A1 = sm + ABY;
  char* B0 = sm + 2 * ABY;
  char* B1 = sm + 2 * ABY + BBY;
  // T1: XCD swizzle. Dispatch round-robins lin%8 across XCDs -> give each XCD one
  // n-column (B panel L2-resident), m varies within XCD.
  const int lin = blockIdx.x + gridDim.x * blockIdx.y;
  const int m0 = (lin >> 3) * BM, n0 = (lin & 7) * BN;
  const int tid = threadIdx.x, lane = tid & 63, w = tid >> 6;
  const int wr = w & 1, wc = w >> 1;  // 2M x 4N waves, 16-row/16-col stripes
  const int lr = lane & 15, lu = lane >> 4;
  const short* Am = A + (size_t)m0 * K;
  const short* Bn = Bt + (size_t)n0 * K;
  f32x4 acc[KFN * 2][JFN * 2] = {};
  bf16x8 a[KFN * 2], bJ0[JFN * 2], bJ1[JFN * 2];
  const int NIT = K >> 7;
  const int TMAX = (K >> 6) - 1;

  // prologue: t0 full + t1.{Ah0,Bh1}; wait t0 (leave t1's LPA+LPB loads in flight)
  SA(A0, 0, 0); SB(B0, 1, 0); SA(A0, 1, 0); SB(B0, 0, 0);
  SA(A1, 0, 1); SB(B1, 1, 1);
  VMW; GBAR;

  for (int it = 0; it < NIT; ++it) {
    const int t1 = 2 * it + 1;
    const int t2 = (2 * it + 2 < TMAX) ? 2 * it + 2 : TMAX;
    const int t3 = (2 * it + 3 < TMAX) ? 2 * it + 3 : TMAX;
    // Ph0: even tile, M-half0 x {N0,N1}; stage t1 leftovers (A1h1, B1h0)
    RDA(A0, 0); RDB(B0, 0, bJ0); RDB(B0, 1, bJ1); SA(A1, 1, t1); SB(B1, 0, t1);
    GBAR; LGK; PR1; MF(0, 0, bJ0); MF(0, 1, bJ1); PR0; GBAR;
    // Ph1: M-half1 x {N1,N0} (B from regs); stage t2 into freed A0h0, B0h1
    RDA(A0, 1); SA(A0, 0, t2); SB(B0, 1, t2);
    GBAR; LGK; PR1; MF(1, 1, bJ1); MF(1, 0, bJ0); PR0; VMW; GBAR;
    // Ph2: odd tile, M-half0 x {N0,N1}; stage t2 into freed A0h1, B0h0
    RDA(A1, 0); RDB(B1, 0, bJ0); RDB(B1, 1, bJ1); SA(A0, 1, t2); SB(B0, 0, t2);
    GBAR; LGK; PR1; MF(0, 0, bJ0); MF(0, 1, bJ1); PR0; GBAR;
    // Ph3: M-half1 x {N1,N0}; stage t3 (A1h0, B1h1)
    RDA(A1, 1); SA(A1, 0, t3); SB(B1, 1, t3);
    GBAR; LGK; PR1; MF(1, 1, bJ1); MF(1, 0, bJ0); PR0; VMW; GBAR;
  }

  // ---------------- epilogue ----------------
  if (mode == 2) {
#pragma unroll
    for (int k = 0; k < KFN * 2; k++)
#pragma unroll
      for (int j = 0; j < JFN * 2; j++)
#pragma unroll
        for (int r = 0; r < 4; r++) {
          const int m = m0 + k * 32 + wr * 16 + lu * 4 + r;
          const int n = n0 + j * 64 + wc * 16 + lr;
          ((float*)Out0)[(size_t)m * N + n] = acc[k][j][r];
        }
  } else {
    // Fused RoPE: fragment pair (j=2u, j=2u+1) holds (h, h+64) for same t.
    // Per-thread rotation index i = wc*16+lr is constant.
    const int i_rope = wc * 16 + lr;
    const float inv = __expf(-(float)i_rope * (float)(9.210340371976184 / 64.0));
#pragma unroll
    for (int k = 0; k < KFN * 2; k++) {
      float sn[4], cs[4];
#pragma unroll
      for (int r = 0; r < 4; r++) {
        const int m = m0 + k * 32 + wr * 16 + lu * 4 + r;
        sincosf((float)(m & 2047) * inv, &sn[r], &cs[r]);
      }
#pragma unroll
      for (int u = 0; u < JFN; u++) {
        const int n_lo = n0 + (2 * u) * 64 + wc * 16 + lr;  // h = i_rope (<64)
        const int reg = (n_lo < 2048) ? 0 : ((n_lo < 2560) ? 1 : 2);  // q/k/v
#pragma unroll
        for (int r = 0; r < 4; r++) {
          const int m = m0 + k * 32 + wr * 16 + lu * 4 + r;
          const int bb = m >> 11, t = m & 2047;
          float lo = acc[k][2 * u][r], hi = acc[k][2 * u + 1][r];
          if (reg < 2) {  // rotate
            const float l2 = lo * cs[r] - hi * sn[r];
            const float h2 = hi * cs[r] + lo * sn[r];
            const float sc = (reg == 0) ? 0.08838834764831845f : 1.0f;
            lo = l2 * sc; hi = h2 * sc;
          }
#pragma unroll
          for (int p = 0; p < 2; p++) {
            const int n = n_lo + p * 64;
            const float v = p ? hi : lo;
            if (n < 2048) {  // q: [b][head][t][h]
              ((short*)Out0)[(((size_t)(bb * 16 + (n >> 7))) << 18) + t * 128 + (n & 127)] =
                  f2bf(v);
            } else {  // kv: [c][b][kv][t][h]
              const int nn = n - 2048;
              ((short*)Out1)[(((size_t)(((nn >> 9) * 2 + bb) * 4 + ((nn >> 7) & 3))) << 18) +
                             t * 128 + (nn & 127)] = f2bf(v);
            }
          }
        }
      }
    }
  }
}

// ---------------- flash attention, sliding window + tanh soft-cap ----------------
// Swapped QK^T: sc = mfma(K,Q) -> sc[cg][r] = S[s=s0+cg*16+lu*4+r][t=tw+lr].
// Soft-cap via cubic: 50*tanh(x/50) ~= x - x^3/7500 (err < 2e-3 at |x|=10).
// Fixed-max softmax (cap bounds logits): p = exp(cap); scalar lsum per lane.
__global__ __launch_bounds__(256) void k_attn(
    const short* __restrict__ q, const short* __restrict__ kk,
    const short* __restrict__ vT, short* __restrict__ enc) {
  __shared__ __align__(16) short lK[64 * 128];   // [s][h], byte ^= ((s&7)<<4)
  __shared__ __align__(16) short lV[128 * 64];   // [h][s], byte ^= ((h&7)<<4)
  __shared__ __align__(16) short lP[4][16 * 64]; // per-wave P [t][s], byte ^= ((t&7)<<4)
  const int bn = blockIdx.x, b = bn >> 4, n = bn & 15, kv = n >> 2;
  const int qt0 = (31 - blockIdx.y) * 64;  // heavy blocks dispatched first
  const int tid = threadIdx.x, lane = tid & 63, w = tid >> 6;
  const int lr = lane & 15, lu = lane >> 4;
  const short* qbase = q + (((size_t)(b * 16 + n)) << 18) + (size_t)(qt0 + w * 16) * 128;
  bf16x8 qa[4];
#pragma unroll
  for (int c = 0; c < 4; c++)
    qa[c] = *reinterpret_cast<const bf16x8*>(qbase + lr * 128 + c * 32 + lu * 8);
  f32x4 o[8] = {};
  float lsum = 0.f;
  const short* kbase = kk + (((size_t)(b * 4 + kv)) << 18);
  const short* vbase = vT + (((size_t)(b * 4 + kv)) << 18);
  char* lPw = (char*)lP[w];
  const int tw = qt0 + w * 16;
  const int t_row = tw + lu * 4;
  int st0 = qt0 - 1023; if (st0 < 0) st0 = 0;
  st0 >>= 6;
  const int stE = (qt0 + 63) >> 6;
  for (int st = st0; st <= stE; st++) {
    const int s0 = st << 6;
#pragma unroll
    for (int c = 0; c < 4; c++) {
      const int L = w * 4096 + c * 1024 + lane * 16;  // byte offset in 16 KiB tile
      {  // K tile: linear LDS dest, pre-swizzled global source
        const int s = L >> 8, slot = (L >> 4) & 15;
        const int sp = slot ^ (s & 7);
        __builtin_amdgcn_global_load_lds(
            (const __attribute__((address_space(1))) void*)(kbase + (size_t)(s0 + s) * 128 + sp * 8),
            (__attribute__((address_space(3))) void*)((char*)lK + L), 16, 0, 0);
      }
      {  // V tile
        const int h = L >> 7, slot = (L >> 4) & 7;
        const int u = slot ^ (h & 7);
        __builtin_amdgcn_global_load_lds(
            (const __attribute__((address_space(1))) void*)(vbase + (size_t)h * 2048 + s0 + u * 8),
            (__attribute__((address_space(3))) void*)((char*)lV + L), 16, 0, 0);
      }
    }
    __syncthreads();
    // ---- QK^T (swapped): sc[cg][r] = S[s=cg*16+lu*4+r][t=lr] ----
    f32x4 sc[4];
    __builtin_amdgcn_s_setprio(1);
#pragma unroll
    for (int cg = 0; cg < 4; cg++) {
      sc[cg] = (f32x4){0.f, 0.f, 0.f, 0.f};
      const int s = cg * 16 + lr;
      const int sw = (s & 7) << 4;
#pragma unroll
      for (int c = 0; c < 4; c++) {
        bf16x8 kb = *reinterpret_cast<const bf16x8*>((char*)lK + s * 256 + (((c * 4 + lu) << 4) ^ sw));
        sc[cg] = __builtin_amdgcn_mfma_f32_16x16x32_bf16(kb, qa[c], sc[cg], 0, 0, 0);
      }
    }
    __builtin_amdgcn_s_setprio(0);
    // ---- cubic soft-cap + exp, pack pairs, write P (b32) ----
    const bool allv = (s0 + 63 <= tw) && (s0 + 1008 >= tw);
    if (allv) {
#pragma unroll
      for (int cg = 0; cg < 4; cg++) {
        float pr[4];
#pragma unroll
        for (int r = 0; r < 4; r++) {
          const float x = sc[cg][r];
          const float cap = __builtin_fmaf(x * x * x, -1.3333333e-4f, x);
          const float p = __expf(cap);
          lsum += p;
          pr[r] = p;
        }
        unsigned w0, w1;
        asm("v_cvt_pk_bf16_f32 %0, %1, %2" : "=v"(w0) : "v"(pr[0]), "v"(pr[1]));
        asm("v_cvt_pk_bf16_f32 %0, %1, %2" : "=v"(w1) : "v"(pr[2]), "v"(pr[3]));
        const int sb = (cg * 16 + lu * 4) << 1;  // byte offset of s-pair base
        *(unsigned*)(lPw + (lr << 7) + (sb ^ ((lr & 7) << 4))) = w0;
        *(unsigned*)(lPw + (lr << 7) + ((sb + 4) ^ ((lr & 7) << 4))) = w1;
      }
    } else {
      const int t = tw + lr;
#pragma unroll
      for (int cg = 0; cg < 4; cg++) {
        float pr[4];
#pragma unroll
        for (int r = 0; r < 4; r++) {
          const int s = s0 + cg * 16 + lu * 4 + r;
          const bool valid = (s <= t) & (s + 1024 > t);
          const float x = sc[cg][r];
          const float cap = __builtin_fmaf(x * x * x, -1.3333333e-4f, x);
          float p = __expf(cap);
          p = valid ? p : 0.f;
          lsum += p;
          pr[r] = p;
        }
        unsigned w0, w1;
        asm("v_cvt_pk_bf16_f32 %0, %1, %2" : "=v"(w0) : "v"(pr[0]), "v"(pr[1]));
        asm("v_cvt_pk_bf16_f32 %0, %1, %2" : "=v"(w1) : "v"(pr[2]), "v"(pr[3]));
        const int sb = (cg * 16 + lu * 4) << 1;
        *(unsigned*)(lPw + (lr << 7) + (sb ^ ((lr & 7) << 4))) = w0;
        *(unsigned*)(lPw + (lr << 7) + ((sb + 4) ^ ((lr & 7) << 4))) = w1;
      }
    }
    // ---- PV: o[oc] += P[t][s] * V[s][h] (orientation unchanged) ----
#pragma unroll
    for (int ks = 0; ks < 2; ks++) {
      const bf16x8 pf = *reinterpret_cast<const bf16x8*>(
          lPw + (lr << 7) + ((ks * 64 + lu * 16) ^ ((lr & 7) << 4)));
      __builtin_amdgcn_s_setprio(1);
#pragma unroll
      for (int oc = 0; oc < 8; oc++) {
        const int h = oc * 16 + lr;
        bf16x8 vb = *reinterpret_cast<const bf16x8*>(
            (char*)lV + h * 128 + (((ks * 4 + lu) << 4) ^ ((h & 7) << 4)));
        o[oc] = __builtin_amdgcn_mfma_f32_16x16x32_bf16(pf, vb, o[oc], 0, 0, 0);
      }
      __builtin_amdgcn_s_setprio(0);
    }
    __syncthreads();
  }
  // ---- reduce: lane holds partial sum for column t=tw+lr ----
  float tot = lsum;
  tot += __shfl_xor(tot, 16, 64);
  tot += __shfl_xor(tot, 32, 64);
  float rs[4];
#pragma unroll
  for (int r = 0; r < 4; r++)
    rs[r] = 1.f / __shfl(tot, lu * 4 + r, 64);  // sum for t=tw+lu*4+r held at lane lu*4+r
#pragma unroll
  for (int oc = 0; oc < 8; oc++)
#pragma unroll
    for (int r = 0; r < 4; r++) {
      const int t = t_row + r;
      enc[((size_t)b * 2048 + t) * 2048 + n * 128 + oc * 16 + lr] = f2bf(o[oc][r] * rs[r]);
    }
}

extern "C" void kernel_launch(void* const* d_in, const int* in_sizes, int n_in,
                              void* d_out, int out_size, void* d_ws, size_t ws_size,
                              hipStream_t stream) {
  (void)in_sizes; (void)n_in; (void)out_size; (void)ws_size;
  const float* x    = (const float*)d_in[0];
  const float* wq   = (const float*)d_in[3];
  const float* wkv  = (const float*)d_in[4];
  const float* wvec = (const float*)d_in[5];
  char* ws = (char*)d_ws;
  size_t off = 0;
  short* xbf   = (short*)(ws + off); off += (size_t)8388608 * 2;            // x bf16 [B*T][D]
  short* wall  = (short*)(ws + off); off += (size_t)3072 * 2048 * 2;        // [wqT|wkT|wvT] rows x K
  short* wvecT = (short*)(ws + off); off += (size_t)2048 * 2048 * 2;        // [d][nh]
  short* qbuf  = (short*)(ws + off); off += (size_t)2 * 16 * 2048 * 128 * 2; // q bf16 [b][n][t][h]
  short* kvbuf = (short*)(ws + off); off += (size_t)2 * 2 * 4 * 2048 * 128 * 2; // [c][b][kv][t][h]
  short* vTbuf = (short*)(ws + off); off += (size_t)2 * 4 * 128 * 2048 * 2; // v^T [b][kv][h][s]
  short* encb  = (short*)(ws + off); off += (size_t)2 * 2048 * 2048 * 2;    // [b][t][nh]

  hipFuncSetAttribute(reinterpret_cast<const void*>(&k_gemm256<128, 384>),
                      hipFuncAttributeMaxDynamicSharedMemorySize, 131072);
  hipFuncSetAttribute(reinterpret_cast<const void*>(&k_gemm256<128, 256>),
                      hipFuncAttributeMaxDynamicSharedMemorySize, 98304);

  k_cvt<<<8192, 256, 0, stream>>>(x, xbf, 2097152);
  k_tr<float><<<dim3(4, 64, 16), 256, 0, stream>>>(wq, wall, 2048, 128);
  k_tr<float><<<dim3(4, 64, 4), 256, 0, stream>>>(wkv, wall + 4194304, 2048, 128);
  k_tr<float><<<dim3(4, 64, 4), 256, 0, stream>>>(wkv + 1048576, wall + 5242880, 2048, 128);
  k_tr<float><<<dim3(64, 64, 1), 256, 0, stream>>>(wvec, wvecT, 2048, 2048);
  k_gemm256<128, 384><<<dim3(32, 8), 512, 131072, stream>>>(xbf, wall, qbuf, kvbuf,
                                                            3072, 2048, 0);
  k_tr<short><<<dim3(4, 64, 8), 256, 0, stream>>>(kvbuf + 2097152, vTbuf, 2048, 128);
  k_attn<<<dim3(32, 32), 256, 0, stream>>>(qbuf, kvbuf, vTbuf, encb);
  k_gemm256<128, 256><<<dim3(32, 8), 512, 98304, stream>>>(encb, wvecT, d_out, nullptr,
                                                           2048, 2048, 2);
}